// Round 3
// baseline (737.854 us; speedup 1.0000x reference)
//
#include <hip/hip_runtime.h>
#include <hip/hip_bf16.h>

#define B_ 2
#define S_ 4096
#define HID_ 2048
#define NH_ 32
#define NKV_ 8
#define HD_ 64
#define GROUPS_ 4
#define NCH_ 32   // outer_sum S-chunks

typedef short short8 __attribute__((ext_vector_type(8)));
typedef float floatx4 __attribute__((ext_vector_type(4)));

__device__ __forceinline__ float bf2f(unsigned short u){
  union { unsigned int i; float f; } v; v.i = ((unsigned int)u) << 16; return v.f;
}
__device__ __forceinline__ unsigned short f2bf(float f){
  union { float f; unsigned int i; } v; v.f = f;
  unsigned int i = v.i;
  unsigned int r = (i + 0x7fffu + ((i >> 16) & 1u)) >> 16;  // RNE
  return (unsigned short)r;
}

// async global->LDS, 16B per lane, LDS dest = wave-uniform base + lane*16
__device__ __forceinline__ void async_copy16(unsigned short* lds, const unsigned short* g){
  __builtin_amdgcn_global_load_lds((const __attribute__((address_space(1))) void*)g,
                                   (__attribute__((address_space(3))) void*)lds,
                                   16, 0, 0);
}

// ---------------- fp32 -> bf16 bulk convert (hidden_states) ----------------
__global__ void conv_bf16(const float* __restrict__ x, unsigned short* __restrict__ y, int n4){
  int i = blockIdx.x * 256 + threadIdx.x;
  if (i < n4){
    float4 v = ((const float4*)x)[i];
    ushort4 o;
    o.x = f2bf(v.x); o.y = f2bf(v.y); o.z = f2bf(v.z); o.w = f2bf(v.w);
    ((ushort4*)y)[i] = o;
  }
}

// ---------------- W[K,N] fp32 -> Wt[N,K] bf16 (tiled transpose) ----------------
__global__ void transpose_to_bf16(const float* __restrict__ W, unsigned short* __restrict__ Wt,
                                  int K, int N){
  __shared__ float tile[32][33];
  int n0 = blockIdx.x * 32, k0 = blockIdx.y * 32;
  int tx = threadIdx.x, ty = threadIdx.y;   // 32 x 8
  #pragma unroll
  for (int j = 0; j < 4; j++)
    tile[ty + j*8][tx] = W[(size_t)(k0 + ty + j*8) * N + n0 + tx];
  __syncthreads();
  #pragma unroll
  for (int j = 0; j < 4; j++)
    Wt[(size_t)(n0 + ty + j*8) * K + k0 + tx] = f2bf(tile[tx][ty + j*8]);
}

// ---------------- 256x256-tile 4-phase pipelined GEMM: C = A @ Bt^T ----------------
// 512 threads = 8 waves (2M x 4N), per-wave 128x64 output, BK=64, 128 KiB dbuf LDS.
// Every MFMA's fragments are ds_read >=1 phase earlier; stages spread 2 loads/phase-pair;
// vmcnt(4) at ph2 confirms tile T+1 before its first reads at ph3 (one barrier later).
//   ph0: read bfT[2-3]+afT[4-5]            | MFMA Q00 = afT[0-3] x bfT[0-1]
//   ph1: read afT[6-7]                     | MFMA Q01 = afT[0-3] x bfT[2-3]
//   ph2: stage A(T+2) ; vmcnt(4)           | MFMA Q10 = afT[4-7] x bfT[0-1]
//   ph3: stage B(T+2) ; read af'[0-3]+bf'[0-1] (tile T+1, other buf) | MFMA Q11
#define GTILE 16384   // 256*64 bf16 elements per operand per buffer

__global__ __launch_bounds__(512, 2) void gemm256(
    const unsigned short* __restrict__ A, const unsigned short* __restrict__ Bt,
    float* __restrict__ C, int M, int N, int K)
{
  __shared__ __align__(16) unsigned short As[2 * GTILE];
  __shared__ __align__(16) unsigned short Bs[2 * GTILE];

  const int tid = threadIdx.x;
  const int w = tid >> 6, lane = tid & 63;
  const int wr = w >> 2, wc = w & 3;
  const int l15 = lane & 15, quad = lane >> 4;

  // bijective XCD-aware swizzle (nwg % 8 == 0 for all shapes here)
  const int nbx = N >> 8;
  int flat = blockIdx.y * nbx + blockIdx.x;
  int nwg  = nbx * (M >> 8);
  int cpx  = nwg >> 3;
  int swz  = (flat & 7) * cpx + (flat >> 3);
  int bx = swz % nbx, by = swz / nbx;
  const int m0 = by << 8, n0 = bx << 8;

  // ---- staging addressing (per wave-call: 64 lanes x 16B = 512 shorts linear in LDS) ----
  const int srow = (w << 3) + (lane >> 3);          // row 0..63 within a 64-row call
  const int scc  = (lane & 7) ^ (lane >> 3);        // swizzled 16B chunk within 128B row
  const unsigned short* gA = A  + (size_t)(m0 + srow) * K + scc * 8;
  const unsigned short* gB = Bt + (size_t)(n0 + srow) * K + scc * 8;
  const size_t rs64  = (size_t)64  * K;             // second-call row offset
  const size_t rs128 = (size_t)128 * K;             // half-tile row offset
  unsigned short* lA0 = As + (w << 9);
  unsigned short* lB0 = Bs + (w << 9);

#define STAGE_A(bsel, h, t) do { \
    unsigned short* _d = lA0 + (bsel) * GTILE + (h) * 8192; \
    const unsigned short* _g = gA + (size_t)(h) * rs128 + (size_t)(t) * 64; \
    async_copy16(_d, _g); \
    async_copy16(_d + 4096, _g + rs64); \
  } while (0)
#define STAGE_B(bsel, h, t) do { \
    unsigned short* _d = lB0 + (bsel) * GTILE + (h) * 8192; \
    const unsigned short* _g = gB + (size_t)(h) * rs128 + (size_t)(t) * 64; \
    async_copy16(_d, _g); \
    async_copy16(_d + 4096, _g + rs64); \
  } while (0)
#define SCHED0 __builtin_amdgcn_sched_barrier(0)
#define BARRIER do { SCHED0; __builtin_amdgcn_s_barrier(); SCHED0; } while (0)

  // ---- fragment read offsets (shorts): row*64 + ((kchunk ^ (row&7))<<3); row&7 == lane&7 ----
  const int ks0  = ((quad     ^ (lane & 7)) << 3);
  const int ks1  = (((4+quad) ^ (lane & 7)) << 3);
  const int arow = (wr * 128 + l15) * 64;
  const int brow = (wc * 64  + l15) * 64;

  floatx4 acc[8][4] = {};
  short8 af[8][2], bfr[4][2];

  const int nt = K >> 6;

  // ---- prologue: stage tile0 (buf0) and tile1 (buf1); tile0 landed; pre-read Q00 frags ----
  STAGE_A(0, 0, 0); STAGE_A(0, 1, 0); STAGE_B(0, 0, 0); STAGE_B(0, 1, 0);
  if (nt > 1){
    STAGE_A(1, 0, 1); STAGE_A(1, 1, 1); STAGE_B(1, 0, 1); STAGE_B(1, 1, 1);
    asm volatile("s_waitcnt vmcnt(8)" ::: "memory");
  } else {
    asm volatile("s_waitcnt vmcnt(0)" ::: "memory");
  }
  BARRIER;
  #pragma unroll
  for (int m = 0; m < 4; ++m){
    af[m][0] = *(const short8*)(As + arow + m * 1024 + ks0);
    af[m][1] = *(const short8*)(As + arow + m * 1024 + ks1);
  }
  #pragma unroll
  for (int n = 0; n < 2; ++n){
    bfr[n][0] = *(const short8*)(Bs + brow + n * 1024 + ks0);
    bfr[n][1] = *(const short8*)(Bs + brow + n * 1024 + ks1);
  }
  SCHED0;

  for (int T = 0; T < nt; ++T){
    const int p = T & 1;
    const unsigned short* Ab = As + p * GTILE;
    const unsigned short* Bb = Bs + p * GTILE;
    const unsigned short* Aq = As + (p ^ 1) * GTILE;
    const unsigned short* Bq = Bs + (p ^ 1) * GTILE;

    // ============ ph0: read bfT[2-3] + afT[4-5] | MFMA Q00 ============
    #pragma unroll
    for (int n = 2; n < 4; ++n){
      bfr[n][0] = *(const short8*)(Bb + brow + n * 1024 + ks0);
      bfr[n][1] = *(const short8*)(Bb + brow + n * 1024 + ks1);
    }
    #pragma unroll
    for (int m = 4; m < 6; ++m){
      af[m][0] = *(const short8*)(Ab + arow + m * 1024 + ks0);
      af[m][1] = *(const short8*)(Ab + arow + m * 1024 + ks1);
    }
    BARRIER;
    __builtin_amdgcn_s_setprio(1);
    #pragma unroll
    for (int m = 0; m < 4; ++m)
      #pragma unroll
      for (int n = 0; n < 2; ++n){
        acc[m][n] = __builtin_amdgcn_mfma_f32_16x16x32_bf16(af[m][0], bfr[n][0], acc[m][n], 0, 0, 0);
        acc[m][n] = __builtin_amdgcn_mfma_f32_16x16x32_bf16(af[m][1], bfr[n][1], acc[m][n], 0, 0, 0);
      }
    __builtin_amdgcn_s_setprio(0);
    BARRIER;

    // ============ ph1: read afT[6-7] | MFMA Q01 ============
    #pragma unroll
    for (int m = 6; m < 8; ++m){
      af[m][0] = *(const short8*)(Ab + arow + m * 1024 + ks0);
      af[m][1] = *(const short8*)(Ab + arow + m * 1024 + ks1);
    }
    BARRIER;
    __builtin_amdgcn_s_setprio(1);
    #pragma unroll
    for (int m = 0; m < 4; ++m)
      #pragma unroll
      for (int n = 2; n < 4; ++n){
        acc[m][n] = __builtin_amdgcn_mfma_f32_16x16x32_bf16(af[m][0], bfr[n][0], acc[m][n], 0, 0, 0);
        acc[m][n] = __builtin_amdgcn_mfma_f32_16x16x32_bf16(af[m][1], bfr[n][1], acc[m][n], 0, 0, 0);
      }
    __builtin_amdgcn_s_setprio(0);
    BARRIER;

    // ============ ph2: stage A(T+2); vmcnt(4) | MFMA Q10 ============
    // vmcnt(4) leaves only the 4 A-stages just issued in flight -> tile T+1 fully
    // landed before the ph2-end barrier; its first reads are in ph3 (safe cross-wave).
    if (T + 2 < nt){
      STAGE_A(p, 0, T + 2); STAGE_A(p, 1, T + 2);
      asm volatile("s_waitcnt vmcnt(4)" ::: "memory");
    } else {
      asm volatile("s_waitcnt vmcnt(0)" ::: "memory");
    }
    BARRIER;
    __builtin_amdgcn_s_setprio(1);
    #pragma unroll
    for (int m = 4; m < 8; ++m)
      #pragma unroll
      for (int n = 0; n < 2; ++n){
        acc[m][n] = __builtin_amdgcn_mfma_f32_16x16x32_bf16(af[m][0], bfr[n][0], acc[m][n], 0, 0, 0);
        acc[m][n] = __builtin_amdgcn_mfma_f32_16x16x32_bf16(af[m][1], bfr[n][1], acc[m][n], 0, 0, 0);
      }
    __builtin_amdgcn_s_setprio(0);
    BARRIER;

    // ============ ph3: stage B(T+2); read tile T+1 Q00 frags | MFMA Q11 ============
    if (T + 2 < nt){ STAGE_B(p, 0, T + 2); STAGE_B(p, 1, T + 2); }
    if (T + 1 < nt){
      #pragma unroll
      for (int m = 0; m < 4; ++m){
        af[m][0] = *(const short8*)(Aq + arow + m * 1024 + ks0);
        af[m][1] = *(const short8*)(Aq + arow + m * 1024 + ks1);
      }
      #pragma unroll
      for (int n = 0; n < 2; ++n){
        bfr[n][0] = *(const short8*)(Bq + brow + n * 1024 + ks0);
        bfr[n][1] = *(const short8*)(Bq + brow + n * 1024 + ks1);
      }
    }
    BARRIER;
    __builtin_amdgcn_s_setprio(1);
    #pragma unroll
    for (int m = 4; m < 8; ++m)
      #pragma unroll
      for (int n = 2; n < 4; ++n){
        acc[m][n] = __builtin_amdgcn_mfma_f32_16x16x32_bf16(af[m][0], bfr[n][0], acc[m][n], 0, 0, 0);
        acc[m][n] = __builtin_amdgcn_mfma_f32_16x16x32_bf16(af[m][1], bfr[n][1], acc[m][n], 0, 0, 0);
      }
    __builtin_amdgcn_s_setprio(0);
    BARRIER;
  }

#undef STAGE_A
#undef STAGE_B
#undef SCHED0
#undef BARRIER

  #pragma unroll
  for (int mi = 0; mi < 8; ++mi){
    const int row = m0 + wr * 128 + mi * 16 + quad * 4;
    #pragma unroll
    for (int ni = 0; ni < 4; ++ni){
      const int col = n0 + wc * 64 + ni * 16 + l15;
      #pragma unroll
      for (int r = 0; r < 4; ++r)
        C[(size_t)(row + r) * N + col] = acc[mi][ni][r];
    }
  }
}

// ---------------- RoPE + kappa for Q: [B,S,NH,HD] fp32 -> [B,NH,S,HD] bf16 ----------------
__global__ void rope_kappa_q(const float* __restrict__ Qlin, unsigned short* __restrict__ Qk){
  int idx = blockIdx.x * 256 + threadIdx.x;    // B*S*NH*32 = 2^23 threads
  int i = idx & 31;
  int n = (idx >> 5) & (NH_ - 1);
  int s = (idx >> 10) & (S_ - 1);
  int b = idx >> 22;
  float invf = exp2f(-(float)i * (13.287712379549449f / 32.0f));  // 10000^(-i/32)
  float ang = (float)s * invf;
  float c = cosf(ang), sn = sinf(ang);
  size_t in_o = ((size_t)(b * S_ + s) * NH_ + n) * HD_;
  float x1 = Qlin[in_o + i];
  float x2 = Qlin[in_o + i + 32];
  float r1 = x1 * c - x2 * sn;
  float r2 = x2 * c + x1 * sn;
  r1 = r1 > 0.f ? r1 + 1.f : __expf(r1);
  r2 = r2 > 0.f ? r2 + 1.f : __expf(r2);
  size_t o = ((size_t)(b * NH_ + n) * S_ + s) * HD_;
  Qk[o + i] = f2bf(r1);
  Qk[o + i + 32] = f2bf(r2);
}

// ---------------- RoPE + kappa for K (fused KV layout [B,S,1024], K = cols 0..511) ----------------
__global__ void rope_kappa_k(const float* __restrict__ KVlin, unsigned short* __restrict__ Kk){
  int idx = blockIdx.x * 256 + threadIdx.x;    // B*S*NKV*32 = 2^21 threads
  int i = idx & 31;
  int kv = (idx >> 5) & (NKV_ - 1);
  int s = (idx >> 8) & (S_ - 1);
  int b = idx >> 20;
  float invf = exp2f(-(float)i * (13.287712379549449f / 32.0f));
  float ang = (float)s * invf;
  float c = cosf(ang), sn = sinf(ang);
  size_t in_o = (size_t)(b * S_ + s) * 1024 + kv * HD_;
  float x1 = KVlin[in_o + i];
  float x2 = KVlin[in_o + i + 32];
  float r1 = x1 * c - x2 * sn;
  float r2 = x2 * c + x1 * sn;
  r1 = r1 > 0.f ? r1 + 1.f : __expf(r1);
  r2 = r2 > 0.f ? r2 + 1.f : __expf(r2);
  size_t o = ((size_t)(b * NKV_ + kv) * S_ + s) * HD_;
  Kk[o + i] = f2bf(r1);
  Kk[o + i + 32] = f2bf(r2);
}

// ---------------- Qg[b,n,d] = mean_s Qk[b,n,s,d]  (split-S, atomics) ----------------
__global__ __launch_bounds__(256) void qg_mean(const unsigned short* __restrict__ Qk,
                                               float* __restrict__ Qg){
  int bn = blockIdx.x, chunk = blockIdx.y;     // 64 x 16
  int tid = threadIdx.x;
  int dgrp = tid & 7, sgrp = tid >> 3;         // 8 d-chunks x 32 s-rows
  const unsigned short* base = Qk + (size_t)bn * S_ * HD_
                             + (size_t)(chunk * 256 + sgrp) * HD_ + dgrp * 8;
  float acc[8] = {};
  #pragma unroll
  for (int i = 0; i < 8; i++){
    short8 v = *(const short8*)(base + (size_t)i * 32 * HD_);
    #pragma unroll
    for (int e = 0; e < 8; e++) acc[e] += bf2f((unsigned short)v[e]);
  }
  __shared__ float red[256][8];
  #pragma unroll
  for (int e = 0; e < 8; e++) red[tid][e] = acc[e];
  __syncthreads();
  if (tid < 64){
    int dg = tid >> 3, e = tid & 7;
    float s = 0.f;
    #pragma unroll
    for (int g = 0; g < 32; g++) s += red[g * 8 + dg][e];
    atomicAdd(&Qg[bn * 64 + tid], s * (1.0f / (float)S_));
  }
}

// ---------------- logits[b,n,s] = dot(Qg[b,n], Kk[b,kv,s]) ----------------
__global__ __launch_bounds__(256) void logits_kernel(const unsigned short* __restrict__ Kk,
                                                     const float* __restrict__ Qg,
                                                     float* __restrict__ logits){
  int bn = blockIdx.x, chunk = blockIdx.y;     // 64 x 16
  int b = bn / NH_, n = bn % NH_, kv = n / GROUPS_;
  int tid = threadIdx.x;
  __shared__ float qg[64];
  if (tid < 64) qg[tid] = Qg[bn * 64 + tid];
  __syncthreads();
  int s = chunk * 256 + tid;
  const unsigned short* row = Kk + ((size_t)(b * NKV_ + kv) * S_ + s) * HD_;
  float acc = 0.f;
  #pragma unroll
  for (int c = 0; c < 8; c++){
    short8 v = *(const short8*)(row + c * 8);
    #pragma unroll
    for (int e = 0; e < 8; e++) acc += qg[c * 8 + e] * bf2f((unsigned short)v[e]);
  }
  logits[(size_t)bn * S_ + s] = acc;
}

// ---------------- softmax * S over logits -> alpha (in place OK) ----------------
__global__ __launch_bounds__(256) void softmax_kernel(const float* __restrict__ logits,
                                                      float* __restrict__ alpha){
  int bn = blockIdx.x;
  int tid = threadIdx.x;
  float l[16];
  float mymax = -1e30f;
  #pragma unroll
  for (int j = 0; j < 16; j++){
    l[j] = logits[(size_t)bn * S_ + j * 256 + tid];
    mymax = fmaxf(mymax, l[j]);
  }
  __shared__ float red[256];
  red[tid] = mymax; __syncthreads();
  for (int st = 128; st > 0; st >>= 1){
    if (tid < st) red[tid] = fmaxf(red[tid], red[tid + st]);
    __syncthreads();
  }
  float gmax = red[0];
  __syncthreads();
  float mysum = 0.f;
  #pragma unroll
  for (int j = 0; j < 16; j++){ l[j] = __expf(l[j] - gmax); mysum += l[j]; }
  red[tid] = mysum; __syncthreads();
  for (int st = 128; st > 0; st >>= 1){
    if (tid < st) red[tid] += red[tid + st];
    __syncthreads();
  }
  float inv = (float)S_ / red[0];
  #pragma unroll
  for (int j = 0; j < 16; j++)
    alpha[(size_t)bn * S_ + j * 256 + tid] = l[j] * inv;
}

// ---------------- outer_sum: per (b,kv,chunk), all 4 GQA heads; V from fused KV cols 512.. ----------------
__global__ __launch_bounds__(256) void outer_sum_kernel(const unsigned short* __restrict__ Kk,
                                                        const float* __restrict__ KVlin,
                                                        const float* __restrict__ alpha,
                                                        float* __restrict__ part){
  int bkv = blockIdx.x, chunk = blockIdx.y;     // 16 x NCH_
  int b = bkv >> 3, kv = bkv & 7;
  int tid = threadIdx.x;
  int d = tid >> 2, fb = (tid & 3) * 16;
  __shared__ float ks[64][64];   // [si][d]
  __shared__ float vs[64][64];   // [si][f]
  __shared__ float as[4][64];    // [h][si]
  float acc[4][16] = {};
  const unsigned short* kb = Kk + (size_t)(b * NKV_ + kv) * S_ * HD_;
  const int SPC = S_ / NCH_;     // 128 s per chunk

  for (int t = 0; t < SPC / 64; t++){
    int ss = chunk * SPC + t * 64;
    #pragma unroll
    for (int j = 0; j < 16; j++){
      int idx = j * 256 + tid;
      int si = idx >> 6, dd = idx & 63;
      ks[si][dd] = bf2f(kb[(size_t)(ss + si) * HD_ + dd]);
      vs[si][dd] = KVlin[(size_t)(b * S_ + ss + si) * 1024 + 512 + kv * HD_ + dd];
    }
    {
      int h = tid >> 6, si = tid & 63;
      as[h][si] = alpha[(size_t)(b * NH_ + kv * GROUPS_ + h) * S_ + ss + si];
    }
    __syncthreads();
    #pragma unroll 4
    for (int si = 0; si < 64; si++){
      float k = ks[si][d];
      float4 v0 = *(const float4*)&vs[si][fb];
      float4 v1 = *(const float4*)&vs[si][fb + 4];
      float4 v2 = *(const float4*)&vs[si][fb + 8];
      float4 v3 = *(const float4*)&vs[si][fb + 12];
      #pragma unroll
      for (int h = 0; h < 4; h++){
        float ak = as[h][si] * k;
        acc[h][0]  += ak * v0.x; acc[h][1]  += ak * v0.y; acc[h][2]  += ak * v0.z; acc[h][3]  += ak * v0.w;
        acc[h][4]  += ak * v1.x; acc[h][5]  += ak * v1.y; acc[h][6]  += ak * v1.z; acc[h][7]  += ak * v1.w;
        acc[h][8]  += ak * v2.x; acc[h][9]  += ak * v2.y; acc[h][10] += ak * v2.z; acc[h][11] += ak * v2.w;
        acc[h][12] += ak * v3.x; acc[h][13] += ak * v3.y; acc[h][14] += ak * v3.z; acc[h][15] += ak * v3.w;
      }
    }
    __syncthreads();
  }

  #pragma unroll
  for (int h = 0; h < 4; h++){
    float* pb = part + ((size_t)(chunk * 16 + bkv) * 4 + h) * 4096 + d * 64 + fb;
    #pragma unroll
    for (int j = 0; j < 4; j++)
      *(float4*)&pb[j * 4] = *(float4*)&acc[h][j * 4];
  }
}

// ---------------- reduce partials over NCH_ chunks -> transposed split-bf16 osum ----------------
// osumb layout: [bn][plane][f][d] bf16, plane 0 = hi, plane 1 = lo (x - hi).
__global__ __launch_bounds__(256) void osum_reduce_t(const float* __restrict__ part,
                                                     unsigned short* __restrict__ osumb){
  int bn = blockIdx.x;            // 64
  int tid = threadIdx.x;
  __shared__ float os[64][65];
  const float4* p4 = (const float4*)part;
  #pragma unroll
  for (int r = 0; r < 4; r++){
    int idx4 = r * 256 + tid;     // float4 index within this bn's 1024
    float4 s = {0.f, 0.f, 0.f, 0.f};
    #pragma unroll 8
    for (int c = 0; c < NCH_; c++){
      float4 v = p4[(size_t)c * 65536 + bn * 1024 + idx4];
      s.x += v.x; s.y += v.y; s.z += v.z; s.w += v.w;
    }
    int d = idx4 >> 4;            // (idx4*4)/64
    int f0 = (idx4 & 15) * 4;
    os[d][f0] = s.x; os[d][f0+1] = s.y; os[d][f0+2] = s.z; os[d][f0+3] = s.w;
  }
  __syncthreads();
  int f = tid >> 2, d0 = (tid & 3) * 16;
  unsigned short hi[16], lo[16];
  #pragma unroll
  for (int j = 0; j < 16; j++){
    float x = os[d0 + j][f];
    unsigned short h = f2bf(x);
    hi[j] = h;
    lo[j] = f2bf(x - bf2f(h));
  }
  unsigned short* oh = osumb + ((size_t)bn * 2) * 4096 + (size_t)f * 64 + d0;
  unsigned short* ol = oh + 4096;
  *(short8*)(oh)     = *(const short8*)(hi);
  *(short8*)(oh + 8) = *(const short8*)(hi + 8);
  *(short8*)(ol)     = *(const short8*)(lo);
  *(short8*)(ol + 8) = *(const short8*)(lo + 8);
}

// ---------------- ctx via MFMA: R = Qk @ osum (hi+lo), ctx = bf16(Xphi * R) ----------------
__global__ __launch_bounds__(256) void ctx_mfma(const unsigned short* __restrict__ Qk,
                                                const unsigned short* __restrict__ osumb,
                                                const float* __restrict__ Xphi,
                                                unsigned short* __restrict__ ctx){
  int bn = blockIdx.x, sc = blockIdx.y;   // 64 x 16
  int b = bn >> 5, n = bn & 31;
  int tid = threadIdx.x;
  int w = tid >> 6, lane = tid & 63;
  int l15 = lane & 15, quad = lane >> 4;

  const unsigned short* obase = osumb + ((size_t)bn * 2) * 4096;
  short8 bh[4][2], bl[4][2];
  #pragma unroll
  for (int nf = 0; nf < 4; nf++){
    int f = nf * 16 + l15;
    #pragma unroll
    for (int kh = 0; kh < 2; kh++){
      bh[nf][kh] = *(const short8*)(obase + (size_t)f * 64 + kh * 32 + quad * 8);
      bl[nf][kh] = *(const short8*)(obase + 4096 + (size_t)f * 64 + kh * 32 + quad * 8);
    }
  }

  int s0 = sc * 256 + w * 64;
  const unsigned short* qbase = Qk + ((size_t)bn * S_ + s0) * HD_;
  floatx4 acc[4][4] = {};
  #pragma unroll
  for (int m = 0; m < 4; m++){
    short8 a0 = *(const short8*)(qbase + (size_t)(m * 16 + l15) * HD_ + quad * 8);
    short8 a1 = *(const short8*)(qbase + (size_t)(m * 16 + l15) * HD_ + 32 + quad * 8);
    #pragma unroll
    for (int nf = 0; nf < 4; nf++){
      acc[m][nf] = __builtin_amdgcn_mfma_f32_16x16x32_bf16(a0, bh[nf][0], acc[m][nf], 0, 0, 0);
      acc[m][nf] = __builtin_amdgcn_mfma_f32_16x16x32_bf16(a1, bh[nf][1], acc[m][nf], 0, 0, 0);
      acc[m][nf] = __builtin_amdgcn_mfma_f32_16x16x32_bf16(a0, bl[nf][0], acc[m][nf], 0, 0, 0);
      acc[m][nf] = __builtin_amdgcn_mfma_f32_16x16x32_bf16(a1, bl[nf][1], acc[m][nf], 0, 0, 0);
    }
  }

  // epilogue: C/D mapping col=l15, row=quad*4+r; multiply by Xphi, store bf16
  #pragma unroll
  for (int m = 0; m < 4; m++){
    #pragma unroll
    for (int r = 0; r < 4; r++){
      int s = s0 + m * 16 + quad * 4 + r;
      const float* xp = Xphi + ((size_t)(b * S_ + s) * NH_ + n) * HD_;
      unsigned short* cp = ctx + (size_t)(b * S_ + s) * HID_ + n * HD_;
      #pragma unroll
      for (int nf = 0; nf < 4; nf++){
        int f = nf * 16 + l15;
        cp[f] = f2bf(xp[f] * acc[m][nf][r]);
      }
    }
  }
}

extern "C" void kernel_launch(void* const* d_in, const int* in_sizes, int n_in,
                              void* d_out, int out_size, void* d_ws, size_t ws_size,
                              hipStream_t stream) {
  const float* hs   = (const float*)d_in[0];
  const float* Wq   = (const float*)d_in[1];
  const float* Wk   = (const float*)d_in[2];
  const float* Wv   = (const float*)d_in[3];
  const float* Wphi = (const float*)d_in[4];
  const float* Wo   = (const float*)d_in[5];
  float* out = (float*)d_out;

  char* ws = (char*)d_ws;
  const size_t M = (size_t)B_ * S_;          // 8192
  size_t off = 0;
  auto alloc = [&](size_t bytes){ size_t o = off; off += (bytes + 255) & ~(size_t)255; return o; };

  size_t off_hsb   = alloc(M * HID_ * 2);                 // 32MB bf16
  size_t off_wqt   = alloc((size_t)HID_ * HID_ * 2);      // 8MB
  size_t off_wkvt  = alloc((size_t)HID_ * 1024 * 2);      // 4MB  [Wk^T; Wv^T]
  size_t off_wpt   = alloc((size_t)HID_ * HID_ * 2);      // 8MB
  size_t off_wot   = alloc((size_t)HID_ * HID_ * 2);      // 8MB
  size_t off_qlin  = alloc(M * HID_ * 4);                 // 64MB fp32 (Xphi later; osum partials between)
  size_t off_kvlin = alloc(M * 1024 * 4);                 // 32MB fp32 fused K|V
  size_t off_qk    = alloc(M * HID_ * 2);                 // 32MB bf16 [B,NH,S,D]
  size_t off_kk    = alloc(M * 512 * 2);                  // 8MB  bf16 [B,NKV,S,D]
  size_t off_qg    = alloc(64 * 64 * 4);
  size_t off_alph  = alloc((size_t)B_ * NH_ * S_ * 4);    // 1MB
  size_t off_osumb = alloc((size_t)64 * 2 * 4096 * 2);    // 1MB split-bf16 osum^T
  size_t off_ctx   = off_kvlin;                           // reuse kvlin region (32MB bf16)
  size_t off_part  = off_qlin;                            // 32MB partials in dead qlin window
  (void)ws_size;

  unsigned short* hsb  = (unsigned short*)(ws + off_hsb);
  unsigned short* wqt  = (unsigned short*)(ws + off_wqt);
  unsigned short* wkvt = (unsigned short*)(ws + off_wkvt);
  unsigned short* wpt  = (unsigned short*)(ws + off_wpt);
  unsigned short* wot  = (unsigned short*)(ws + off_wot);
  float* qlin  = (float*)(ws + off_qlin);
  float* kvlin = (float*)(ws + off_kvlin);
  unsigned short* qk = (unsigned short*)(ws + off_qk);
  unsigned short* kk = (unsigned short*)(ws + off_kk);
  float* qg   = (float*)(ws + off_qg);
  float* alph = (float*)(ws + off_alph);
  unsigned short* osumb = (unsigned short*)(ws + off_osumb);
  float* part = (float*)(ws + off_part);
  unsigned short* ctx = (unsigned short*)(ws + off_ctx);

  // 1. hs -> bf16
  conv_bf16<<<(int)(M * HID_ / 4 / 256), 256, 0, stream>>>(hs, hsb, (int)(M * HID_ / 4));
  // 2. weight transposes (W[K,N] -> Wt[N,K] bf16); Wk/Wv concatenated
  transpose_to_bf16<<<dim3(HID_/32, HID_/32), dim3(32,8), 0, stream>>>(Wq, wqt, HID_, HID_);
  transpose_to_bf16<<<dim3(512/32,  HID_/32), dim3(32,8), 0, stream>>>(Wk, wkvt, HID_, 512);
  transpose_to_bf16<<<dim3(512/32,  HID_/32), dim3(32,8), 0, stream>>>(Wv, wkvt + (size_t)512 * HID_, HID_, 512);
  transpose_to_bf16<<<dim3(HID_/32, HID_/32), dim3(32,8), 0, stream>>>(Wphi, wpt, HID_, HID_);
  transpose_to_bf16<<<dim3(HID_/32, HID_/32), dim3(32,8), 0, stream>>>(Wo, wot, HID_, HID_);
  // 3-4. Q projection + fused KV projection (256x256-tile pipelined GEMM)
  gemm256<<<dim3(HID_/256, M/256), 512, 0, stream>>>(hsb, wqt, qlin, (int)M, HID_, HID_);
  gemm256<<<dim3(1024/256, M/256), 512, 0, stream>>>(hsb, wkvt, kvlin, (int)M, 1024, HID_);
  // 5-6. RoPE + kappa (+ layout to [B,H,S,D])
  rope_kappa_q<<<(int)(M * NH_ * 32 / 256), 256, 0, stream>>>(qlin, qk);
  rope_kappa_k<<<(int)(M * NKV_ * 32 / 256), 256, 0, stream>>>(kvlin, kk);
  // 7. global query (split-S + atomics)
  hipMemsetAsync(qg, 0, 64 * 64 * 4, stream);
  qg_mean<<<dim3(B_ * NH_, S_ / 256), 256, 0, stream>>>(qk, qg);
  // 8. logits + softmax * S
  logits_kernel<<<dim3(B_ * NH_, S_ / 256), 256, 0, stream>>>(kk, qg, alph);
  softmax_kernel<<<B_ * NH_, 256, 0, stream>>>(alph, alph);
  // 9. outer_sum (partials into dead qlin region) + transposed split-bf16 reduce
  outer_sum_kernel<<<dim3(B_ * NKV_, NCH_), 256, 0, stream>>>(kk, kvlin, alph, part);
  osum_reduce_t<<<64, 256, 0, stream>>>(part, osumb);
  // 10. Xphi projection (reuses qlin region — partials dead after reduce)
  gemm256<<<dim3(HID_/256, M/256), 512, 0, stream>>>(hsb, wpt, qlin, (int)M, HID_, HID_);
  // 11. ctx = Xphi * (Qk @ osum)  -> bf16 (MFMA, reuses kvlin region)
  ctx_mfma<<<dim3(B_ * NH_, S_ / 64 / 4), 256, 0, stream>>>(qk, osumb, qlin, ctx);
  // 12. out = ctx @ Wo
  gemm256<<<dim3(HID_/256, M/256), 512, 0, stream>>>(ctx, wot, out, (int)M, HID_, HID_);
}

// Round 4
// 552.653 us; speedup vs baseline: 1.3351x; 1.3351x over previous
//
#include <hip/hip_runtime.h>
#include <hip/hip_bf16.h>

#define B_ 2
#define S_ 4096
#define HID_ 2048
#define NH_ 32
#define NKV_ 8
#define HD_ 64
#define GROUPS_ 4
#define NCH_ 32   // outer_sum S-chunks

typedef short short8 __attribute__((ext_vector_type(8)));
typedef float floatx4 __attribute__((ext_vector_type(4)));

__device__ __forceinline__ float bf2f(unsigned short u){
  union { unsigned int i; float f; } v; v.i = ((unsigned int)u) << 16; return v.f;
}
__device__ __forceinline__ unsigned short f2bf(float f){
  union { float f; unsigned int i; } v; v.f = f;
  unsigned int i = v.i;
  unsigned int r = (i + 0x7fffu + ((i >> 16) & 1u)) >> 16;  // RNE
  return (unsigned short)r;
}

// async global->LDS, 16B per lane, LDS dest = wave-uniform base + lane*16
__device__ __forceinline__ void async_copy16(unsigned short* lds, const unsigned short* g){
  __builtin_amdgcn_global_load_lds((const __attribute__((address_space(1))) void*)g,
                                   (__attribute__((address_space(3))) void*)lds,
                                   16, 0, 0);
}

// ---------------- fp32 -> bf16 bulk convert (hidden_states) ----------------
__global__ void conv_bf16(const float* __restrict__ x, unsigned short* __restrict__ y, int n4){
  int i = blockIdx.x * 256 + threadIdx.x;
  if (i < n4){
    float4 v = ((const float4*)x)[i];
    ushort4 o;
    o.x = f2bf(v.x); o.y = f2bf(v.y); o.z = f2bf(v.z); o.w = f2bf(v.w);
    ((ushort4*)y)[i] = o;
  }
}

// ---------------- W[K,N] fp32 -> Wt[N,K] bf16 (tiled transpose) ----------------
__global__ void transpose_to_bf16(const float* __restrict__ W, unsigned short* __restrict__ Wt,
                                  int K, int N){
  __shared__ float tile[32][33];
  int n0 = blockIdx.x * 32, k0 = blockIdx.y * 32;
  int tx = threadIdx.x, ty = threadIdx.y;   // 32 x 8
  #pragma unroll
  for (int j = 0; j < 4; j++)
    tile[ty + j*8][tx] = W[(size_t)(k0 + ty + j*8) * N + n0 + tx];
  __syncthreads();
  #pragma unroll
  for (int j = 0; j < 4; j++)
    Wt[(size_t)(n0 + ty + j*8) * K + k0 + tx] = f2bf(tile[tx][ty + j*8]);
}

// ---------------- 256x256-tile 8-phase GEMM: C = A[M,K]bf16 @ Bt[N,K]^T bf16 ----------------
// R1-proven schedule (78 us @ M=8192,N=2048,K=2048). cbf16: epilogue stores bf16 (else fp32).
#define GTILE 16384   // 256*64 bf16 elements per operand per buffer

__global__ __launch_bounds__(512, 2) void gemm256(
    const unsigned short* __restrict__ A, const unsigned short* __restrict__ Bt,
    void* __restrict__ Cv, int M, int N, int K, int cbf16)
{
  __shared__ __align__(16) unsigned short As[2 * GTILE];
  __shared__ __align__(16) unsigned short Bs[2 * GTILE];

  const int tid = threadIdx.x;
  const int w = tid >> 6, lane = tid & 63;
  const int wr = w >> 2, wc = w & 3;
  const int l15 = lane & 15, quad = lane >> 4;

  // bijective XCD-aware swizzle (nwg % 8 == 0 for all shapes here)
  const int nbx = N >> 8;
  int flat = blockIdx.y * nbx + blockIdx.x;
  int nwg  = nbx * (M >> 8);
  int cpx  = nwg >> 3;
  int swz  = (flat & 7) * cpx + (flat >> 3);
  int bx = swz % nbx, by = swz / nbx;
  const int m0 = by << 8, n0 = bx << 8;

  // ---- staging addressing (per wave-call: 64 lanes x 16B = 512 shorts linear in LDS) ----
  const int srow = (w << 3) + (lane >> 3);          // row 0..63 within a 64-row call
  const int scc  = (lane & 7) ^ (lane >> 3);        // swizzled 16B chunk within 128B row
  const unsigned short* gA = A  + (size_t)(m0 + srow) * K + scc * 8;
  const unsigned short* gB = Bt + (size_t)(n0 + srow) * K + scc * 8;
  const size_t rs64  = (size_t)64  * K;             // second-call row offset
  const size_t rs128 = (size_t)128 * K;             // half-tile row offset
  unsigned short* lA0 = As + (w << 9);
  unsigned short* lB0 = Bs + (w << 9);

#define STAGE_A(bsel, h, t) do { \
    unsigned short* _d = lA0 + (bsel) * GTILE + (h) * 8192; \
    const unsigned short* _g = gA + (size_t)(h) * rs128 + (size_t)(t) * 64; \
    async_copy16(_d, _g); \
    async_copy16(_d + 4096, _g + rs64); \
  } while (0)
#define STAGE_B(bsel, h, t) do { \
    unsigned short* _d = lB0 + (bsel) * GTILE + (h) * 8192; \
    const unsigned short* _g = gB + (size_t)(h) * rs128 + (size_t)(t) * 64; \
    async_copy16(_d, _g); \
    async_copy16(_d + 4096, _g + rs64); \
  } while (0)
#define SCHED0 __builtin_amdgcn_sched_barrier(0)

  // ---- fragment read offsets (shorts): row*64 + ((kchunk ^ (row&7))<<3); row&7 == lane&7 ----
  const int ks0  = ((quad     ^ (lane & 7)) << 3);
  const int ks1  = (((4+quad) ^ (lane & 7)) << 3);
  const int arow = (wr * 128 + l15) * 64;
  const int brow = (wc * 64  + l15) * 64;

  floatx4 acc[8][4] = {};
  short8 af[8][2], bfr[4][2];

  const int nt = K >> 6;

  // ---- prologue: stage tile0 (buf0) and tile1 (buf1); allow tile1's 8 loads in flight ----
  STAGE_A(0, 0, 0); STAGE_A(0, 1, 0); STAGE_B(0, 0, 0); STAGE_B(0, 1, 0);
  if (nt > 1){
    STAGE_A(1, 0, 1); STAGE_A(1, 1, 1); STAGE_B(1, 0, 1); STAGE_B(1, 1, 1);
    asm volatile("s_waitcnt vmcnt(8)" ::: "memory");
  } else {
    asm volatile("s_waitcnt vmcnt(0)" ::: "memory");
  }
  SCHED0;
  __builtin_amdgcn_s_barrier();
  SCHED0;

  for (int T = 0; T < nt; ++T){
    const int cb = T & 1;
    const unsigned short* Ab = As + cb * GTILE;
    const unsigned short* Bb = Bs + cb * GTILE;

    // ================= phase 0 =================
    #pragma unroll
    for (int m = 0; m < 4; ++m){
      af[m][0] = *(const short8*)(Ab + arow + m * 1024 + ks0);
      af[m][1] = *(const short8*)(Ab + arow + m * 1024 + ks1);
    }
    #pragma unroll
    for (int n = 0; n < 2; ++n){
      bfr[n][0] = *(const short8*)(Bb + brow + n * 1024 + ks0);
      bfr[n][1] = *(const short8*)(Bb + brow + n * 1024 + ks1);
    }
    SCHED0; __builtin_amdgcn_s_barrier(); SCHED0;
    __builtin_amdgcn_s_setprio(1);
    #pragma unroll
    for (int m = 0; m < 4; ++m)
      #pragma unroll
      for (int n = 0; n < 2; ++n){
        acc[m][n] = __builtin_amdgcn_mfma_f32_16x16x32_bf16(af[m][0], bfr[n][0], acc[m][n], 0, 0, 0);
        acc[m][n] = __builtin_amdgcn_mfma_f32_16x16x32_bf16(af[m][1], bfr[n][1], acc[m][n], 0, 0, 0);
      }
    __builtin_amdgcn_s_setprio(0);
    SCHED0; __builtin_amdgcn_s_barrier(); SCHED0;

    // ================= phase 1 =================
    #pragma unroll
    for (int m = 0; m < 4; ++m){
      af[4+m][0] = *(const short8*)(Ab + arow + (4+m) * 1024 + ks0);
      af[4+m][1] = *(const short8*)(Ab + arow + (4+m) * 1024 + ks1);
    }
    #pragma unroll
    for (int n = 0; n < 2; ++n){
      bfr[2+n][0] = *(const short8*)(Bb + brow + (2+n) * 1024 + ks0);
      bfr[2+n][1] = *(const short8*)(Bb + brow + (2+n) * 1024 + ks1);
    }
    SCHED0; __builtin_amdgcn_s_barrier(); SCHED0;
    __builtin_amdgcn_s_setprio(1);
    #pragma unroll
    for (int m = 0; m < 4; ++m)
      #pragma unroll
      for (int n = 0; n < 2; ++n){
        acc[m][2+n] = __builtin_amdgcn_mfma_f32_16x16x32_bf16(af[m][0], bfr[2+n][0], acc[m][2+n], 0, 0, 0);
        acc[m][2+n] = __builtin_amdgcn_mfma_f32_16x16x32_bf16(af[m][1], bfr[2+n][1], acc[m][2+n], 0, 0, 0);
      }
    __builtin_amdgcn_s_setprio(0);
    SCHED0; __builtin_amdgcn_s_barrier(); SCHED0;

    // ================= phase 2 =================
    if (T + 2 < nt){ STAGE_A(cb, 0, T + 2); STAGE_A(cb, 1, T + 2); }
    SCHED0; __builtin_amdgcn_s_barrier(); SCHED0;
    __builtin_amdgcn_s_setprio(1);
    #pragma unroll
    for (int m = 0; m < 4; ++m)
      #pragma unroll
      for (int n = 0; n < 2; ++n){
        acc[4+m][n] = __builtin_amdgcn_mfma_f32_16x16x32_bf16(af[4+m][0], bfr[n][0], acc[4+m][n], 0, 0, 0);
        acc[4+m][n] = __builtin_amdgcn_mfma_f32_16x16x32_bf16(af[4+m][1], bfr[n][1], acc[4+m][n], 0, 0, 0);
      }
    __builtin_amdgcn_s_setprio(0);
    SCHED0; __builtin_amdgcn_s_barrier(); SCHED0;

    // ================= phase 3 =================
    if (T + 2 < nt){
      STAGE_B(cb, 0, T + 2); STAGE_B(cb, 1, T + 2);
      asm volatile("s_waitcnt vmcnt(8)" ::: "memory");   // tile T+1 landed; T+2's 8 stay in flight
    } else {
      asm volatile("s_waitcnt vmcnt(0)" ::: "memory");   // epilogue drain
    }
    SCHED0; __builtin_amdgcn_s_barrier(); SCHED0;
    __builtin_amdgcn_s_setprio(1);
    #pragma unroll
    for (int m = 0; m < 4; ++m)
      #pragma unroll
      for (int n = 0; n < 2; ++n){
        acc[4+m][2+n] = __builtin_amdgcn_mfma_f32_16x16x32_bf16(af[4+m][0], bfr[2+n][0], acc[4+m][2+n], 0, 0, 0);
        acc[4+m][2+n] = __builtin_amdgcn_mfma_f32_16x16x32_bf16(af[4+m][1], bfr[2+n][1], acc[4+m][2+n], 0, 0, 0);
      }
    __builtin_amdgcn_s_setprio(0);
    SCHED0; __builtin_amdgcn_s_barrier(); SCHED0;
  }

#undef STAGE_A
#undef STAGE_B
#undef SCHED0

  if (cbf16){
    unsigned short* Cb = (unsigned short*)Cv;
    #pragma unroll
    for (int mi = 0; mi < 8; ++mi){
      const int row = m0 + wr * 128 + mi * 16 + quad * 4;
      #pragma unroll
      for (int ni = 0; ni < 4; ++ni){
        const int col = n0 + wc * 64 + ni * 16 + l15;
        #pragma unroll
        for (int r = 0; r < 4; ++r)
          Cb[(size_t)(row + r) * N + col] = f2bf(acc[mi][ni][r]);
      }
    }
  } else {
    float* Cf = (float*)Cv;
    #pragma unroll
    for (int mi = 0; mi < 8; ++mi){
      const int row = m0 + wr * 128 + mi * 16 + quad * 4;
      #pragma unroll
      for (int ni = 0; ni < 4; ++ni){
        const int col = n0 + wc * 64 + ni * 16 + l15;
        #pragma unroll
        for (int r = 0; r < 4; ++r)
          Cf[(size_t)(row + r) * N + col] = acc[mi][ni][r];
      }
    }
  }
}

// ---------------- RoPE + kappa for Q: [B,S,NH,HD] bf16 -> [B,NH,S,HD] bf16 ----------------
__global__ void rope_kappa_q(const unsigned short* __restrict__ Qlin, unsigned short* __restrict__ Qk){
  int idx = blockIdx.x * 256 + threadIdx.x;    // B*S*NH*32 = 2^23 threads
  int i = idx & 31;
  int n = (idx >> 5) & (NH_ - 1);
  int s = (idx >> 10) & (S_ - 1);
  int b = idx >> 22;
  float invf = exp2f(-(float)i * (13.287712379549449f / 32.0f));  // 10000^(-i/32)
  float ang = (float)s * invf;
  float c = cosf(ang), sn = sinf(ang);
  size_t in_o = ((size_t)(b * S_ + s) * NH_ + n) * HD_;
  float x1 = bf2f(Qlin[in_o + i]);
  float x2 = bf2f(Qlin[in_o + i + 32]);
  float r1 = x1 * c - x2 * sn;
  float r2 = x2 * c + x1 * sn;
  r1 = r1 > 0.f ? r1 + 1.f : __expf(r1);
  r2 = r2 > 0.f ? r2 + 1.f : __expf(r2);
  size_t o = ((size_t)(b * NH_ + n) * S_ + s) * HD_;
  Qk[o + i] = f2bf(r1);
  Qk[o + i + 32] = f2bf(r2);
}

// ---------------- RoPE + kappa for K (fused KV layout [B,S,1024] bf16, K = cols 0..511) ----------------
__global__ void rope_kappa_k(const unsigned short* __restrict__ KVlin, unsigned short* __restrict__ Kk){
  int idx = blockIdx.x * 256 + threadIdx.x;    // B*S*NKV*32 = 2^21 threads
  int i = idx & 31;
  int kv = (idx >> 5) & (NKV_ - 1);
  int s = (idx >> 8) & (S_ - 1);
  int b = idx >> 20;
  float invf = exp2f(-(float)i * (13.287712379549449f / 32.0f));
  float ang = (float)s * invf;
  float c = cosf(ang), sn = sinf(ang);
  size_t in_o = (size_t)(b * S_ + s) * 1024 + kv * HD_;
  float x1 = bf2f(KVlin[in_o + i]);
  float x2 = bf2f(KVlin[in_o + i + 32]);
  float r1 = x1 * c - x2 * sn;
  float r2 = x2 * c + x1 * sn;
  r1 = r1 > 0.f ? r1 + 1.f : __expf(r1);
  r2 = r2 > 0.f ? r2 + 1.f : __expf(r2);
  size_t o = ((size_t)(b * NKV_ + kv) * S_ + s) * HD_;
  Kk[o + i] = f2bf(r1);
  Kk[o + i + 32] = f2bf(r2);
}

// ---------------- Qg[b,n,d] = mean_s Qk[b,n,s,d]  (split-S, atomics) ----------------
__global__ __launch_bounds__(256) void qg_mean(const unsigned short* __restrict__ Qk,
                                               float* __restrict__ Qg){
  int bn = blockIdx.x, chunk = blockIdx.y;     // 64 x 16
  int tid = threadIdx.x;
  int dgrp = tid & 7, sgrp = tid >> 3;         // 8 d-chunks x 32 s-rows
  const unsigned short* base = Qk + (size_t)bn * S_ * HD_
                             + (size_t)(chunk * 256 + sgrp) * HD_ + dgrp * 8;
  float acc[8] = {};
  #pragma unroll
  for (int i = 0; i < 8; i++){
    short8 v = *(const short8*)(base + (size_t)i * 32 * HD_);
    #pragma unroll
    for (int e = 0; e < 8; e++) acc[e] += bf2f((unsigned short)v[e]);
  }
  __shared__ float red[256][8];
  #pragma unroll
  for (int e = 0; e < 8; e++) red[tid][e] = acc[e];
  __syncthreads();
  if (tid < 64){
    int dg = tid >> 3, e = tid & 7;
    float s = 0.f;
    #pragma unroll
    for (int g = 0; g < 32; g++) s += red[g * 8 + dg][e];
    atomicAdd(&Qg[bn * 64 + tid], s * (1.0f / (float)S_));
  }
}

// ---------------- logits[b,n,s] = dot(Qg[b,n], Kk[b,kv,s]) ----------------
__global__ __launch_bounds__(256) void logits_kernel(const unsigned short* __restrict__ Kk,
                                                     const float* __restrict__ Qg,
                                                     float* __restrict__ logits){
  int bn = blockIdx.x, chunk = blockIdx.y;     // 64 x 16
  int b = bn / NH_, n = bn % NH_, kv = n / GROUPS_;
  int tid = threadIdx.x;
  __shared__ float qg[64];
  if (tid < 64) qg[tid] = Qg[bn * 64 + tid];
  __syncthreads();
  int s = chunk * 256 + tid;
  const unsigned short* row = Kk + ((size_t)(b * NKV_ + kv) * S_ + s) * HD_;
  float acc = 0.f;
  #pragma unroll
  for (int c = 0; c < 8; c++){
    short8 v = *(const short8*)(row + c * 8);
    #pragma unroll
    for (int e = 0; e < 8; e++) acc += qg[c * 8 + e] * bf2f((unsigned short)v[e]);
  }
  logits[(size_t)bn * S_ + s] = acc;
}

// ---------------- softmax * S over logits -> alpha (in place OK) ----------------
__global__ __launch_bounds__(256) void softmax_kernel(const float* __restrict__ logits,
                                                      float* __restrict__ alpha){
  int bn = blockIdx.x;
  int tid = threadIdx.x;
  float l[16];
  float mymax = -1e30f;
  #pragma unroll
  for (int j = 0; j < 16; j++){
    l[j] = logits[(size_t)bn * S_ + j * 256 + tid];
    mymax = fmaxf(mymax, l[j]);
  }
  __shared__ float red[256];
  red[tid] = mymax; __syncthreads();
  for (int st = 128; st > 0; st >>= 1){
    if (tid < st) red[tid] = fmaxf(red[tid], red[tid + st]);
    __syncthreads();
  }
  float gmax = red[0];
  __syncthreads();
  float mysum = 0.f;
  #pragma unroll
  for (int j = 0; j < 16; j++){ l[j] = __expf(l[j] - gmax); mysum += l[j]; }
  red[tid] = mysum; __syncthreads();
  for (int st = 128; st > 0; st >>= 1){
    if (tid < st) red[tid] += red[tid + st];
    __syncthreads();
  }
  float inv = (float)S_ / red[0];
  #pragma unroll
  for (int j = 0; j < 16; j++)
    alpha[(size_t)bn * S_ + j * 256 + tid] = l[j] * inv;
}

// ---------------- outer_sum: per (b,kv,chunk), all 4 GQA heads; V from bf16 KV cols 512.. ----------------
__global__ __launch_bounds__(256) void outer_sum_kernel(const unsigned short* __restrict__ Kk,
                                                        const unsigned short* __restrict__ KVlin,
                                                        const float* __restrict__ alpha,
                                                        float* __restrict__ part){
  int bkv = blockIdx.x, chunk = blockIdx.y;     // 16 x NCH_
  int b = bkv >> 3, kv = bkv & 7;
  int tid = threadIdx.x;
  int d = tid >> 2, fb = (tid & 3) * 16;
  __shared__ float ks[64][64];   // [si][d]
  __shared__ float vs[64][64];   // [si][f]
  __shared__ float as[4][64];    // [h][si]
  float acc[4][16] = {};
  const unsigned short* kb = Kk + (size_t)(b * NKV_ + kv) * S_ * HD_;
  const int SPC = S_ / NCH_;     // 128 s per chunk

  for (int t = 0; t < SPC / 64; t++){
    int ss = chunk * SPC + t * 64;
    // stage K and V tiles (64x64 bf16 each) with short4 loads
    #pragma unroll
    for (int jj = 0; jj < 4; jj++){
      int idx4 = jj * 256 + tid;          // 1024 short4 chunks per tile
      int si = idx4 >> 4, c4 = (idx4 & 15) * 4;
      ushort4 kv4 = *(const ushort4*)(kb + (size_t)(ss + si) * HD_ + c4);
      ks[si][c4]   = bf2f(kv4.x); ks[si][c4+1] = bf2f(kv4.y);
      ks[si][c4+2] = bf2f(kv4.z); ks[si][c4+3] = bf2f(kv4.w);
      ushort4 vv4 = *(const ushort4*)(KVlin + (size_t)(b * S_ + ss + si) * 1024 + 512 + kv * HD_ + c4);
      vs[si][c4]   = bf2f(vv4.x); vs[si][c4+1] = bf2f(vv4.y);
      vs[si][c4+2] = bf2f(vv4.z); vs[si][c4+3] = bf2f(vv4.w);
    }
    {
      int h = tid >> 6, si = tid & 63;
      as[h][si] = alpha[(size_t)(b * NH_ + kv * GROUPS_ + h) * S_ + ss + si];
    }
    __syncthreads();
    #pragma unroll 4
    for (int si = 0; si < 64; si++){
      float k = ks[si][d];
      float4 v0 = *(const float4*)&vs[si][fb];
      float4 v1 = *(const float4*)&vs[si][fb + 4];
      float4 v2 = *(const float4*)&vs[si][fb + 8];
      float4 v3 = *(const float4*)&vs[si][fb + 12];
      #pragma unroll
      for (int h = 0; h < 4; h++){
        float ak = as[h][si] * k;
        acc[h][0]  += ak * v0.x; acc[h][1]  += ak * v0.y; acc[h][2]  += ak * v0.z; acc[h][3]  += ak * v0.w;
        acc[h][4]  += ak * v1.x; acc[h][5]  += ak * v1.y; acc[h][6]  += ak * v1.z; acc[h][7]  += ak * v1.w;
        acc[h][8]  += ak * v2.x; acc[h][9]  += ak * v2.y; acc[h][10] += ak * v2.z; acc[h][11] += ak * v2.w;
        acc[h][12] += ak * v3.x; acc[h][13] += ak * v3.y; acc[h][14] += ak * v3.z; acc[h][15] += ak * v3.w;
      }
    }
    __syncthreads();
  }

  #pragma unroll
  for (int h = 0; h < 4; h++){
    float* pb = part + ((size_t)(chunk * 16 + bkv) * 4 + h) * 4096 + d * 64 + fb;
    #pragma unroll
    for (int j = 0; j < 4; j++)
      *(float4*)&pb[j * 4] = *(float4*)&acc[h][j * 4];
  }
}

// ---------------- reduce partials over NCH_ chunks -> transposed split-bf16 osum ----------------
// osumb layout: [bn][plane][f][d] bf16, plane 0 = hi, plane 1 = lo (x - hi).
__global__ __launch_bounds__(256) void osum_reduce_t(const float* __restrict__ part,
                                                     unsigned short* __restrict__ osumb){
  int bn = blockIdx.x;            // 64
  int tid = threadIdx.x;
  __shared__ float os[64][65];
  const float4* p4 = (const float4*)part;
  #pragma unroll
  for (int r = 0; r < 4; r++){
    int idx4 = r * 256 + tid;     // float4 index within this bn's 1024
    float4 s = {0.f, 0.f, 0.f, 0.f};
    #pragma unroll 8
    for (int c = 0; c < NCH_; c++){
      float4 v = p4[(size_t)c * 65536 + bn * 1024 + idx4];
      s.x += v.x; s.y += v.y; s.z += v.z; s.w += v.w;
    }
    int d = idx4 >> 4;            // (idx4*4)/64
    int f0 = (idx4 & 15) * 4;
    os[d][f0] = s.x; os[d][f0+1] = s.y; os[d][f0+2] = s.z; os[d][f0+3] = s.w;
  }
  __syncthreads();
  int f = tid >> 2, d0 = (tid & 3) * 16;
  unsigned short hi[16], lo[16];
  #pragma unroll
  for (int j = 0; j < 16; j++){
    float x = os[d0 + j][f];
    unsigned short h = f2bf(x);
    hi[j] = h;
    lo[j] = f2bf(x - bf2f(h));
  }
  unsigned short* oh = osumb + ((size_t)bn * 2) * 4096 + (size_t)f * 64 + d0;
  unsigned short* ol = oh + 4096;
  *(short8*)(oh)     = *(const short8*)(hi);
  *(short8*)(oh + 8) = *(const short8*)(hi + 8);
  *(short8*)(ol)     = *(const short8*)(lo);
  *(short8*)(ol + 8) = *(const short8*)(lo + 8);
}

// ---------------- ctx via MFMA: R = Qk @ osum (hi+lo), ctx = bf16(Xphi * R) ----------------
__global__ __launch_bounds__(256) void ctx_mfma(const unsigned short* __restrict__ Qk,
                                                const unsigned short* __restrict__ osumb,
                                                const unsigned short* __restrict__ Xphi,
                                                unsigned short* __restrict__ ctx){
  int bn = blockIdx.x, sc = blockIdx.y;   // 64 x 16
  int b = bn >> 5, n = bn & 31;
  int tid = threadIdx.x;
  int w = tid >> 6, lane = tid & 63;
  int l15 = lane & 15, quad = lane >> 4;

  const unsigned short* obase = osumb + ((size_t)bn * 2) * 4096;
  short8 bh[4][2], bl[4][2];
  #pragma unroll
  for (int nf = 0; nf < 4; nf++){
    int f = nf * 16 + l15;
    #pragma unroll
    for (int kh = 0; kh < 2; kh++){
      bh[nf][kh] = *(const short8*)(obase + (size_t)f * 64 + kh * 32 + quad * 8);
      bl[nf][kh] = *(const short8*)(obase + 4096 + (size_t)f * 64 + kh * 32 + quad * 8);
    }
  }

  int s0 = sc * 256 + w * 64;
  const unsigned short* qbase = Qk + ((size_t)bn * S_ + s0) * HD_;
  floatx4 acc[4][4] = {};
  #pragma unroll
  for (int m = 0; m < 4; m++){
    short8 a0 = *(const short8*)(qbase + (size_t)(m * 16 + l15) * HD_ + quad * 8);
    short8 a1 = *(const short8*)(qbase + (size_t)(m * 16 + l15) * HD_ + 32 + quad * 8);
    #pragma unroll
    for (int nf = 0; nf < 4; nf++){
      acc[m][nf] = __builtin_amdgcn_mfma_f32_16x16x32_bf16(a0, bh[nf][0], acc[m][nf], 0, 0, 0);
      acc[m][nf] = __builtin_amdgcn_mfma_f32_16x16x32_bf16(a1, bh[nf][1], acc[m][nf], 0, 0, 0);
      acc[m][nf] = __builtin_amdgcn_mfma_f32_16x16x32_bf16(a0, bl[nf][0], acc[m][nf], 0, 0, 0);
      acc[m][nf] = __builtin_amdgcn_mfma_f32_16x16x32_bf16(a1, bl[nf][1], acc[m][nf], 0, 0, 0);
    }
  }

  // epilogue: C/D mapping col=l15, row=quad*4+r; multiply by Xphi (bf16), store bf16
  #pragma unroll
  for (int m = 0; m < 4; m++){
    #pragma unroll
    for (int r = 0; r < 4; r++){
      int s = s0 + m * 16 + quad * 4 + r;
      const unsigned short* xp = Xphi + ((size_t)(b * S_ + s) * NH_ + n) * HD_;
      unsigned short* cp = ctx + (size_t)(b * S_ + s) * HID_ + n * HD_;
      #pragma unroll
      for (int nf = 0; nf < 4; nf++){
        int f = nf * 16 + l15;
        cp[f] = f2bf(bf2f(xp[f]) * acc[m][nf][r]);
      }
    }
  }
}

extern "C" void kernel_launch(void* const* d_in, const int* in_sizes, int n_in,
                              void* d_out, int out_size, void* d_ws, size_t ws_size,
                              hipStream_t stream) {
  const float* hs   = (const float*)d_in[0];
  const float* Wq   = (const float*)d_in[1];
  const float* Wk   = (const float*)d_in[2];
  const float* Wv   = (const float*)d_in[3];
  const float* Wphi = (const float*)d_in[4];
  const float* Wo   = (const float*)d_in[5];
  float* out = (float*)d_out;

  char* ws = (char*)d_ws;
  const size_t M = (size_t)B_ * S_;          // 8192
  size_t off = 0;
  auto alloc = [&](size_t bytes){ size_t o = off; off += (bytes + 255) & ~(size_t)255; return o; };

  size_t off_hsb   = alloc(M * HID_ * 2);                 // 32MB bf16
  size_t off_wqt   = alloc((size_t)HID_ * HID_ * 2);      // 8MB
  size_t off_wkvt  = alloc((size_t)HID_ * 1024 * 2);      // 4MB  [Wk^T; Wv^T]
  size_t off_wpt   = alloc((size_t)HID_ * HID_ * 2);      // 8MB
  size_t off_wot   = alloc((size_t)HID_ * HID_ * 2);      // 8MB
  size_t off_qlin  = alloc(M * HID_ * 2);                 // 32MB bf16 (Qlin; later part fp32 32MB; later Xphi bf16)
  size_t off_kvlin = alloc(M * 1024 * 2);                 // 16MB bf16 fused K|V
  size_t off_qk    = alloc(M * HID_ * 2);                 // 32MB bf16 [B,NH,S,D]
  size_t off_kk    = alloc(M * 512 * 2);                  // 8MB  bf16 [B,NKV,S,D]
  size_t off_qg    = alloc(64 * 64 * 4);
  size_t off_alph  = alloc((size_t)B_ * NH_ * S_ * 4);    // 1MB
  size_t off_osumb = alloc((size_t)64 * 2 * 4096 * 2);    // 1MB split-bf16 osum^T
  size_t off_ctx   = alloc(M * HID_ * 2);                 // 32MB bf16
  size_t off_part  = off_qlin;                            // 32MB fp32 partials in dead qlin window
  (void)ws_size;

  unsigned short* hsb  = (unsigned short*)(ws + off_hsb);
  unsigned short* wqt  = (unsigned short*)(ws + off_wqt);
  unsigned short* wkvt = (unsigned short*)(ws + off_wkvt);
  unsigned short* wpt  = (unsigned short*)(ws + off_wpt);
  unsigned short* wot  = (unsigned short*)(ws + off_wot);
  unsigned short* qlinb  = (unsigned short*)(ws + off_qlin);   // Qlin bf16, later Xphi bf16
  unsigned short* kvlinb = (unsigned short*)(ws + off_kvlin);
  unsigned short* qk = (unsigned short*)(ws + off_qk);
  unsigned short* kk = (unsigned short*)(ws + off_kk);
  float* qg   = (float*)(ws + off_qg);
  float* alph = (float*)(ws + off_alph);
  unsigned short* osumb = (unsigned short*)(ws + off_osumb);
  float* part = (float*)(ws + off_part);
  unsigned short* ctx = (unsigned short*)(ws + off_ctx);

  // 1. hs -> bf16
  conv_bf16<<<(int)(M * HID_ / 4 / 256), 256, 0, stream>>>(hs, hsb, (int)(M * HID_ / 4));
  // 2. weight transposes (W[K,N] -> Wt[N,K] bf16); Wk/Wv concatenated
  transpose_to_bf16<<<dim3(HID_/32, HID_/32), dim3(32,8), 0, stream>>>(Wq, wqt, HID_, HID_);
  transpose_to_bf16<<<dim3(512/32,  HID_/32), dim3(32,8), 0, stream>>>(Wk, wkvt, HID_, 512);
  transpose_to_bf16<<<dim3(512/32,  HID_/32), dim3(32,8), 0, stream>>>(Wv, wkvt + (size_t)512 * HID_, HID_, 512);
  transpose_to_bf16<<<dim3(HID_/32, HID_/32), dim3(32,8), 0, stream>>>(Wphi, wpt, HID_, HID_);
  transpose_to_bf16<<<dim3(HID_/32, HID_/32), dim3(32,8), 0, stream>>>(Wo, wot, HID_, HID_);
  // 3-4. Q projection + fused KV projection (bf16 C)
  gemm256<<<dim3(HID_/256, M/256), 512, 0, stream>>>(hsb, wqt, qlinb, (int)M, HID_, HID_, 1);
  gemm256<<<dim3(1024/256, M/256), 512, 0, stream>>>(hsb, wkvt, kvlinb, (int)M, 1024, HID_, 1);
  // 5-6. RoPE + kappa (+ layout to [B,H,S,D])
  rope_kappa_q<<<(int)(M * NH_ * 32 / 256), 256, 0, stream>>>(qlinb, qk);
  rope_kappa_k<<<(int)(M * NKV_ * 32 / 256), 256, 0, stream>>>(kvlinb, kk);
  // 7. global query (split-S + atomics)
  hipMemsetAsync(qg, 0, 64 * 64 * 4, stream);
  qg_mean<<<dim3(B_ * NH_, S_ / 256), 256, 0, stream>>>(qk, qg);
  // 8. logits + softmax * S
  logits_kernel<<<dim3(B_ * NH_, S_ / 256), 256, 0, stream>>>(kk, qg, alph);
  softmax_kernel<<<B_ * NH_, 256, 0, stream>>>(alph, alph);
  // 9. outer_sum (partials into dead qlin region) + transposed split-bf16 reduce
  outer_sum_kernel<<<dim3(B_ * NKV_, NCH_), 256, 0, stream>>>(kk, kvlinb, alph, part);
  osum_reduce_t<<<64, 256, 0, stream>>>(part, osumb);
  // 10. Xphi projection (bf16 C into qlin region — partials dead after reduce)
  gemm256<<<dim3(HID_/256, M/256), 512, 0, stream>>>(hsb, wpt, qlinb, (int)M, HID_, HID_, 1);
  // 11. ctx = Xphi * (Qk @ osum)  -> bf16 (MFMA)
  ctx_mfma<<<dim3(B_ * NH_, S_ / 64 / 4), 256, 0, stream>>>(qk, osumb, qlinb, ctx);
  // 12. out = ctx @ Wo (fp32 C)
  gemm256<<<dim3(HID_/256, M/256), 512, 0, stream>>>(ctx, wot, out, (int)M, HID_, HID_, 0);
}

// Round 5
// 544.991 us; speedup vs baseline: 1.3539x; 1.0141x over previous
//
#include <hip/hip_runtime.h>
#include <hip/hip_bf16.h>

#define B_ 2
#define S_ 4096
#define HID_ 2048
#define NH_ 32
#define NKV_ 8
#define HD_ 64
#define GROUPS_ 4
#define NCH_ 32   // outer_sum S-chunks
#define NLIN_ 5120  // fused projection width: Q 0..2047 | K 2048..2559 | V 2560..3071 | phi 3072..5119

typedef short short8 __attribute__((ext_vector_type(8)));
typedef float floatx4 __attribute__((ext_vector_type(4)));

__device__ __forceinline__ float bf2f(unsigned short u){
  union { unsigned int i; float f; } v; v.i = ((unsigned int)u) << 16; return v.f;
}
__device__ __forceinline__ unsigned short f2bf(float f){
  union { float f; unsigned int i; } v; v.f = f;
  unsigned int i = v.i;
  unsigned int r = (i + 0x7fffu + ((i >> 16) & 1u)) >> 16;  // RNE
  return (unsigned short)r;
}

// async global->LDS, 16B per lane, LDS dest = wave-uniform base + lane*16
__device__ __forceinline__ void async_copy16(unsigned short* lds, const unsigned short* g){
  __builtin_amdgcn_global_load_lds((const __attribute__((address_space(1))) void*)g,
                                   (__attribute__((address_space(3))) void*)lds,
                                   16, 0, 0);
}

// ---------------- fp32 -> bf16 bulk convert (hidden_states) ----------------
__global__ void conv_bf16(const float* __restrict__ x, unsigned short* __restrict__ y, int n4){
  int i = blockIdx.x * 256 + threadIdx.x;
  if (i < n4){
    float4 v = ((const float4*)x)[i];
    ushort4 o;
    o.x = f2bf(v.x); o.y = f2bf(v.y); o.z = f2bf(v.z); o.w = f2bf(v.w);
    ((ushort4*)y)[i] = o;
  }
}

// ---------------- W[K,N] fp32 -> Wt[N,K] bf16 (tiled transpose) ----------------
__global__ void transpose_to_bf16(const float* __restrict__ W, unsigned short* __restrict__ Wt,
                                  int K, int N){
  __shared__ float tile[32][33];
  int n0 = blockIdx.x * 32, k0 = blockIdx.y * 32;
  int tx = threadIdx.x, ty = threadIdx.y;   // 32 x 8
  #pragma unroll
  for (int j = 0; j < 4; j++)
    tile[ty + j*8][tx] = W[(size_t)(k0 + ty + j*8) * N + n0 + tx];
  __syncthreads();
  #pragma unroll
  for (int j = 0; j < 4; j++)
    Wt[(size_t)(n0 + ty + j*8) * K + k0 + tx] = f2bf(tile[tx][ty + j*8]);
}

// ---------------- 256x256-tile 8-phase GEMM: C = A[M,K]bf16 @ Bt[N,K]^T bf16 ----------------
// R1-proven schedule. MFMA bodies are k-outer: dependent MFMAs on the same acc are 8
// instructions apart (k-inner chained them back-to-back -> dep-latency bubbles).
// cbf16: epilogue stores bf16 (else fp32).
#define GTILE 16384   // 256*64 bf16 elements per operand per buffer

__global__ __launch_bounds__(512, 2) void gemm256(
    const unsigned short* __restrict__ A, const unsigned short* __restrict__ Bt,
    void* __restrict__ Cv, int M, int N, int K, int cbf16)
{
  __shared__ __align__(16) unsigned short As[2 * GTILE];
  __shared__ __align__(16) unsigned short Bs[2 * GTILE];

  const int tid = threadIdx.x;
  const int w = tid >> 6, lane = tid & 63;
  const int wr = w >> 2, wc = w & 3;
  const int l15 = lane & 15, quad = lane >> 4;

  // bijective XCD-aware swizzle (nwg % 8 == 0 for all shapes here)
  const int nbx = N >> 8;
  int flat = blockIdx.y * nbx + blockIdx.x;
  int nwg  = nbx * (M >> 8);
  int cpx  = nwg >> 3;
  int swz  = (flat & 7) * cpx + (flat >> 3);
  int bx = swz % nbx, by = swz / nbx;
  const int m0 = by << 8, n0 = bx << 8;

  // ---- staging addressing (per wave-call: 64 lanes x 16B = 512 shorts linear in LDS) ----
  const int srow = (w << 3) + (lane >> 3);          // row 0..63 within a 64-row call
  const int scc  = (lane & 7) ^ (lane >> 3);        // swizzled 16B chunk within 128B row
  const unsigned short* gA = A  + (size_t)(m0 + srow) * K + scc * 8;
  const unsigned short* gB = Bt + (size_t)(n0 + srow) * K + scc * 8;
  const size_t rs64  = (size_t)64  * K;             // second-call row offset
  const size_t rs128 = (size_t)128 * K;             // half-tile row offset
  unsigned short* lA0 = As + (w << 9);
  unsigned short* lB0 = Bs + (w << 9);

#define STAGE_A(bsel, h, t) do { \
    unsigned short* _d = lA0 + (bsel) * GTILE + (h) * 8192; \
    const unsigned short* _g = gA + (size_t)(h) * rs128 + (size_t)(t) * 64; \
    async_copy16(_d, _g); \
    async_copy16(_d + 4096, _g + rs64); \
  } while (0)
#define STAGE_B(bsel, h, t) do { \
    unsigned short* _d = lB0 + (bsel) * GTILE + (h) * 8192; \
    const unsigned short* _g = gB + (size_t)(h) * rs128 + (size_t)(t) * 64; \
    async_copy16(_d, _g); \
    async_copy16(_d + 4096, _g + rs64); \
  } while (0)
#define SCHED0 __builtin_amdgcn_sched_barrier(0)

  // ---- fragment read offsets (shorts): row*64 + ((kchunk ^ (row&7))<<3); row&7 == lane&7 ----
  const int ks0  = ((quad     ^ (lane & 7)) << 3);
  const int ks1  = (((4+quad) ^ (lane & 7)) << 3);
  const int arow = (wr * 128 + l15) * 64;
  const int brow = (wc * 64  + l15) * 64;

  floatx4 acc[8][4] = {};
  short8 af[8][2], bfr[4][2];

  const int nt = K >> 6;

  // ---- prologue: stage tile0 (buf0) and tile1 (buf1); allow tile1's 8 loads in flight ----
  STAGE_A(0, 0, 0); STAGE_A(0, 1, 0); STAGE_B(0, 0, 0); STAGE_B(0, 1, 0);
  if (nt > 1){
    STAGE_A(1, 0, 1); STAGE_A(1, 1, 1); STAGE_B(1, 0, 1); STAGE_B(1, 1, 1);
    asm volatile("s_waitcnt vmcnt(8)" ::: "memory");
  } else {
    asm volatile("s_waitcnt vmcnt(0)" ::: "memory");
  }
  SCHED0;
  __builtin_amdgcn_s_barrier();
  SCHED0;

  for (int T = 0; T < nt; ++T){
    const int cb = T & 1;
    const unsigned short* Ab = As + cb * GTILE;
    const unsigned short* Bb = Bs + cb * GTILE;

    // ================= phase 0: read af[0-3],bf[0-1] | MFMA Q00 =================
    #pragma unroll
    for (int m = 0; m < 4; ++m){
      af[m][0] = *(const short8*)(Ab + arow + m * 1024 + ks0);
      af[m][1] = *(const short8*)(Ab + arow + m * 1024 + ks1);
    }
    #pragma unroll
    for (int n = 0; n < 2; ++n){
      bfr[n][0] = *(const short8*)(Bb + brow + n * 1024 + ks0);
      bfr[n][1] = *(const short8*)(Bb + brow + n * 1024 + ks1);
    }
    SCHED0; __builtin_amdgcn_s_barrier(); SCHED0;
    __builtin_amdgcn_s_setprio(1);
    #pragma unroll
    for (int k = 0; k < 2; ++k)
      #pragma unroll
      for (int m = 0; m < 4; ++m)
        #pragma unroll
        for (int n = 0; n < 2; ++n)
          acc[m][n] = __builtin_amdgcn_mfma_f32_16x16x32_bf16(af[m][k], bfr[n][k], acc[m][n], 0, 0, 0);
    __builtin_amdgcn_s_setprio(0);
    SCHED0; __builtin_amdgcn_s_barrier(); SCHED0;

    // ================= phase 1: read af[4-7],bf[2-3] | MFMA Q01 =================
    #pragma unroll
    for (int m = 0; m < 4; ++m){
      af[4+m][0] = *(const short8*)(Ab + arow + (4+m) * 1024 + ks0);
      af[4+m][1] = *(const short8*)(Ab + arow + (4+m) * 1024 + ks1);
    }
    #pragma unroll
    for (int n = 0; n < 2; ++n){
      bfr[2+n][0] = *(const short8*)(Bb + brow + (2+n) * 1024 + ks0);
      bfr[2+n][1] = *(const short8*)(Bb + brow + (2+n) * 1024 + ks1);
    }
    SCHED0; __builtin_amdgcn_s_barrier(); SCHED0;
    __builtin_amdgcn_s_setprio(1);
    #pragma unroll
    for (int k = 0; k < 2; ++k)
      #pragma unroll
      for (int m = 0; m < 4; ++m)
        #pragma unroll
        for (int n = 0; n < 2; ++n)
          acc[m][2+n] = __builtin_amdgcn_mfma_f32_16x16x32_bf16(af[m][k], bfr[2+n][k], acc[m][2+n], 0, 0, 0);
    __builtin_amdgcn_s_setprio(0);
    SCHED0; __builtin_amdgcn_s_barrier(); SCHED0;

    // ================= phase 2: stage A(T+2) | MFMA Q10 =================
    if (T + 2 < nt){ STAGE_A(cb, 0, T + 2); STAGE_A(cb, 1, T + 2); }
    SCHED0; __builtin_amdgcn_s_barrier(); SCHED0;
    __builtin_amdgcn_s_setprio(1);
    #pragma unroll
    for (int k = 0; k < 2; ++k)
      #pragma unroll
      for (int m = 0; m < 4; ++m)
        #pragma unroll
        for (int n = 0; n < 2; ++n)
          acc[4+m][n] = __builtin_amdgcn_mfma_f32_16x16x32_bf16(af[4+m][k], bfr[n][k], acc[4+m][n], 0, 0, 0);
    __builtin_amdgcn_s_setprio(0);
    SCHED0; __builtin_amdgcn_s_barrier(); SCHED0;

    // ================= phase 3: stage B(T+2); vmcnt(8) | MFMA Q11 =================
    if (T + 2 < nt){
      STAGE_B(cb, 0, T + 2); STAGE_B(cb, 1, T + 2);
      asm volatile("s_waitcnt vmcnt(8)" ::: "memory");   // tile T+1 landed; T+2's 8 stay in flight
    } else {
      asm volatile("s_waitcnt vmcnt(0)" ::: "memory");   // epilogue drain
    }
    SCHED0; __builtin_amdgcn_s_barrier(); SCHED0;
    __builtin_amdgcn_s_setprio(1);
    #pragma unroll
    for (int k = 0; k < 2; ++k)
      #pragma unroll
      for (int m = 0; m < 4; ++m)
        #pragma unroll
        for (int n = 0; n < 2; ++n)
          acc[4+m][2+n] = __builtin_amdgcn_mfma_f32_16x16x32_bf16(af[4+m][k], bfr[2+n][k], acc[4+m][2+n], 0, 0, 0);
    __builtin_amdgcn_s_setprio(0);
    SCHED0; __builtin_amdgcn_s_barrier(); SCHED0;
  }

#undef STAGE_A
#undef STAGE_B
#undef SCHED0

  if (cbf16){
    unsigned short* Cb = (unsigned short*)Cv;
    #pragma unroll
    for (int mi = 0; mi < 8; ++mi){
      const int row = m0 + wr * 128 + mi * 16 + quad * 4;
      #pragma unroll
      for (int ni = 0; ni < 4; ++ni){
        const int col = n0 + wc * 64 + ni * 16 + l15;
        #pragma unroll
        for (int r = 0; r < 4; ++r)
          Cb[(size_t)(row + r) * N + col] = f2bf(acc[mi][ni][r]);
      }
    }
  } else {
    float* Cf = (float*)Cv;
    #pragma unroll
    for (int mi = 0; mi < 8; ++mi){
      const int row = m0 + wr * 128 + mi * 16 + quad * 4;
      #pragma unroll
      for (int ni = 0; ni < 4; ++ni){
        const int col = n0 + wc * 64 + ni * 16 + l15;
        #pragma unroll
        for (int r = 0; r < 4; ++r)
          Cf[(size_t)(row + r) * N + col] = acc[mi][ni][r];
      }
    }
  }
}

// ---------------- RoPE + kappa for Q: lin[B,S,5120] cols 0..2047 -> [B,NH,S,HD] bf16 ----------------
__global__ void rope_kappa_q(const unsigned short* __restrict__ lin, unsigned short* __restrict__ Qk){
  int idx = blockIdx.x * 256 + threadIdx.x;    // B*S*NH*32 = 2^23 threads
  int i = idx & 31;
  int n = (idx >> 5) & (NH_ - 1);
  int s = (idx >> 10) & (S_ - 1);
  int b = idx >> 22;
  float invf = exp2f(-(float)i * (13.287712379549449f / 32.0f));  // 10000^(-i/32)
  float ang = (float)s * invf;
  float c = cosf(ang), sn = sinf(ang);
  size_t in_o = (size_t)(b * S_ + s) * NLIN_ + n * HD_;
  float x1 = bf2f(lin[in_o + i]);
  float x2 = bf2f(lin[in_o + i + 32]);
  float r1 = x1 * c - x2 * sn;
  float r2 = x2 * c + x1 * sn;
  r1 = r1 > 0.f ? r1 + 1.f : __expf(r1);
  r2 = r2 > 0.f ? r2 + 1.f : __expf(r2);
  size_t o = ((size_t)(b * NH_ + n) * S_ + s) * HD_;
  Qk[o + i] = f2bf(r1);
  Qk[o + i + 32] = f2bf(r2);
}

// ---------------- RoPE + kappa for K: lin cols 2048..2559 -> [B,NKV,S,HD] bf16 ----------------
__global__ void rope_kappa_k(const unsigned short* __restrict__ lin, unsigned short* __restrict__ Kk){
  int idx = blockIdx.x * 256 + threadIdx.x;    // B*S*NKV*32 = 2^21 threads
  int i = idx & 31;
  int kv = (idx >> 5) & (NKV_ - 1);
  int s = (idx >> 8) & (S_ - 1);
  int b = idx >> 20;
  float invf = exp2f(-(float)i * (13.287712379549449f / 32.0f));
  float ang = (float)s * invf;
  float c = cosf(ang), sn = sinf(ang);
  size_t in_o = (size_t)(b * S_ + s) * NLIN_ + 2048 + kv * HD_;
  float x1 = bf2f(lin[in_o + i]);
  float x2 = bf2f(lin[in_o + i + 32]);
  float r1 = x1 * c - x2 * sn;
  float r2 = x2 * c + x1 * sn;
  r1 = r1 > 0.f ? r1 + 1.f : __expf(r1);
  r2 = r2 > 0.f ? r2 + 1.f : __expf(r2);
  size_t o = ((size_t)(b * NKV_ + kv) * S_ + s) * HD_;
  Kk[o + i] = f2bf(r1);
  Kk[o + i + 32] = f2bf(r2);
}

// ---------------- Qg[b,n,d] = mean_s Qk[b,n,s,d]  (split-S, atomics) ----------------
__global__ __launch_bounds__(256) void qg_mean(const unsigned short* __restrict__ Qk,
                                               float* __restrict__ Qg){
  int bn = blockIdx.x, chunk = blockIdx.y;     // 64 x 16
  int tid = threadIdx.x;
  int dgrp = tid & 7, sgrp = tid >> 3;         // 8 d-chunks x 32 s-rows
  const unsigned short* base = Qk + (size_t)bn * S_ * HD_
                             + (size_t)(chunk * 256 + sgrp) * HD_ + dgrp * 8;
  float acc[8] = {};
  #pragma unroll
  for (int i = 0; i < 8; i++){
    short8 v = *(const short8*)(base + (size_t)i * 32 * HD_);
    #pragma unroll
    for (int e = 0; e < 8; e++) acc[e] += bf2f((unsigned short)v[e]);
  }
  __shared__ float red[256][8];
  #pragma unroll
  for (int e = 0; e < 8; e++) red[tid][e] = acc[e];
  __syncthreads();
  if (tid < 64){
    int dg = tid >> 3, e = tid & 7;
    float s = 0.f;
    #pragma unroll
    for (int g = 0; g < 32; g++) s += red[g * 8 + dg][e];
    atomicAdd(&Qg[bn * 64 + tid], s * (1.0f / (float)S_));
  }
}

// ---------------- logits[b,n,s] = dot(Qg[b,n], Kk[b,kv,s]) ----------------
__global__ __launch_bounds__(256) void logits_kernel(const unsigned short* __restrict__ Kk,
                                                     const float* __restrict__ Qg,
                                                     float* __restrict__ logits){
  int bn = blockIdx.x, chunk = blockIdx.y;     // 64 x 16
  int b = bn / NH_, n = bn % NH_, kv = n / GROUPS_;
  int tid = threadIdx.x;
  __shared__ float qg[64];
  if (tid < 64) qg[tid] = Qg[bn * 64 + tid];
  __syncthreads();
  int s = chunk * 256 + tid;
  const unsigned short* row = Kk + ((size_t)(b * NKV_ + kv) * S_ + s) * HD_;
  float acc = 0.f;
  #pragma unroll
  for (int c = 0; c < 8; c++){
    short8 v = *(const short8*)(row + c * 8);
    #pragma unroll
    for (int e = 0; e < 8; e++) acc += qg[c * 8 + e] * bf2f((unsigned short)v[e]);
  }
  logits[(size_t)bn * S_ + s] = acc;
}

// ---------------- softmax * S over logits -> alpha (in place OK) ----------------
__global__ __launch_bounds__(256) void softmax_kernel(const float* __restrict__ logits,
                                                      float* __restrict__ alpha){
  int bn = blockIdx.x;
  int tid = threadIdx.x;
  float l[16];
  float mymax = -1e30f;
  #pragma unroll
  for (int j = 0; j < 16; j++){
    l[j] = logits[(size_t)bn * S_ + j * 256 + tid];
    mymax = fmaxf(mymax, l[j]);
  }
  __shared__ float red[256];
  red[tid] = mymax; __syncthreads();
  for (int st = 128; st > 0; st >>= 1){
    if (tid < st) red[tid] = fmaxf(red[tid], red[tid + st]);
    __syncthreads();
  }
  float gmax = red[0];
  __syncthreads();
  float mysum = 0.f;
  #pragma unroll
  for (int j = 0; j < 16; j++){ l[j] = __expf(l[j] - gmax); mysum += l[j]; }
  red[tid] = mysum; __syncthreads();
  for (int st = 128; st > 0; st >>= 1){
    if (tid < st) red[tid] += red[tid + st];
    __syncthreads();
  }
  float inv = (float)S_ / red[0];
  #pragma unroll
  for (int j = 0; j < 16; j++)
    alpha[(size_t)bn * S_ + j * 256 + tid] = l[j] * inv;
}

// ---------------- outer_sum: per (b,kv,chunk), all 4 GQA heads; V from lin cols 2560.. ----------------
__global__ __launch_bounds__(256) void outer_sum_kernel(const unsigned short* __restrict__ Kk,
                                                        const unsigned short* __restrict__ lin,
                                                        const float* __restrict__ alpha,
                                                        float* __restrict__ part){
  int bkv = blockIdx.x, chunk = blockIdx.y;     // 16 x NCH_
  int b = bkv >> 3, kv = bkv & 7;
  int tid = threadIdx.x;
  int d = tid >> 2, fb = (tid & 3) * 16;
  __shared__ float ks[64][64];   // [si][d]
  __shared__ float vs[64][64];   // [si][f]
  __shared__ float as[4][64];    // [h][si]
  float acc[4][16] = {};
  const unsigned short* kb = Kk + (size_t)(b * NKV_ + kv) * S_ * HD_;
  const int SPC = S_ / NCH_;     // 128 s per chunk

  for (int t = 0; t < SPC / 64; t++){
    int ss = chunk * SPC + t * 64;
    // stage K and V tiles (64x64 bf16 each) with short4 loads
    #pragma unroll
    for (int jj = 0; jj < 4; jj++){
      int idx4 = jj * 256 + tid;          // 1024 short4 chunks per tile
      int si = idx4 >> 4, c4 = (idx4 & 15) * 4;
      ushort4 kv4 = *(const ushort4*)(kb + (size_t)(ss + si) * HD_ + c4);
      ks[si][c4]   = bf2f(kv4.x); ks[si][c4+1] = bf2f(kv4.y);
      ks[si][c4+2] = bf2f(kv4.z); ks[si][c4+3] = bf2f(kv4.w);
      ushort4 vv4 = *(const ushort4*)(lin + (size_t)(b * S_ + ss + si) * NLIN_ + 2560 + kv * HD_ + c4);
      vs[si][c4]   = bf2f(vv4.x); vs[si][c4+1] = bf2f(vv4.y);
      vs[si][c4+2] = bf2f(vv4.z); vs[si][c4+3] = bf2f(vv4.w);
    }
    {
      int h = tid >> 6, si = tid & 63;
      as[h][si] = alpha[(size_t)(b * NH_ + kv * GROUPS_ + h) * S_ + ss + si];
    }
    __syncthreads();
    #pragma unroll 4
    for (int si = 0; si < 64; si++){
      float k = ks[si][d];
      float4 v0 = *(const float4*)&vs[si][fb];
      float4 v1 = *(const float4*)&vs[si][fb + 4];
      float4 v2 = *(const float4*)&vs[si][fb + 8];
      float4 v3 = *(const float4*)&vs[si][fb + 12];
      #pragma unroll
      for (int h = 0; h < 4; h++){
        float ak = as[h][si] * k;
        acc[h][0]  += ak * v0.x; acc[h][1]  += ak * v0.y; acc[h][2]  += ak * v0.z; acc[h][3]  += ak * v0.w;
        acc[h][4]  += ak * v1.x; acc[h][5]  += ak * v1.y; acc[h][6]  += ak * v1.z; acc[h][7]  += ak * v1.w;
        acc[h][8]  += ak * v2.x; acc[h][9]  += ak * v2.y; acc[h][10] += ak * v2.z; acc[h][11] += ak * v2.w;
        acc[h][12] += ak * v3.x; acc[h][13] += ak * v3.y; acc[h][14] += ak * v3.z; acc[h][15] += ak * v3.w;
      }
    }
    __syncthreads();
  }

  #pragma unroll
  for (int h = 0; h < 4; h++){
    float* pb = part + ((size_t)(chunk * 16 + bkv) * 4 + h) * 4096 + d * 64 + fb;
    #pragma unroll
    for (int j = 0; j < 4; j++)
      *(float4*)&pb[j * 4] = *(float4*)&acc[h][j * 4];
  }
}

// ---------------- reduce partials over NCH_ chunks -> transposed split-bf16 osum ----------------
// osumb layout: [bn][plane][f][d] bf16, plane 0 = hi, plane 1 = lo (x - hi).
__global__ __launch_bounds__(256) void osum_reduce_t(const float* __restrict__ part,
                                                     unsigned short* __restrict__ osumb){
  int bn = blockIdx.x;            // 64
  int tid = threadIdx.x;
  __shared__ float os[64][65];
  const float4* p4 = (const float4*)part;
  #pragma unroll
  for (int r = 0; r < 4; r++){
    int idx4 = r * 256 + tid;     // float4 index within this bn's 1024
    float4 s = {0.f, 0.f, 0.f, 0.f};
    #pragma unroll 8
    for (int c = 0; c < NCH_; c++){
      float4 v = p4[(size_t)c * 65536 + bn * 1024 + idx4];
      s.x += v.x; s.y += v.y; s.z += v.z; s.w += v.w;
    }
    int d = idx4 >> 4;            // (idx4*4)/64
    int f0 = (idx4 & 15) * 4;
    os[d][f0] = s.x; os[d][f0+1] = s.y; os[d][f0+2] = s.z; os[d][f0+3] = s.w;
  }
  __syncthreads();
  int f = tid >> 2, d0 = (tid & 3) * 16;
  unsigned short hi[16], lo[16];
  #pragma unroll
  for (int j = 0; j < 16; j++){
    float x = os[d0 + j][f];
    unsigned short h = f2bf(x);
    hi[j] = h;
    lo[j] = f2bf(x - bf2f(h));
  }
  unsigned short* oh = osumb + ((size_t)bn * 2) * 4096 + (size_t)f * 64 + d0;
  unsigned short* ol = oh + 4096;
  *(short8*)(oh)     = *(const short8*)(hi);
  *(short8*)(oh + 8) = *(const short8*)(hi + 8);
  *(short8*)(ol)     = *(const short8*)(lo);
  *(short8*)(ol + 8) = *(const short8*)(lo + 8);
}

// ---------------- ctx via MFMA: R = Qk @ osum (hi+lo), ctx = bf16(Xphi * R) ----------------
// Xphi read from lin cols 3072.., stride NLIN_.
__global__ __launch_bounds__(256) void ctx_mfma(const unsigned short* __restrict__ Qk,
                                                const unsigned short* __restrict__ osumb,
                                                const unsigned short* __restrict__ lin,
                                                unsigned short* __restrict__ ctx){
  int bn = blockIdx.x, sc = blockIdx.y;   // 64 x 16
  int b = bn >> 5, n = bn & 31;
  int tid = threadIdx.x;
  int w = tid >> 6, lane = tid & 63;
  int l15 = lane & 15, quad = lane >> 4;

  const unsigned short* obase = osumb + ((size_t)bn * 2) * 4096;
  short8 bh[4][2], bl[4][2];
  #pragma unroll
  for (int nf = 0; nf < 4; nf++){
    int f = nf * 16 + l15;
    #pragma unroll
    for (int kh = 0; kh < 2; kh++){
      bh[nf][kh] = *(const short8*)(obase + (size_t)f * 64 + kh * 32 + quad * 8);
      bl[nf][kh] = *(const short8*)(obase + 4096 + (size_t)f * 64 + kh * 32 + quad * 8);
    }
  }

  int s0 = sc * 256 + w * 64;
  const unsigned short* qbase = Qk + ((size_t)bn * S_ + s0) * HD_;
  floatx4 acc[4][4] = {};
  #pragma unroll
  for (int m = 0; m < 4; m++){
    short8 a0 = *(const short8*)(qbase + (size_t)(m * 16 + l15) * HD_ + quad * 8);
    short8 a1 = *(const short8*)(qbase + (size_t)(m * 16 + l15) * HD_ + 32 + quad * 8);
    #pragma unroll
    for (int nf = 0; nf < 4; nf++){
      acc[m][nf] = __builtin_amdgcn_mfma_f32_16x16x32_bf16(a0, bh[nf][0], acc[m][nf], 0, 0, 0);
      acc[m][nf] = __builtin_amdgcn_mfma_f32_16x16x32_bf16(a1, bh[nf][1], acc[m][nf], 0, 0, 0);
      acc[m][nf] = __builtin_amdgcn_mfma_f32_16x16x32_bf16(a0, bl[nf][0], acc[m][nf], 0, 0, 0);
      acc[m][nf] = __builtin_amdgcn_mfma_f32_16x16x32_bf16(a1, bl[nf][1], acc[m][nf], 0, 0, 0);
    }
  }

  // epilogue: C/D mapping col=l15, row=quad*4+r; multiply by Xphi (bf16), store bf16
  #pragma unroll
  for (int m = 0; m < 4; m++){
    #pragma unroll
    for (int r = 0; r < 4; r++){
      int s = s0 + m * 16 + quad * 4 + r;
      const unsigned short* xp = lin + (size_t)(b * S_ + s) * NLIN_ + 3072 + n * HD_;
      unsigned short* cp = ctx + (size_t)(b * S_ + s) * HID_ + n * HD_;
      #pragma unroll
      for (int nf = 0; nf < 4; nf++){
        int f = nf * 16 + l15;
        cp[f] = f2bf(bf2f(xp[f]) * acc[m][nf][r]);
      }
    }
  }
}

extern "C" void kernel_launch(void* const* d_in, const int* in_sizes, int n_in,
                              void* d_out, int out_size, void* d_ws, size_t ws_size,
                              hipStream_t stream) {
  const float* hs   = (const float*)d_in[0];
  const float* Wq   = (const float*)d_in[1];
  const float* Wk   = (const float*)d_in[2];
  const float* Wv   = (const float*)d_in[3];
  const float* Wphi = (const float*)d_in[4];
  const float* Wo   = (const float*)d_in[5];
  float* out = (float*)d_out;

  char* ws = (char*)d_ws;
  const size_t M = (size_t)B_ * S_;          // 8192
  size_t off = 0;
  auto alloc = [&](size_t bytes){ size_t o = off; off += (bytes + 255) & ~(size_t)255; return o; };

  // region X (32MB): hsb bf16 -> part fp32 -> ctx bf16 (strictly sequential lifetimes)
  size_t off_x     = alloc(M * HID_ * 4);                 // 32MB (fp32-part sized)
  size_t off_wcat  = alloc((size_t)NLIN_ * HID_ * 2);     // 20MB  [Wq^T; Wk^T; Wv^T; Wphi^T]
  size_t off_wot   = alloc((size_t)HID_ * HID_ * 2);      // 8MB
  size_t off_lin   = alloc(M * NLIN_ * 2);                // 80MB bf16 fused Q|K|V|phi
  size_t off_qk    = alloc(M * HID_ * 2);                 // 32MB bf16 [B,NH,S,D]
  size_t off_kk    = alloc(M * 512 * 2);                  // 8MB  bf16 [B,NKV,S,D]
  size_t off_qg    = alloc(64 * 64 * 4);
  size_t off_alph  = alloc((size_t)B_ * NH_ * S_ * 4);    // 1MB
  size_t off_osumb = alloc((size_t)64 * 2 * 4096 * 2);    // 1MB split-bf16 osum^T
  (void)ws_size;

  unsigned short* hsb  = (unsigned short*)(ws + off_x);
  float*          part = (float*)(ws + off_x);
  unsigned short* ctx  = (unsigned short*)(ws + off_x);
  unsigned short* wcat = (unsigned short*)(ws + off_wcat);
  unsigned short* wot  = (unsigned short*)(ws + off_wot);
  unsigned short* lin  = (unsigned short*)(ws + off_lin);
  unsigned short* qk = (unsigned short*)(ws + off_qk);
  unsigned short* kk = (unsigned short*)(ws + off_kk);
  float* qg   = (float*)(ws + off_qg);
  float* alph = (float*)(ws + off_alph);
  unsigned short* osumb = (unsigned short*)(ws + off_osumb);

  // 1. hs -> bf16 (into X)
  conv_bf16<<<(int)(M * HID_ / 4 / 256), 256, 0, stream>>>(hs, hsb, (int)(M * HID_ / 4));
  // 2. weight transposes into concatenated Wt rows: Wq 0..2047 | Wk 2048.. | Wv 2560.. | Wphi 3072..
  transpose_to_bf16<<<dim3(HID_/32, HID_/32), dim3(32,8), 0, stream>>>(Wq,   wcat,                          HID_, HID_);
  transpose_to_bf16<<<dim3(512/32,  HID_/32), dim3(32,8), 0, stream>>>(Wk,   wcat + (size_t)2048 * HID_,    HID_, 512);
  transpose_to_bf16<<<dim3(512/32,  HID_/32), dim3(32,8), 0, stream>>>(Wv,   wcat + (size_t)2560 * HID_,    HID_, 512);
  transpose_to_bf16<<<dim3(HID_/32, HID_/32), dim3(32,8), 0, stream>>>(Wphi, wcat + (size_t)3072 * HID_,    HID_, HID_);
  transpose_to_bf16<<<dim3(HID_/32, HID_/32), dim3(32,8), 0, stream>>>(Wo,   wot,                           HID_, HID_);
  // 3. fused Q|K|V|phi projection (bf16 C, 640 blocks = 2.5 full-GPU rounds)
  gemm256<<<dim3(NLIN_/256, M/256), 512, 0, stream>>>(hsb, wcat, lin, (int)M, NLIN_, HID_, 1);
  // 4. RoPE + kappa (+ layout to [B,H,S,D])
  rope_kappa_q<<<(int)(M * NH_ * 32 / 256), 256, 0, stream>>>(lin, qk);
  rope_kappa_k<<<(int)(M * NKV_ * 32 / 256), 256, 0, stream>>>(lin, kk);
  // 5. global query (split-S + atomics)
  hipMemsetAsync(qg, 0, 64 * 64 * 4, stream);
  qg_mean<<<dim3(B_ * NH_, S_ / 256), 256, 0, stream>>>(qk, qg);
  // 6. logits + softmax * S
  logits_kernel<<<dim3(B_ * NH_, S_ / 256), 256, 0, stream>>>(kk, qg, alph);
  softmax_kernel<<<B_ * NH_, 256, 0, stream>>>(alph, alph);
  // 7. outer_sum (partials into X — hsb dead after fused gemm) + transposed split-bf16 reduce
  outer_sum_kernel<<<dim3(B_ * NKV_, NCH_), 256, 0, stream>>>(kk, lin, alph, part);
  osum_reduce_t<<<64, 256, 0, stream>>>(part, osumb);
  // 8. ctx = Xphi * (Qk @ osum) -> bf16 into X (part dead after reduce)
  ctx_mfma<<<dim3(B_ * NH_, S_ / 64 / 4), 256, 0, stream>>>(qk, osumb, lin, ctx);
  // 9. out = ctx @ Wo (fp32 C)
  gemm256<<<dim3(HID_/256, M/256), 512, 0, stream>>>(ctx, wot, out, (int)M, HID_, HID_, 0);
}

// Round 6
// 538.837 us; speedup vs baseline: 1.3693x; 1.0114x over previous
//
#include <hip/hip_runtime.h>
#include <hip/hip_bf16.h>

#define B_ 2
#define S_ 4096
#define HID_ 2048
#define NH_ 32
#define NKV_ 8
#define HD_ 64
#define GROUPS_ 4
#define NCH_ 32   // outer_sum S-chunks
#define NLIN_ 5120  // fused projection width: Q 0..2047 | K 2048..2559 | V 2560..3071 | phi 3072..5119

typedef short short8 __attribute__((ext_vector_type(8)));
typedef float floatx4 __attribute__((ext_vector_type(4)));

__device__ __forceinline__ float bf2f(unsigned short u){
  union { unsigned int i; float f; } v; v.i = ((unsigned int)u) << 16; return v.f;
}
__device__ __forceinline__ unsigned short f2bf(float f){
  union { float f; unsigned int i; } v; v.f = f;
  unsigned int i = v.i;
  unsigned int r = (i + 0x7fffu + ((i >> 16) & 1u)) >> 16;  // RNE
  return (unsigned short)r;
}

// async global->LDS, 16B per lane, LDS dest = wave-uniform base + lane*16
__device__ __forceinline__ void async_copy16(unsigned short* lds, const unsigned short* g){
  __builtin_amdgcn_global_load_lds((const __attribute__((address_space(1))) void*)g,
                                   (__attribute__((address_space(3))) void*)lds,
                                   16, 0, 0);
}

// ---------------- fp32 -> bf16 bulk convert (hidden_states) ----------------
__global__ void conv_bf16(const float* __restrict__ x, unsigned short* __restrict__ y, int n4){
  int i = blockIdx.x * 256 + threadIdx.x;
  if (i < n4){
    float4 v = ((const float4*)x)[i];
    ushort4 o;
    o.x = f2bf(v.x); o.y = f2bf(v.y); o.z = f2bf(v.z); o.w = f2bf(v.w);
    ((ushort4*)y)[i] = o;
  }
}

// ---------------- all 5 weight transposes in one launch (z selects) ----------------
__global__ void transpose_all(const float* __restrict__ Wq, const float* __restrict__ Wk,
                              const float* __restrict__ Wv, const float* __restrict__ Wphi,
                              const float* __restrict__ Wo,
                              unsigned short* __restrict__ wcat, unsigned short* __restrict__ wot){
  const float* W; unsigned short* Wt; int N;
  switch (blockIdx.z){
    case 0:  W = Wq;   Wt = wcat;                              N = 2048; break;
    case 1:  W = Wk;   Wt = wcat + (size_t)2048 * HID_;        N = 512;  break;
    case 2:  W = Wv;   Wt = wcat + (size_t)2560 * HID_;        N = 512;  break;
    case 3:  W = Wphi; Wt = wcat + (size_t)3072 * HID_;        N = 2048; break;
    default: W = Wo;   Wt = wot;                               N = 2048; break;
  }
  int n0 = blockIdx.x * 32, k0 = blockIdx.y * 32;
  if (n0 >= N) return;
  __shared__ float tile[32][33];
  int tx = threadIdx.x, ty = threadIdx.y;   // 32 x 8
  #pragma unroll
  for (int j = 0; j < 4; j++)
    tile[ty + j*8][tx] = W[(size_t)(k0 + ty + j*8) * N + n0 + tx];
  __syncthreads();
  #pragma unroll
  for (int j = 0; j < 4; j++)
    Wt[(size_t)(n0 + ty + j*8) * HID_ + k0 + tx] = f2bf(tile[tx][ty + j*8]);
}

// ---------------- 256x256-tile 2-phase GEMM: C = A[M,K]bf16 @ Bt[N,K]^T bf16 ----------------
// R1 schedule with the two middle barriers removed (order-preserving relaxation):
//   phA: read all 24 frags | barrier | 32 MFMA (m0-3 x n0-3) | barrier
//   phB: stage A+B(T+2), vmcnt(8) | barrier | 32 MFMA (m4-7 x n0-3) | barrier
// Invariants identical to R1: reads of buf cb complete a barrier before its restage;
// vmcnt(8) confirms tile T+1 one full phase before its first read (next phA).
#define GTILE 16384   // 256*64 bf16 elements per operand per buffer

__global__ __launch_bounds__(512, 2) void gemm256(
    const unsigned short* __restrict__ A, const unsigned short* __restrict__ Bt,
    void* __restrict__ Cv, int M, int N, int K, int cbf16)
{
  __shared__ __align__(16) unsigned short As[2 * GTILE];
  __shared__ __align__(16) unsigned short Bs[2 * GTILE];

  const int tid = threadIdx.x;
  const int w = tid >> 6, lane = tid & 63;
  const int wr = w >> 2, wc = w & 3;
  const int l15 = lane & 15, quad = lane >> 4;

  // bijective XCD-aware swizzle (nwg % 8 == 0 for all shapes here)
  const int nbx = N >> 8;
  int flat = blockIdx.y * nbx + blockIdx.x;
  int nwg  = nbx * (M >> 8);
  int cpx  = nwg >> 3;
  int swz  = (flat & 7) * cpx + (flat >> 3);
  int bx = swz % nbx, by = swz / nbx;
  const int m0 = by << 8, n0 = bx << 8;

  // ---- staging addressing (per wave-call: 64 lanes x 16B = 512 shorts linear in LDS) ----
  const int srow = (w << 3) + (lane >> 3);          // row 0..63 within a 64-row call
  const int scc  = (lane & 7) ^ (lane >> 3);        // swizzled 16B chunk within 128B row
  const unsigned short* gA = A  + (size_t)(m0 + srow) * K + scc * 8;
  const unsigned short* gB = Bt + (size_t)(n0 + srow) * K + scc * 8;
  const size_t rs64  = (size_t)64  * K;             // second-call row offset
  const size_t rs128 = (size_t)128 * K;             // half-tile row offset
  unsigned short* lA0 = As + (w << 9);
  unsigned short* lB0 = Bs + (w << 9);

#define STAGE_A(bsel, h, t) do { \
    unsigned short* _d = lA0 + (bsel) * GTILE + (h) * 8192; \
    const unsigned short* _g = gA + (size_t)(h) * rs128 + (size_t)(t) * 64; \
    async_copy16(_d, _g); \
    async_copy16(_d + 4096, _g + rs64); \
  } while (0)
#define STAGE_B(bsel, h, t) do { \
    unsigned short* _d = lB0 + (bsel) * GTILE + (h) * 8192; \
    const unsigned short* _g = gB + (size_t)(h) * rs128 + (size_t)(t) * 64; \
    async_copy16(_d, _g); \
    async_copy16(_d + 4096, _g + rs64); \
  } while (0)
#define SCHED0 __builtin_amdgcn_sched_barrier(0)

  // ---- fragment read offsets (shorts): row*64 + ((kchunk ^ (row&7))<<3); row&7 == lane&7 ----
  const int ks0  = ((quad     ^ (lane & 7)) << 3);
  const int ks1  = (((4+quad) ^ (lane & 7)) << 3);
  const int arow = (wr * 128 + l15) * 64;
  const int brow = (wc * 64  + l15) * 64;

  floatx4 acc[8][4] = {};
  short8 af[8][2], bfr[4][2];

  const int nt = K >> 6;

  // ---- prologue: stage tile0 (buf0) and tile1 (buf1); allow tile1's 8 loads in flight ----
  STAGE_A(0, 0, 0); STAGE_A(0, 1, 0); STAGE_B(0, 0, 0); STAGE_B(0, 1, 0);
  if (nt > 1){
    STAGE_A(1, 0, 1); STAGE_A(1, 1, 1); STAGE_B(1, 0, 1); STAGE_B(1, 1, 1);
    asm volatile("s_waitcnt vmcnt(8)" ::: "memory");
  } else {
    asm volatile("s_waitcnt vmcnt(0)" ::: "memory");
  }
  SCHED0;
  __builtin_amdgcn_s_barrier();
  SCHED0;

  for (int T = 0; T < nt; ++T){
    const int cb = T & 1;
    const unsigned short* Ab = As + cb * GTILE;
    const unsigned short* Bb = Bs + cb * GTILE;

    // ================= phase A: read all 24 frags | MFMA m0-3 x n0-3 =================
    #pragma unroll
    for (int m = 0; m < 8; ++m){
      af[m][0] = *(const short8*)(Ab + arow + m * 1024 + ks0);
      af[m][1] = *(const short8*)(Ab + arow + m * 1024 + ks1);
    }
    #pragma unroll
    for (int n = 0; n < 4; ++n){
      bfr[n][0] = *(const short8*)(Bb + brow + n * 1024 + ks0);
      bfr[n][1] = *(const short8*)(Bb + brow + n * 1024 + ks1);
    }
    SCHED0; __builtin_amdgcn_s_barrier(); SCHED0;
    __builtin_amdgcn_s_setprio(1);
    #pragma unroll
    for (int k = 0; k < 2; ++k)
      #pragma unroll
      for (int m = 0; m < 4; ++m)
        #pragma unroll
        for (int n = 0; n < 4; ++n)
          acc[m][n] = __builtin_amdgcn_mfma_f32_16x16x32_bf16(af[m][k], bfr[n][k], acc[m][n], 0, 0, 0);
    __builtin_amdgcn_s_setprio(0);
    SCHED0; __builtin_amdgcn_s_barrier(); SCHED0;

    // ================= phase B: stage A+B(T+2); vmcnt(8) | MFMA m4-7 x n0-3 =================
    if (T + 2 < nt){
      STAGE_A(cb, 0, T + 2); STAGE_A(cb, 1, T + 2);
      STAGE_B(cb, 0, T + 2); STAGE_B(cb, 1, T + 2);
      asm volatile("s_waitcnt vmcnt(8)" ::: "memory");   // tile T+1 landed; T+2's 8 stay in flight
    } else {
      asm volatile("s_waitcnt vmcnt(0)" ::: "memory");   // epilogue drain
    }
    SCHED0; __builtin_amdgcn_s_barrier(); SCHED0;
    __builtin_amdgcn_s_setprio(1);
    #pragma unroll
    for (int k = 0; k < 2; ++k)
      #pragma unroll
      for (int m = 0; m < 4; ++m)
        #pragma unroll
        for (int n = 0; n < 4; ++n)
          acc[4+m][n] = __builtin_amdgcn_mfma_f32_16x16x32_bf16(af[4+m][k], bfr[n][k], acc[4+m][n], 0, 0, 0);
    __builtin_amdgcn_s_setprio(0);
    SCHED0; __builtin_amdgcn_s_barrier(); SCHED0;
  }

#undef STAGE_A
#undef STAGE_B
#undef SCHED0

  if (cbf16){
    unsigned short* Cb = (unsigned short*)Cv;
    #pragma unroll
    for (int mi = 0; mi < 8; ++mi){
      const int row = m0 + wr * 128 + mi * 16 + quad * 4;
      #pragma unroll
      for (int ni = 0; ni < 4; ++ni){
        const int col = n0 + wc * 64 + ni * 16 + l15;
        #pragma unroll
        for (int r = 0; r < 4; ++r)
          Cb[(size_t)(row + r) * N + col] = f2bf(acc[mi][ni][r]);
      }
    }
  } else {
    float* Cf = (float*)Cv;
    #pragma unroll
    for (int mi = 0; mi < 8; ++mi){
      const int row = m0 + wr * 128 + mi * 16 + quad * 4;
      #pragma unroll
      for (int ni = 0; ni < 4; ++ni){
        const int col = n0 + wc * 64 + ni * 16 + l15;
        #pragma unroll
        for (int r = 0; r < 4; ++r)
          Cf[(size_t)(row + r) * N + col] = acc[mi][ni][r];
      }
    }
  }
}

// ---------------- fused RoPE + kappa for Q and K (one launch) ----------------
// blocks 0..32767: Q path (lin cols 0..2047 -> Qk [B,NH,S,HD])
// blocks 32768..40959: K path (lin cols 2048..2559 -> Kk [B,NKV,S,HD])
__global__ void rope_fused(const unsigned short* __restrict__ lin,
                           unsigned short* __restrict__ Qk, unsigned short* __restrict__ Kk){
  int blk = blockIdx.x;
  if (blk < 32768){
    int idx = blk * 256 + threadIdx.x;    // B*S*NH*32 = 2^23 threads
    int i = idx & 31;
    int n = (idx >> 5) & (NH_ - 1);
    int s = (idx >> 10) & (S_ - 1);
    int b = idx >> 22;
    float invf = exp2f(-(float)i * (13.287712379549449f / 32.0f));  // 10000^(-i/32)
    float ang = (float)s * invf;
    float c = cosf(ang), sn = sinf(ang);
    size_t in_o = (size_t)(b * S_ + s) * NLIN_ + n * HD_;
    float x1 = bf2f(lin[in_o + i]);
    float x2 = bf2f(lin[in_o + i + 32]);
    float r1 = x1 * c - x2 * sn;
    float r2 = x2 * c + x1 * sn;
    r1 = r1 > 0.f ? r1 + 1.f : __expf(r1);
    r2 = r2 > 0.f ? r2 + 1.f : __expf(r2);
    size_t o = ((size_t)(b * NH_ + n) * S_ + s) * HD_;
    Qk[o + i] = f2bf(r1);
    Qk[o + i + 32] = f2bf(r2);
  } else {
    int idx = (blk - 32768) * 256 + threadIdx.x;   // B*S*NKV*32 = 2^21 threads
    int i = idx & 31;
    int kv = (idx >> 5) & (NKV_ - 1);
    int s = (idx >> 8) & (S_ - 1);
    int b = idx >> 20;
    float invf = exp2f(-(float)i * (13.287712379549449f / 32.0f));
    float ang = (float)s * invf;
    float c = cosf(ang), sn = sinf(ang);
    size_t in_o = (size_t)(b * S_ + s) * NLIN_ + 2048 + kv * HD_;
    float x1 = bf2f(lin[in_o + i]);
    float x2 = bf2f(lin[in_o + i + 32]);
    float r1 = x1 * c - x2 * sn;
    float r2 = x2 * c + x1 * sn;
    r1 = r1 > 0.f ? r1 + 1.f : __expf(r1);
    r2 = r2 > 0.f ? r2 + 1.f : __expf(r2);
    size_t o = ((size_t)(b * NKV_ + kv) * S_ + s) * HD_;
    Kk[o + i] = f2bf(r1);
    Kk[o + i + 32] = f2bf(r2);
  }
}

// ---------------- Qg[b,n,d] = mean_s Qk[b,n,s,d]  (split-S, atomics) ----------------
__global__ __launch_bounds__(256) void qg_mean(const unsigned short* __restrict__ Qk,
                                               float* __restrict__ Qg){
  int bn = blockIdx.x, chunk = blockIdx.y;     // 64 x 16
  int tid = threadIdx.x;
  int dgrp = tid & 7, sgrp = tid >> 3;         // 8 d-chunks x 32 s-rows
  const unsigned short* base = Qk + (size_t)bn * S_ * HD_
                             + (size_t)(chunk * 256 + sgrp) * HD_ + dgrp * 8;
  float acc[8] = {};
  #pragma unroll
  for (int i = 0; i < 8; i++){
    short8 v = *(const short8*)(base + (size_t)i * 32 * HD_);
    #pragma unroll
    for (int e = 0; e < 8; e++) acc[e] += bf2f((unsigned short)v[e]);
  }
  __shared__ float red[256][8];
  #pragma unroll
  for (int e = 0; e < 8; e++) red[tid][e] = acc[e];
  __syncthreads();
  if (tid < 64){
    int dg = tid >> 3, e = tid & 7;
    float s = 0.f;
    #pragma unroll
    for (int g = 0; g < 32; g++) s += red[g * 8 + dg][e];
    atomicAdd(&Qg[bn * 64 + tid], s * (1.0f / (float)S_));
  }
}

// ---------------- logits[b,n,s] = dot(Qg[b,n], Kk[b,kv,s]) ----------------
__global__ __launch_bounds__(256) void logits_kernel(const unsigned short* __restrict__ Kk,
                                                     const float* __restrict__ Qg,
                                                     float* __restrict__ logits){
  int bn = blockIdx.x, chunk = blockIdx.y;     // 64 x 16
  int b = bn / NH_, n = bn % NH_, kv = n / GROUPS_;
  int tid = threadIdx.x;
  __shared__ float qg[64];
  if (tid < 64) qg[tid] = Qg[bn * 64 + tid];
  __syncthreads();
  int s = chunk * 256 + tid;
  const unsigned short* row = Kk + ((size_t)(b * NKV_ + kv) * S_ + s) * HD_;
  float acc = 0.f;
  #pragma unroll
  for (int c = 0; c < 8; c++){
    short8 v = *(const short8*)(row + c * 8);
    #pragma unroll
    for (int e = 0; e < 8; e++) acc += qg[c * 8 + e] * bf2f((unsigned short)v[e]);
  }
  logits[(size_t)bn * S_ + s] = acc;
}

// ---------------- softmax * S over logits -> alpha (in place OK) ----------------
__global__ __launch_bounds__(256) void softmax_kernel(const float* __restrict__ logits,
                                                      float* __restrict__ alpha){
  int bn = blockIdx.x;
  int tid = threadIdx.x;
  float l[16];
  float mymax = -1e30f;
  #pragma unroll
  for (int j = 0; j < 16; j++){
    l[j] = logits[(size_t)bn * S_ + j * 256 + tid];
    mymax = fmaxf(mymax, l[j]);
  }
  __shared__ float red[256];
  red[tid] = mymax; __syncthreads();
  for (int st = 128; st > 0; st >>= 1){
    if (tid < st) red[tid] = fmaxf(red[tid], red[tid + st]);
    __syncthreads();
  }
  float gmax = red[0];
  __syncthreads();
  float mysum = 0.f;
  #pragma unroll
  for (int j = 0; j < 16; j++){ l[j] = __expf(l[j] - gmax); mysum += l[j]; }
  red[tid] = mysum; __syncthreads();
  for (int st = 128; st > 0; st >>= 1){
    if (tid < st) red[tid] += red[tid + st];
    __syncthreads();
  }
  float inv = (float)S_ / red[0];
  #pragma unroll
  for (int j = 0; j < 16; j++)
    alpha[(size_t)bn * S_ + j * 256 + tid] = l[j] * inv;
}

// ---------------- outer_sum: per (b,kv,chunk), all 4 GQA heads; V from lin cols 2560.. ----------------
__global__ __launch_bounds__(256) void outer_sum_kernel(const unsigned short* __restrict__ Kk,
                                                        const unsigned short* __restrict__ lin,
                                                        const float* __restrict__ alpha,
                                                        float* __restrict__ part){
  int bkv = blockIdx.x, chunk = blockIdx.y;     // 16 x NCH_
  int b = bkv >> 3, kv = bkv & 7;
  int tid = threadIdx.x;
  int d = tid >> 2, fb = (tid & 3) * 16;
  __shared__ float ks[64][64];   // [si][d]
  __shared__ float vs[64][64];   // [si][f]
  __shared__ float as4[64][4];   // [si][h] -- one b128 broadcast read per si
  float acc[4][16] = {};
  const unsigned short* kb = Kk + (size_t)(b * NKV_ + kv) * S_ * HD_;
  const int SPC = S_ / NCH_;     // 128 s per chunk

  for (int t = 0; t < SPC / 64; t++){
    int ss = chunk * SPC + t * 64;
    // stage K and V tiles (64x64 bf16 each) with short4 loads
    #pragma unroll
    for (int jj = 0; jj < 4; jj++){
      int idx4 = jj * 256 + tid;          // 1024 short4 chunks per tile
      int si = idx4 >> 4, c4 = (idx4 & 15) * 4;
      ushort4 kv4 = *(const ushort4*)(kb + (size_t)(ss + si) * HD_ + c4);
      ks[si][c4]   = bf2f(kv4.x); ks[si][c4+1] = bf2f(kv4.y);
      ks[si][c4+2] = bf2f(kv4.z); ks[si][c4+3] = bf2f(kv4.w);
      ushort4 vv4 = *(const ushort4*)(lin + (size_t)(b * S_ + ss + si) * NLIN_ + 2560 + kv * HD_ + c4);
      vs[si][c4]   = bf2f(vv4.x); vs[si][c4+1] = bf2f(vv4.y);
      vs[si][c4+2] = bf2f(vv4.z); vs[si][c4+3] = bf2f(vv4.w);
    }
    {
      int si = tid >> 2, h = tid & 3;
      as4[si][h] = alpha[(size_t)(b * NH_ + kv * GROUPS_ + h) * S_ + ss + si];
    }
    __syncthreads();
    #pragma unroll 4
    for (int si = 0; si < 64; si++){
      float k = ks[si][d];
      float4 a4 = *(const float4*)&as4[si][0];
      float4 v0 = *(const float4*)&vs[si][fb];
      float4 v1 = *(const float4*)&vs[si][fb + 4];
      float4 v2 = *(const float4*)&vs[si][fb + 8];
      float4 v3 = *(const float4*)&vs[si][fb + 12];
      float ak0 = a4.x * k, ak1 = a4.y * k, ak2 = a4.z * k, ak3 = a4.w * k;
      acc[0][0]  += ak0 * v0.x; acc[0][1]  += ak0 * v0.y; acc[0][2]  += ak0 * v0.z; acc[0][3]  += ak0 * v0.w;
      acc[0][4]  += ak0 * v1.x; acc[0][5]  += ak0 * v1.y; acc[0][6]  += ak0 * v1.z; acc[0][7]  += ak0 * v1.w;
      acc[0][8]  += ak0 * v2.x; acc[0][9]  += ak0 * v2.y; acc[0][10] += ak0 * v2.z; acc[0][11] += ak0 * v2.w;
      acc[0][12] += ak0 * v3.x; acc[0][13] += ak0 * v3.y; acc[0][14] += ak0 * v3.z; acc[0][15] += ak0 * v3.w;
      acc[1][0]  += ak1 * v0.x; acc[1][1]  += ak1 * v0.y; acc[1][2]  += ak1 * v0.z; acc[1][3]  += ak1 * v0.w;
      acc[1][4]  += ak1 * v1.x; acc[1][5]  += ak1 * v1.y; acc[1][6]  += ak1 * v1.z; acc[1][7]  += ak1 * v1.w;
      acc[1][8]  += ak1 * v2.x; acc[1][9]  += ak1 * v2.y; acc[1][10] += ak1 * v2.z; acc[1][11] += ak1 * v2.w;
      acc[1][12] += ak1 * v3.x; acc[1][13] += ak1 * v3.y; acc[1][14] += ak1 * v3.z; acc[1][15] += ak1 * v3.w;
      acc[2][0]  += ak2 * v0.x; acc[2][1]  += ak2 * v0.y; acc[2][2]  += ak2 * v0.z; acc[2][3]  += ak2 * v0.w;
      acc[2][4]  += ak2 * v1.x; acc[2][5]  += ak2 * v1.y; acc[2][6]  += ak2 * v1.z; acc[2][7]  += ak2 * v1.w;
      acc[2][8]  += ak2 * v2.x; acc[2][9]  += ak2 * v2.y; acc[2][10] += ak2 * v2.z; acc[2][11] += ak2 * v2.w;
      acc[2][12] += ak2 * v3.x; acc[2][13] += ak2 * v3.y; acc[2][14] += ak2 * v3.z; acc[2][15] += ak2 * v3.w;
      acc[3][0]  += ak3 * v0.x; acc[3][1]  += ak3 * v0.y; acc[3][2]  += ak3 * v0.z; acc[3][3]  += ak3 * v0.w;
      acc[3][4]  += ak3 * v1.x; acc[3][5]  += ak3 * v1.y; acc[3][6]  += ak3 * v1.z; acc[3][7]  += ak3 * v1.w;
      acc[3][8]  += ak3 * v2.x; acc[3][9]  += ak3 * v2.y; acc[3][10] += ak3 * v2.z; acc[3][11] += ak3 * v2.w;
      acc[3][12] += ak3 * v3.x; acc[3][13] += ak3 * v3.y; acc[3][14] += ak3 * v3.z; acc[3][15] += ak3 * v3.w;
    }
    __syncthreads();
  }

  #pragma unroll
  for (int h = 0; h < 4; h++){
    float* pb = part + ((size_t)(chunk * 16 + bkv) * 4 + h) * 4096 + d * 64 + fb;
    #pragma unroll
    for (int j = 0; j < 4; j++)
      *(float4*)&pb[j * 4] = *(float4*)&acc[h][j * 4];
  }
}

// ---------------- reduce partials over NCH_ chunks -> transposed split-bf16 osum ----------------
// osumb layout: [bn][plane][f][d] bf16, plane 0 = hi, plane 1 = lo (x - hi).
__global__ __launch_bounds__(256) void osum_reduce_t(const float* __restrict__ part,
                                                     unsigned short* __restrict__ osumb){
  int bn = blockIdx.x;            // 64
  int tid = threadIdx.x;
  __shared__ float os[64][65];
  const float4* p4 = (const float4*)part;
  #pragma unroll
  for (int r = 0; r < 4; r++){
    int idx4 = r * 256 + tid;     // float4 index within this bn's 1024
    float4 s = {0.f, 0.f, 0.f, 0.f};
    #pragma unroll 8
    for (int c = 0; c < NCH_; c++){
      float4 v = p4[(size_t)c * 65536 + bn * 1024 + idx4];
      s.x += v.x; s.y += v.y; s.z += v.z; s.w += v.w;
    }
    int d = idx4 >> 4;            // (idx4*4)/64
    int f0 = (idx4 & 15) * 4;
    os[d][f0] = s.x; os[d][f0+1] = s.y; os[d][f0+2] = s.z; os[d][f0+3] = s.w;
  }
  __syncthreads();
  int f = tid >> 2, d0 = (tid & 3) * 16;
  unsigned short hi[16], lo[16];
  #pragma unroll
  for (int j = 0; j < 16; j++){
    float x = os[d0 + j][f];
    unsigned short h = f2bf(x);
    hi[j] = h;
    lo[j] = f2bf(x - bf2f(h));
  }
  unsigned short* oh = osumb + ((size_t)bn * 2) * 4096 + (size_t)f * 64 + d0;
  unsigned short* ol = oh + 4096;
  *(short8*)(oh)     = *(const short8*)(hi);
  *(short8*)(oh + 8) = *(const short8*)(hi + 8);
  *(short8*)(ol)     = *(const short8*)(lo);
  *(short8*)(ol + 8) = *(const short8*)(lo + 8);
}

// ---------------- ctx via MFMA: R = Qk @ osum (hi+lo), ctx = bf16(Xphi * R) ----------------
// Xphi read from lin cols 3072.., stride NLIN_.
__global__ __launch_bounds__(256) void ctx_mfma(const unsigned short* __restrict__ Qk,
                                                const unsigned short* __restrict__ osumb,
                                                const unsigned short* __restrict__ lin,
                                                unsigned short* __restrict__ ctx){
  int bn = blockIdx.x, sc = blockIdx.y;   // 64 x 16
  int b = bn >> 5, n = bn & 31;
  int tid = threadIdx.x;
  int w = tid >> 6, lane = tid & 63;
  int l15 = lane & 15, quad = lane >> 4;

  const unsigned short* obase = osumb + ((size_t)bn * 2) * 4096;
  short8 bh[4][2], bl[4][2];
  #pragma unroll
  for (int nf = 0; nf < 4; nf++){
    int f = nf * 16 + l15;
    #pragma unroll
    for (int kh = 0; kh < 2; kh++){
      bh[nf][kh] = *(const short8*)(obase + (size_t)f * 64 + kh * 32 + quad * 8);
      bl[nf][kh] = *(const short8*)(obase + 4096 + (size_t)f * 64 + kh * 32 + quad * 8);
    }
  }

  int s0 = sc * 256 + w * 64;
  const unsigned short* qbase = Qk + ((size_t)bn * S_ + s0) * HD_;
  floatx4 acc[4][4] = {};
  #pragma unroll
  for (int m = 0; m < 4; m++){
    short8 a0 = *(const short8*)(qbase + (size_t)(m * 16 + l15) * HD_ + quad * 8);
    short8 a1 = *(const short8*)(qbase + (size_t)(m * 16 + l15) * HD_ + 32 + quad * 8);
    #pragma unroll
    for (int nf = 0; nf < 4; nf++){
      acc[m][nf] = __builtin_amdgcn_mfma_f32_16x16x32_bf16(a0, bh[nf][0], acc[m][nf], 0, 0, 0);
      acc[m][nf] = __builtin_amdgcn_mfma_f32_16x16x32_bf16(a1, bh[nf][1], acc[m][nf], 0, 0, 0);
      acc[m][nf] = __builtin_amdgcn_mfma_f32_16x16x32_bf16(a0, bl[nf][0], acc[m][nf], 0, 0, 0);
      acc[m][nf] = __builtin_amdgcn_mfma_f32_16x16x32_bf16(a1, bl[nf][1], acc[m][nf], 0, 0, 0);
    }
  }

  // epilogue: C/D mapping col=l15, row=quad*4+r; multiply by Xphi (bf16), store bf16
  #pragma unroll
  for (int m = 0; m < 4; m++){
    #pragma unroll
    for (int r = 0; r < 4; r++){
      int s = s0 + m * 16 + quad * 4 + r;
      const unsigned short* xp = lin + (size_t)(b * S_ + s) * NLIN_ + 3072 + n * HD_;
      unsigned short* cp = ctx + (size_t)(b * S_ + s) * HID_ + n * HD_;
      #pragma unroll
      for (int nf = 0; nf < 4; nf++){
        int f = nf * 16 + l15;
        cp[f] = f2bf(bf2f(xp[f]) * acc[m][nf][r]);
      }
    }
  }
}

extern "C" void kernel_launch(void* const* d_in, const int* in_sizes, int n_in,
                              void* d_out, int out_size, void* d_ws, size_t ws_size,
                              hipStream_t stream) {
  const float* hs   = (const float*)d_in[0];
  const float* Wq   = (const float*)d_in[1];
  const float* Wk   = (const float*)d_in[2];
  const float* Wv   = (const float*)d_in[3];
  const float* Wphi = (const float*)d_in[4];
  const float* Wo   = (const float*)d_in[5];
  float* out = (float*)d_out;

  char* ws = (char*)d_ws;
  const size_t M = (size_t)B_ * S_;          // 8192
  size_t off = 0;
  auto alloc = [&](size_t bytes){ size_t o = off; off += (bytes + 255) & ~(size_t)255; return o; };

  // region X (32MB): hsb bf16 -> part fp32 -> ctx bf16 (strictly sequential lifetimes)
  size_t off_x     = alloc(M * HID_ * 4);                 // 32MB (fp32-part sized)
  size_t off_wcat  = alloc((size_t)NLIN_ * HID_ * 2);     // 20MB  [Wq^T; Wk^T; Wv^T; Wphi^T]
  size_t off_wot   = alloc((size_t)HID_ * HID_ * 2);      // 8MB
  size_t off_lin   = alloc(M * NLIN_ * 2);                // 80MB bf16 fused Q|K|V|phi
  size_t off_qk    = alloc(M * HID_ * 2);                 // 32MB bf16 [B,NH,S,D]
  size_t off_kk    = alloc(M * 512 * 2);                  // 8MB  bf16 [B,NKV,S,D]
  size_t off_qg    = alloc(64 * 64 * 4);
  size_t off_alph  = alloc((size_t)B_ * NH_ * S_ * 4);    // 1MB
  size_t off_osumb = alloc((size_t)64 * 2 * 4096 * 2);    // 1MB split-bf16 osum^T
  (void)ws_size;

  unsigned short* hsb  = (unsigned short*)(ws + off_x);
  float*          part = (float*)(ws + off_x);
  unsigned short* ctx  = (unsigned short*)(ws + off_x);
  unsigned short* wcat = (unsigned short*)(ws + off_wcat);
  unsigned short* wot  = (unsigned short*)(ws + off_wot);
  unsigned short* lin  = (unsigned short*)(ws + off_lin);
  unsigned short* qk = (unsigned short*)(ws + off_qk);
  unsigned short* kk = (unsigned short*)(ws + off_kk);
  float* qg   = (float*)(ws + off_qg);
  float* alph = (float*)(ws + off_alph);
  unsigned short* osumb = (unsigned short*)(ws + off_osumb);

  // 1. hs -> bf16 (into X)
  conv_bf16<<<(int)(M * HID_ / 4 / 256), 256, 0, stream>>>(hs, hsb, (int)(M * HID_ / 4));
  // 2. all weight transposes in one launch
  transpose_all<<<dim3(64, 64, 5), dim3(32, 8), 0, stream>>>(Wq, Wk, Wv, Wphi, Wo, wcat, wot);
  // 3. fused Q|K|V|phi projection (bf16 C)
  gemm256<<<dim3(NLIN_/256, M/256), 512, 0, stream>>>(hsb, wcat, lin, (int)M, NLIN_, HID_, 1);
  // 4. fused RoPE + kappa for Q and K
  rope_fused<<<32768 + 8192, 256, 0, stream>>>(lin, qk, kk);
  // 5. global query (split-S + atomics)
  hipMemsetAsync(qg, 0, 64 * 64 * 4, stream);
  qg_mean<<<dim3(B_ * NH_, S_ / 256), 256, 0, stream>>>(qk, qg);
  // 6. logits + softmax * S
  logits_kernel<<<dim3(B_ * NH_, S_ / 256), 256, 0, stream>>>(kk, qg, alph);
  softmax_kernel<<<B_ * NH_, 256, 0, stream>>>(alph, alph);
  // 7. outer_sum (partials into X — hsb dead after fused gemm) + transposed split-bf16 reduce
  outer_sum_kernel<<<dim3(B_ * NKV_, NCH_), 256, 0, stream>>>(kk, lin, alph, part);
  osum_reduce_t<<<64, 256, 0, stream>>>(part, osumb);
  // 8. ctx = Xphi * (Qk @ osum) -> bf16 into X (part dead after reduce)
  ctx_mfma<<<dim3(B_ * NH_, S_ / 64 / 4), 256, 0, stream>>>(qk, osumb, lin, ctx);
  // 9. out = ctx @ Wo (fp32 C)
  gemm256<<<dim3(HID_/256, M/256), 512, 0, stream>>>(ctx, wot, out, (int)M, HID_, HID_, 0);
}

// Round 8
// 516.589 us; speedup vs baseline: 1.4283x; 1.0431x over previous
//
#include <hip/hip_runtime.h>
#include <hip/hip_bf16.h>

#define B_ 2
#define S_ 4096
#define HID_ 2048
#define NH_ 32
#define NKV_ 8
#define HD_ 64
#define GROUPS_ 4
#define NCH_ 32   // outer_sum S-chunks
#define NLIN_ 5120  // fused projection width: Q 0..2047 | K 2048..2559 | V 2560..3071 | phi 3072..5119

typedef short short8 __attribute__((ext_vector_type(8)));
typedef float floatx4 __attribute__((ext_vector_type(4)));

__device__ __forceinline__ float bf2f(unsigned short u){
  union { unsigned int i; float f; } v; v.i = ((unsigned int)u) << 16; return v.f;
}
__device__ __forceinline__ unsigned short f2bf(float f){
  union { float f; unsigned int i; } v; v.f = f;
  unsigned int i = v.i;
  unsigned int r = (i + 0x7fffu + ((i >> 16) & 1u)) >> 16;  // RNE
  return (unsigned short)r;
}

// async global->LDS, 16B per lane, LDS dest = wave-uniform base + lane*16
__device__ __forceinline__ void async_copy16(unsigned short* lds, const unsigned short* g){
  __builtin_amdgcn_global_load_lds((const __attribute__((address_space(1))) void*)g,
                                   (__attribute__((address_space(3))) void*)lds,
                                   16, 0, 0);
}

// ---------------- fp32 -> bf16 bulk convert (hidden_states) ----------------
__global__ void conv_bf16(const float* __restrict__ x, unsigned short* __restrict__ y, int n4){
  int i = blockIdx.x * 256 + threadIdx.x;
  if (i < n4){
    float4 v = ((const float4*)x)[i];
    ushort4 o;
    o.x = f2bf(v.x); o.y = f2bf(v.y); o.z = f2bf(v.z); o.w = f2bf(v.w);
    ((ushort4*)y)[i] = o;
  }
}

// ---------------- all 5 weight transposes in one launch (z selects) ----------------
__global__ void transpose_all(const float* __restrict__ Wq, const float* __restrict__ Wk,
                              const float* __restrict__ Wv, const float* __restrict__ Wphi,
                              const float* __restrict__ Wo,
                              unsigned short* __restrict__ wcat, unsigned short* __restrict__ wot){
  const float* W; unsigned short* Wt; int N;
  switch (blockIdx.z){
    case 0:  W = Wq;   Wt = wcat;                              N = 2048; break;
    case 1:  W = Wk;   Wt = wcat + (size_t)2048 * HID_;        N = 512;  break;
    case 2:  W = Wv;   Wt = wcat + (size_t)2560 * HID_;        N = 512;  break;
    case 3:  W = Wphi; Wt = wcat + (size_t)3072 * HID_;        N = 2048; break;
    default: W = Wo;   Wt = wot;                               N = 2048; break;
  }
  int n0 = blockIdx.x * 32, k0 = blockIdx.y * 32;
  if (n0 >= N) return;
  __shared__ float tile[32][33];
  int tx = threadIdx.x, ty = threadIdx.y;   // 32 x 8
  #pragma unroll
  for (int j = 0; j < 4; j++)
    tile[ty + j*8][tx] = W[(size_t)(k0 + ty + j*8) * N + n0 + tx];
  __syncthreads();
  #pragma unroll
  for (int j = 0; j < 4; j++)
    Wt[(size_t)(n0 + ty + j*8) * HID_ + k0 + tx] = f2bf(tile[tx][ty + j*8]);
}

// ---------------- 256x256-tile 4-phase interleaved GEMM: C = A[M,K]bf16 @ Bt[N,K]^T ----------------
// m201-style per-phase interleave on R1-proven invariants. Fragment remap confines each
// wave's reads to one half-tile per operand:
//   af[0-3] rows m*16+wr*64 (A-half0), af[4-7] +128 (A-half1)
//   bfr[0-1] rows n*16+wc*32 (B-half0), bfr[2-3] +128 (B-half1)
// Death: A0,B0 after p0; B1 after p1; A1 after p2. Stage 1 half-tile/phase:
//   p0: A1(T+1)->buf^1 | reads a0-3,b0-1 (12) | MFMA m0-3 x n0-1
//   p1: A0(T+2)->buf   | reads b2-3 (4)       | MFMA m0-3 x n2-3
//   p2: B0(T+2)->buf   | reads a4-7 (8)       | MFMA m4-7 x n0-1
//   p3: B1(T+2)->buf; vmcnt(6)                | MFMA m4-7 x n2-3
// vmcnt ledger: steady state has 14 outstanding at p3; vmcnt(6) confirms the oldest 8 =
// ALL of tile T+1, one barrier before its first read. cbf16: epilogue stores bf16.
#define GTILE 16384   // 256*64 bf16 elements per operand per buffer

__global__ __launch_bounds__(512, 2) void gemm256(
    const unsigned short* __restrict__ A, const unsigned short* __restrict__ Bt,
    void* __restrict__ Cv, int M, int N, int K, int cbf16)
{
  __shared__ __align__(16) unsigned short As[2 * GTILE];
  __shared__ __align__(16) unsigned short Bs[2 * GTILE];

  const int tid = threadIdx.x;
  const int w = tid >> 6, lane = tid & 63;
  const int wr = w >> 2, wc = w & 3;
  const int l15 = lane & 15, quad = lane >> 4;

  // bijective XCD-aware swizzle (nwg % 8 == 0 for all shapes here)
  const int nbx = N >> 8;
  int flat = blockIdx.y * nbx + blockIdx.x;
  int nwg  = nbx * (M >> 8);
  int cpx  = nwg >> 3;
  int swz  = (flat & 7) * cpx + (flat >> 3);
  int bx = swz % nbx, by = swz / nbx;
  const int m0 = by << 8, n0 = bx << 8;

  // ---- staging addressing (per wave-call: 64 lanes x 16B = 512 shorts linear in LDS) ----
  const int srow = (w << 3) + (lane >> 3);          // row 0..63 within a 64-row call
  const int scc  = (lane & 7) ^ (lane >> 3);        // swizzled 16B chunk within 128B row
  const unsigned short* gA = A  + (size_t)(m0 + srow) * K + scc * 8;
  const unsigned short* gB = Bt + (size_t)(n0 + srow) * K + scc * 8;
  const size_t rs64  = (size_t)64  * K;             // second-call row offset
  const size_t rs128 = (size_t)128 * K;             // half-tile row offset
  unsigned short* lA0 = As + (w << 9);
  unsigned short* lB0 = Bs + (w << 9);

#define STAGE_A(bsel, h, t) do { \
    unsigned short* _d = lA0 + (bsel) * GTILE + (h) * 8192; \
    const unsigned short* _g = gA + (size_t)(h) * rs128 + (size_t)(t) * 64; \
    async_copy16(_d, _g); \
    async_copy16(_d + 4096, _g + rs64); \
  } while (0)
#define STAGE_B(bsel, h, t) do { \
    unsigned short* _d = lB0 + (bsel) * GTILE + (h) * 8192; \
    const unsigned short* _g = gB + (size_t)(h) * rs128 + (size_t)(t) * 64; \
    async_copy16(_d, _g); \
    async_copy16(_d + 4096, _g + rs64); \
  } while (0)
#define SCHED0 __builtin_amdgcn_sched_barrier(0)

  // ---- fragment read offsets (shorts): row*64 + ((kchunk ^ (row&7))<<3); row&7 == lane&7 ----
  const int ks0  = ((quad     ^ (lane & 7)) << 3);
  const int ks1  = (((4+quad) ^ (lane & 7)) << 3);
  const int arow0 = (wr * 64 + l15) * 64;   // af[m]: + (m&3)*1024 + (m>>2)*8192
  const int brow0 = (wc * 32 + l15) * 64;   // bfr[n]: + (n&1)*1024 + (n>>1)*8192

  floatx4 acc[8][4] = {};
  short8 af[8][2], bfr[4][2];

  const int nt = K >> 6;

  // ---- prologue: full tile0 + tile1 {A0,B0,B1}; tile1's A1 comes from t0-p0's stage ----
  STAGE_A(0, 0, 0); STAGE_A(0, 1, 0); STAGE_B(0, 0, 0); STAGE_B(0, 1, 0);
  if (nt > 1){
    STAGE_A(1, 0, 1); STAGE_B(1, 0, 1); STAGE_B(1, 1, 1);
    asm volatile("s_waitcnt vmcnt(6)" ::: "memory");   // tile0's 8 confirmed
  } else {
    asm volatile("s_waitcnt vmcnt(0)" ::: "memory");
  }
  SCHED0;
  __builtin_amdgcn_s_barrier();
  SCHED0;

  for (int T = 0; T < nt; ++T){
    const int cb = T & 1;
    const unsigned short* Ab = As + cb * GTILE;
    const unsigned short* Bb = Bs + cb * GTILE;

    // ========== p0: reads a0-3,b0-1 | stage A1(T+1) -> buf^1 | MFMA m0-3 x n0-1 ==========
    #pragma unroll
    for (int m = 0; m < 4; ++m){
      af[m][0] = *(const short8*)(Ab + arow0 + m * 1024 + ks0);
      af[m][1] = *(const short8*)(Ab + arow0 + m * 1024 + ks1);
    }
    #pragma unroll
    for (int n = 0; n < 2; ++n){
      bfr[n][0] = *(const short8*)(Bb + brow0 + n * 1024 + ks0);
      bfr[n][1] = *(const short8*)(Bb + brow0 + n * 1024 + ks1);
    }
    if (T + 1 < nt){ STAGE_A(cb ^ 1, 1, T + 1); }
    SCHED0; __builtin_amdgcn_s_barrier(); SCHED0;
    __builtin_amdgcn_s_setprio(1);
    #pragma unroll
    for (int k = 0; k < 2; ++k)
      #pragma unroll
      for (int m = 0; m < 4; ++m)
        #pragma unroll
        for (int n = 0; n < 2; ++n)
          acc[m][n] = __builtin_amdgcn_mfma_f32_16x16x32_bf16(af[m][k], bfr[n][k], acc[m][n], 0, 0, 0);
    __builtin_amdgcn_s_setprio(0);
    SCHED0; __builtin_amdgcn_s_barrier(); SCHED0;

    // ========== p1: reads b2-3 | stage A0(T+2) | MFMA m0-3 x n2-3 ==========
    #pragma unroll
    for (int n = 2; n < 4; ++n){
      bfr[n][0] = *(const short8*)(Bb + brow0 + 8192 + (n - 2) * 1024 + ks0);
      bfr[n][1] = *(const short8*)(Bb + brow0 + 8192 + (n - 2) * 1024 + ks1);
    }
    if (T + 2 < nt){ STAGE_A(cb, 0, T + 2); }
    SCHED0; __builtin_amdgcn_s_barrier(); SCHED0;
    __builtin_amdgcn_s_setprio(1);
    #pragma unroll
    for (int k = 0; k < 2; ++k)
      #pragma unroll
      for (int m = 0; m < 4; ++m)
        #pragma unroll
        for (int n = 2; n < 4; ++n)
          acc[m][n] = __builtin_amdgcn_mfma_f32_16x16x32_bf16(af[m][k], bfr[n][k], acc[m][n], 0, 0, 0);
    __builtin_amdgcn_s_setprio(0);
    SCHED0; __builtin_amdgcn_s_barrier(); SCHED0;

    // ========== p2: reads a4-7 | stage B0(T+2) | MFMA m4-7 x n0-1 ==========
    #pragma unroll
    for (int m = 4; m < 8; ++m){
      af[m][0] = *(const short8*)(Ab + arow0 + 8192 + (m - 4) * 1024 + ks0);
      af[m][1] = *(const short8*)(Ab + arow0 + 8192 + (m - 4) * 1024 + ks1);
    }
    if (T + 2 < nt){ STAGE_B(cb, 0, T + 2); }
    SCHED0; __builtin_amdgcn_s_barrier(); SCHED0;
    __builtin_amdgcn_s_setprio(1);
    #pragma unroll
    for (int k = 0; k < 2; ++k)
      #pragma unroll
      for (int m = 4; m < 8; ++m)
        #pragma unroll
        for (int n = 0; n < 2; ++n)
          acc[m][n] = __builtin_amdgcn_mfma_f32_16x16x32_bf16(af[m][k], bfr[n][k], acc[m][n], 0, 0, 0);
    __builtin_amdgcn_s_setprio(0);
    SCHED0; __builtin_amdgcn_s_barrier(); SCHED0;

    // ========== p3: stage B1(T+2); vmcnt(6) | MFMA m4-7 x n2-3 ==========
    if (T + 2 < nt){
      STAGE_B(cb, 1, T + 2);
      asm volatile("s_waitcnt vmcnt(6)" ::: "memory");   // tile T+1 fully landed
    } else {
      asm volatile("s_waitcnt vmcnt(0)" ::: "memory");   // tail drain
    }
    SCHED0; __builtin_amdgcn_s_barrier(); SCHED0;
    __builtin_amdgcn_s_setprio(1);
    #pragma unroll
    for (int k = 0; k < 2; ++k)
      #pragma unroll
      for (int m = 4; m < 8; ++m)
        #pragma unroll
        for (int n = 2; n < 4; ++n)
          acc[m][n] = __builtin_amdgcn_mfma_f32_16x16x32_bf16(af[m][k], bfr[n][k], acc[m][n], 0, 0, 0);
    __builtin_amdgcn_s_setprio(0);
    SCHED0; __builtin_amdgcn_s_barrier(); SCHED0;
  }

#undef STAGE_A
#undef STAGE_B
#undef SCHED0

  if (cbf16){
    unsigned short* Cb = (unsigned short*)Cv;
    #pragma unroll
    for (int mi = 0; mi < 8; ++mi){
      const int row = m0 + (mi & 3) * 16 + wr * 64 + (mi >> 2) * 128 + quad * 4;
      #pragma unroll
      for (int ni = 0; ni < 4; ++ni){
        const int col = n0 + (ni & 1) * 16 + wc * 32 + (ni >> 1) * 128 + l15;
        #pragma unroll
        for (int r = 0; r < 4; ++r)
          Cb[(size_t)(row + r) * N + col] = f2bf(acc[mi][ni][r]);
      }
    }
  } else {
    float* Cf = (float*)Cv;
    #pragma unroll
    for (int mi = 0; mi < 8; ++mi){
      const int row = m0 + (mi & 3) * 16 + wr * 64 + (mi >> 2) * 128 + quad * 4;
      #pragma unroll
      for (int ni = 0; ni < 4; ++ni){
        const int col = n0 + (ni & 1) * 16 + wc * 32 + (ni >> 1) * 128 + l15;
        #pragma unroll
        for (int r = 0; r < 4; ++r)
          Cf[(size_t)(row + r) * N + col] = acc[mi][ni][r];
      }
    }
  }
}

// ---------------- fused RoPE + kappa for Q and K (one launch) ----------------
__global__ void rope_fused(const unsigned short* __restrict__ lin,
                           unsigned short* __restrict__ Qk, unsigned short* __restrict__ Kk){
  int blk = blockIdx.x;
  if (blk < 32768){
    int idx = blk * 256 + threadIdx.x;    // B*S*NH*32 = 2^23 threads
    int i = idx & 31;
    int n = (idx >> 5) & (NH_ - 1);
    int s = (idx >> 10) & (S_ - 1);
    int b = idx >> 22;
    float invf = exp2f(-(float)i * (13.287712379549449f / 32.0f));  // 10000^(-i/32)
    float ang = (float)s * invf;
    float c = cosf(ang), sn = sinf(ang);
    size_t in_o = (size_t)(b * S_ + s) * NLIN_ + n * HD_;
    float x1 = bf2f(lin[in_o + i]);
    float x2 = bf2f(lin[in_o + i + 32]);
    float r1 = x1 * c - x2 * sn;
    float r2 = x2 * c + x1 * sn;
    r1 = r1 > 0.f ? r1 + 1.f : __expf(r1);
    r2 = r2 > 0.f ? r2 + 1.f : __expf(r2);
    size_t o = ((size_t)(b * NH_ + n) * S_ + s) * HD_;
    Qk[o + i] = f2bf(r1);
    Qk[o + i + 32] = f2bf(r2);
  } else {
    int idx = (blk - 32768) * 256 + threadIdx.x;   // B*S*NKV*32 = 2^21 threads
    int i = idx & 31;
    int kv = (idx >> 5) & (NKV_ - 1);
    int s = (idx >> 8) & (S_ - 1);
    int b = idx >> 20;
    float invf = exp2f(-(float)i * (13.287712379549449f / 32.0f));
    float ang = (float)s * invf;
    float c = cosf(ang), sn = sinf(ang);
    size_t in_o = (size_t)(b * S_ + s) * NLIN_ + 2048 + kv * HD_;
    float x1 = bf2f(lin[in_o + i]);
    float x2 = bf2f(lin[in_o + i + 32]);
    float r1 = x1 * c - x2 * sn;
    float r2 = x2 * c + x1 * sn;
    r1 = r1 > 0.f ? r1 + 1.f : __expf(r1);
    r2 = r2 > 0.f ? r2 + 1.f : __expf(r2);
    size_t o = ((size_t)(b * NKV_ + kv) * S_ + s) * HD_;
    Kk[o + i] = f2bf(r1);
    Kk[o + i + 32] = f2bf(r2);
  }
}

// ---------------- Qg[b,n,d] = mean_s Qk[b,n,s,d]  (split-S, atomics) ----------------
__global__ __launch_bounds__(256) void qg_mean(const unsigned short* __restrict__ Qk,
                                               float* __restrict__ Qg){
  int bn = blockIdx.x, chunk = blockIdx.y;     // 64 x 16
  int tid = threadIdx.x;
  int dgrp = tid & 7, sgrp = tid >> 3;         // 8 d-chunks x 32 s-rows
  const unsigned short* base = Qk + (size_t)bn * S_ * HD_
                             + (size_t)(chunk * 256 + sgrp) * HD_ + dgrp * 8;
  float acc[8] = {};
  #pragma unroll
  for (int i = 0; i < 8; i++){
    short8 v = *(const short8*)(base + (size_t)i * 32 * HD_);
    #pragma unroll
    for (int e = 0; e < 8; e++) acc[e] += bf2f((unsigned short)v[e]);
  }
  __shared__ float red[256][8];
  #pragma unroll
  for (int e = 0; e < 8; e++) red[tid][e] = acc[e];
  __syncthreads();
  if (tid < 64){
    int dg = tid >> 3, e = tid & 7;
    float s = 0.f;
    #pragma unroll
    for (int g = 0; g < 32; g++) s += red[g * 8 + dg][e];
    atomicAdd(&Qg[bn * 64 + tid], s * (1.0f / (float)S_));
  }
}

// ---------------- logits[b,n,s] = dot(Qg[b,n], Kk[b,kv,s]) ----------------
__global__ __launch_bounds__(256) void logits_kernel(const unsigned short* __restrict__ Kk,
                                                     const float* __restrict__ Qg,
                                                     float* __restrict__ logits){
  int bn = blockIdx.x, chunk = blockIdx.y;     // 64 x 16
  int b = bn / NH_, n = bn % NH_, kv = n / GROUPS_;
  int tid = threadIdx.x;
  __shared__ float qg[64];
  if (tid < 64) qg[tid] = Qg[bn * 64 + tid];
  __syncthreads();
  int s = chunk * 256 + tid;
  const unsigned short* row = Kk + ((size_t)(b * NKV_ + kv) * S_ + s) * HD_;
  float acc = 0.f;
  #pragma unroll
  for (int c = 0; c < 8; c++){
    short8 v = *(const short8*)(row + c * 8);
    #pragma unroll
    for (int e = 0; e < 8; e++) acc += qg[c * 8 + e] * bf2f((unsigned short)v[e]);
  }
  logits[(size_t)bn * S_ + s] = acc;
}

// ---------------- softmax * S over logits -> alpha (in place OK) ----------------
__global__ __launch_bounds__(256) void softmax_kernel(const float* __restrict__ logits,
                                                      float* __restrict__ alpha){
  int bn = blockIdx.x;
  int tid = threadIdx.x;
  float l[16];
  float mymax = -1e30f;
  #pragma unroll
  for (int j = 0; j < 16; j++){
    l[j] = logits[(size_t)bn * S_ + j * 256 + tid];
    mymax = fmaxf(mymax, l[j]);
  }
  __shared__ float red[256];
  red[tid] = mymax; __syncthreads();
  for (int st = 128; st > 0; st >>= 1){
    if (tid < st) red[tid] = fmaxf(red[tid], red[tid + st]);
    __syncthreads();
  }
  float gmax = red[0];
  __syncthreads();
  float mysum = 0.f;
  #pragma unroll
  for (int j = 0; j < 16; j++){ l[j] = __expf(l[j] - gmax); mysum += l[j]; }
  red[tid] = mysum; __syncthreads();
  for (int st = 128; st > 0; st >>= 1){
    if (tid < st) red[tid] += red[tid + st];
    __syncthreads();
  }
  float inv = (float)S_ / red[0];
  #pragma unroll
  for (int j = 0; j < 16; j++)
    alpha[(size_t)bn * S_ + j * 256 + tid] = l[j] * inv;
}

// ---------------- outer_sum: per (b,kv,chunk), all 4 GQA heads; V from lin cols 2560.. ----------------
__global__ __launch_bounds__(256) void outer_sum_kernel(const unsigned short* __restrict__ Kk,
                                                        const unsigned short* __restrict__ lin,
                                                        const float* __restrict__ alpha,
                                                        float* __restrict__ part){
  int bkv = blockIdx.x, chunk = blockIdx.y;     // 16 x NCH_
  int b = bkv >> 3, kv = bkv & 7;
  int tid = threadIdx.x;
  int d = tid >> 2, fb = (tid & 3) * 16;
  __shared__ float ks[64][64];   // [si][d]
  __shared__ float vs[64][64];   // [si][f]
  __shared__ float as4[64][4];   // [si][h] -- one b128 broadcast read per si
  float acc[4][16] = {};
  const unsigned short* kb = Kk + (size_t)(b * NKV_ + kv) * S_ * HD_;
  const int SPC = S_ / NCH_;     // 128 s per chunk

  for (int t = 0; t < SPC / 64; t++){
    int ss = chunk * SPC + t * 64;
    // stage K and V tiles (64x64 bf16 each) with short4 loads
    #pragma unroll
    for (int jj = 0; jj < 4; jj++){
      int idx4 = jj * 256 + tid;          // 1024 short4 chunks per tile
      int si = idx4 >> 4, c4 = (idx4 & 15) * 4;
      ushort4 kv4 = *(const ushort4*)(kb + (size_t)(ss + si) * HD_ + c4);
      ks[si][c4]   = bf2f(kv4.x); ks[si][c4+1] = bf2f(kv4.y);
      ks[si][c4+2] = bf2f(kv4.z); ks[si][c4+3] = bf2f(kv4.w);
      ushort4 vv4 = *(const ushort4*)(lin + (size_t)(b * S_ + ss + si) * NLIN_ + 2560 + kv * HD_ + c4);
      vs[si][c4]   = bf2f(vv4.x); vs[si][c4+1] = bf2f(vv4.y);
      vs[si][c4+2] = bf2f(vv4.z); vs[si][c4+3] = bf2f(vv4.w);
    }
    {
      int si = tid >> 2, h = tid & 3;
      as4[si][h] = alpha[(size_t)(b * NH_ + kv * GROUPS_ + h) * S_ + ss + si];
    }
    __syncthreads();
    #pragma unroll 4
    for (int si = 0; si < 64; si++){
      float k = ks[si][d];
      float4 a4 = *(const float4*)&as4[si][0];
      float4 v0 = *(const float4*)&vs[si][fb];
      float4 v1 = *(const float4*)&vs[si][fb + 4];
      float4 v2 = *(const float4*)&vs[si][fb + 8];
      float4 v3 = *(const float4*)&vs[si][fb + 12];
      float ak0 = a4.x * k, ak1 = a4.y * k, ak2 = a4.z * k, ak3 = a4.w * k;
      acc[0][0]  += ak0 * v0.x; acc[0][1]  += ak0 * v0.y; acc[0][2]  += ak0 * v0.z; acc[0][3]  += ak0 * v0.w;
      acc[0][4]  += ak0 * v1.x; acc[0][5]  += ak0 * v1.y; acc[0][6]  += ak0 * v1.z; acc[0][7]  += ak0 * v1.w;
      acc[0][8]  += ak0 * v2.x; acc[0][9]  += ak0 * v2.y; acc[0][10] += ak0 * v2.z; acc[0][11] += ak0 * v2.w;
      acc[0][12] += ak0 * v3.x; acc[0][13] += ak0 * v3.y; acc[0][14] += ak0 * v3.z; acc[0][15] += ak0 * v3.w;
      acc[1][0]  += ak1 * v0.x; acc[1][1]  += ak1 * v0.y; acc[1][2]  += ak1 * v0.z; acc[1][3]  += ak1 * v0.w;
      acc[1][4]  += ak1 * v1.x; acc[1][5]  += ak1 * v1.y; acc[1][6]  += ak1 * v1.z; acc[1][7]  += ak1 * v1.w;
      acc[1][8]  += ak1 * v2.x; acc[1][9]  += ak1 * v2.y; acc[1][10] += ak1 * v2.z; acc[1][11] += ak1 * v2.w;
      acc[1][12] += ak1 * v3.x; acc[1][13] += ak1 * v3.y; acc[1][14] += ak1 * v3.z; acc[1][15] += ak1 * v3.w;
      acc[2][0]  += ak2 * v0.x; acc[2][1]  += ak2 * v0.y; acc[2][2]  += ak2 * v0.z; acc[2][3]  += ak2 * v0.w;
      acc[2][4]  += ak2 * v1.x; acc[2][5]  += ak2 * v1.y; acc[2][6]  += ak2 * v1.z; acc[2][7]  += ak2 * v1.w;
      acc[2][8]  += ak2 * v2.x; acc[2][9]  += ak2 * v2.y; acc[2][10] += ak2 * v2.z; acc[2][11] += ak2 * v2.w;
      acc[2][12] += ak2 * v3.x; acc[2][13] += ak2 * v3.y; acc[2][14] += ak2 * v3.z; acc[2][15] += ak2 * v3.w;
      acc[3][0]  += ak3 * v0.x; acc[3][1]  += ak3 * v0.y; acc[3][2]  += ak3 * v0.z; acc[3][3]  += ak3 * v0.w;
      acc[3][4]  += ak3 * v1.x; acc[3][5]  += ak3 * v1.y; acc[3][6]  += ak3 * v1.z; acc[3][7]  += ak3 * v1.w;
      acc[3][8]  += ak3 * v2.x; acc[3][9]  += ak3 * v2.y; acc[3][10] += ak3 * v2.z; acc[3][11] += ak3 * v2.w;
      acc[3][12] += ak3 * v3.x; acc[3][13] += ak3 * v3.y; acc[3][14] += ak3 * v3.z; acc[3][15] += ak3 * v3.w;
    }
    __syncthreads();
  }

  #pragma unroll
  for (int h = 0; h < 4; h++){
    float* pb = part + ((size_t)(chunk * 16 + bkv) * 4 + h) * 4096 + d * 64 + fb;
    #pragma unroll
    for (int j = 0; j < 4; j++)
      *(float4*)&pb[j * 4] = *(float4*)&acc[h][j * 4];
  }
}

// ---------------- reduce partials over NCH_ chunks -> transposed split-bf16 osum ----------------
// osumb layout: [bn][plane][f][d] bf16, plane 0 = hi, plane 1 = lo (x - hi).
__global__ __launch_bounds__(256) void osum_reduce_t(const float* __restrict__ part,
                                                     unsigned short* __restrict__ osumb){
  int bn = blockIdx.x;            // 64
  int tid = threadIdx.x;
  __shared__ float os[64][65];
  const float4* p4 = (const float4*)part;
  #pragma unroll
  for (int r = 0; r < 4; r++){
    int idx4 = r * 256 + tid;     // float4 index within this bn's 1024
    float4 s = {0.f, 0.f, 0.f, 0.f};
    #pragma unroll 8
    for (int c = 0; c < NCH_; c++){
      float4 v = p4[(size_t)c * 65536 + bn * 1024 + idx4];
      s.x += v.x; s.y += v.y; s.z += v.z; s.w += v.w;
    }
    int d = idx4 >> 4;            // (idx4*4)/64
    int f0 = (idx4 & 15) * 4;
    os[d][f0] = s.x; os[d][f0+1] = s.y; os[d][f0+2] = s.z; os[d][f0+3] = s.w;
  }
  __syncthreads();
  int f = tid >> 2, d0 = (tid & 3) * 16;
  unsigned short hi[16], lo[16];
  #pragma unroll
  for (int j = 0; j < 16; j++){
    float x = os[d0 + j][f];
    unsigned short h = f2bf(x);
    hi[j] = h;
    lo[j] = f2bf(x - bf2f(h));
  }
  unsigned short* oh = osumb + ((size_t)bn * 2) * 4096 + (size_t)f * 64 + d0;
  unsigned short* ol = oh + 4096;
  *(short8*)(oh)     = *(const short8*)(hi);
  *(short8*)(oh + 8) = *(const short8*)(hi + 8);
  *(short8*)(ol)     = *(const short8*)(lo);
  *(short8*)(ol + 8) = *(const short8*)(lo + 8);
}

// ---------------- ctx via MFMA: R = Qk @ osum (hi+lo), ctx = bf16(Xphi * R) ----------------
// Xphi read from lin cols 3072.., stride NLIN_.
__global__ __launch_bounds__(256) void ctx_mfma(const unsigned short* __restrict__ Qk,
                                                const unsigned short* __restrict__ osumb,
                                                const unsigned short* __restrict__ lin,
                                                unsigned short* __restrict__ ctx){
  int bn = blockIdx.x, sc = blockIdx.y;   // 64 x 16
  int b = bn >> 5, n = bn & 31;
  int tid = threadIdx.x;
  int w = tid >> 6, lane = tid & 63;
  int l15 = lane & 15, quad = lane >> 4;

  const unsigned short* obase = osumb + ((size_t)bn * 2) * 4096;
  short8 bh[4][2], bl[4][2];
  #pragma unroll
  for (int nf = 0; nf < 4; nf++){
    int f = nf * 16 + l15;
    #pragma unroll
    for (int kh = 0; kh < 2; kh++){
      bh[nf][kh] = *(const short8*)(obase + (size_t)f * 64 + kh * 32 + quad * 8);
      bl[nf][kh] = *(const short8*)(obase + 4096 + (size_t)f * 64 + kh * 32 + quad * 8);
    }
  }

  int s0 = sc * 256 + w * 64;
  const unsigned short* qbase = Qk + ((size_t)bn * S_ + s0) * HD_;
  floatx4 acc[4][4] = {};
  #pragma unroll
  for (int m = 0; m < 4; m++){
    short8 a0 = *(const short8*)(qbase + (size_t)(m * 16 + l15) * HD_ + quad * 8);
    short8 a1 = *(const short8*)(qbase + (size_t)(m * 16 + l15) * HD_ + 32 + quad * 8);
    #pragma unroll
    for (int nf = 0; nf < 4; nf++){
      acc[m][nf] = __builtin_amdgcn_mfma_f32_16x16x32_bf16(a0, bh[nf][0], acc[m][nf], 0, 0, 0);
      acc[m][nf] = __builtin_amdgcn_mfma_f32_16x16x32_bf16(a1, bh[nf][1], acc[m][nf], 0, 0, 0);
      acc[m][nf] = __builtin_amdgcn_mfma_f32_16x16x32_bf16(a0, bl[nf][0], acc[m][nf], 0, 0, 0);
      acc[m][nf] = __builtin_amdgcn_mfma_f32_16x16x32_bf16(a1, bl[nf][1], acc[m][nf], 0, 0, 0);
    }
  }

  // epilogue: C/D mapping col=l15, row=quad*4+r; multiply by Xphi (bf16), store bf16
  #pragma unroll
  for (int m = 0; m < 4; m++){
    #pragma unroll
    for (int r = 0; r < 4; r++){
      int s = s0 + m * 16 + quad * 4 + r;
      const unsigned short* xp = lin + (size_t)(b * S_ + s) * NLIN_ + 3072 + n * HD_;
      unsigned short* cp = ctx + (size_t)(b * S_ + s) * HID_ + n * HD_;
      #pragma unroll
      for (int nf = 0; nf < 4; nf++){
        int f = nf * 16 + l15;
        cp[f] = f2bf(bf2f(xp[f]) * acc[m][nf][r]);
      }
    }
  }
}

extern "C" void kernel_launch(void* const* d_in, const int* in_sizes, int n_in,
                              void* d_out, int out_size, void* d_ws, size_t ws_size,
                              hipStream_t stream) {
  const float* hs   = (const float*)d_in[0];
  const float* Wq   = (const float*)d_in[1];
  const float* Wk   = (const float*)d_in[2];
  const float* Wv   = (const float*)d_in[3];
  const float* Wphi = (const float*)d_in[4];
  const float* Wo   = (const float*)d_in[5];
  float* out = (float*)d_out;

  char* ws = (char*)d_ws;
  const size_t M = (size_t)B_ * S_;          // 8192
  size_t off = 0;
  auto alloc = [&](size_t bytes){ size_t o = off; off += (bytes + 255) & ~(size_t)255; return o; };

  // region X (32MB): hsb bf16 -> part fp32 -> ctx bf16 (strictly sequential lifetimes)
  size_t off_x     = alloc(M * HID_ * 4);                 // 32MB (fp32-part sized)
  size_t off_wcat  = alloc((size_t)NLIN_ * HID_ * 2);     // 20MB  [Wq^T; Wk^T; Wv^T; Wphi^T]
  size_t off_wot   = alloc((size_t)HID_ * HID_ * 2);      // 8MB
  size_t off_lin   = alloc(M * NLIN_ * 2);                // 80MB bf16 fused Q|K|V|phi
  size_t off_qk    = alloc(M * HID_ * 2);                 // 32MB bf16 [B,NH,S,D]
  size_t off_kk    = alloc(M * 512 * 2);                  // 8MB  bf16 [B,NKV,S,D]
  size_t off_qg    = alloc(64 * 64 * 4);
  size_t off_alph  = alloc((size_t)B_ * NH_ * S_ * 4);    // 1MB
  size_t off_osumb = alloc((size_t)64 * 2 * 4096 * 2);    // 1MB split-bf16 osum^T
  (void)ws_size;

  unsigned short* hsb  = (unsigned short*)(ws + off_x);
  float*          part = (float*)(ws + off_x);
  unsigned short* ctx  = (unsigned short*)(ws + off_x);
  unsigned short* wcat = (unsigned short*)(ws + off_wcat);
  unsigned short* wot  = (unsigned short*)(ws + off_wot);
  unsigned short* lin  = (unsigned short*)(ws + off_lin);
  unsigned short* qk = (unsigned short*)(ws + off_qk);
  unsigned short* kk = (unsigned short*)(ws + off_kk);
  float* qg   = (float*)(ws + off_qg);
  float* alph = (float*)(ws + off_alph);
  unsigned short* osumb = (unsigned short*)(ws + off_osumb);

  // 1. hs -> bf16 (into X)
  conv_bf16<<<(int)(M * HID_ / 4 / 256), 256, 0, stream>>>(hs, hsb, (int)(M * HID_ / 4));
  // 2. all weight transposes in one launch
  transpose_all<<<dim3(64, 64, 5), dim3(32, 8), 0, stream>>>(Wq, Wk, Wv, Wphi, Wo, wcat, wot);
  // 3. fused Q|K|V|phi projection (bf16 C)
  gemm256<<<dim3(NLIN_/256, M/256), 512, 0, stream>>>(hsb, wcat, lin, (int)M, NLIN_, HID_, 1);
  // 4. fused RoPE + kappa for Q and K
  rope_fused<<<32768 + 8192, 256, 0, stream>>>(lin, qk, kk);
  // 5. global query (split-S + atomics)
  hipMemsetAsync(qg, 0, 64 * 64 * 4, stream);
  qg_mean<<<dim3(B_ * NH_, S_ / 256), 256, 0, stream>>>(qk, qg);
  // 6. logits + softmax * S
  logits_kernel<<<dim3(B_ * NH_, S_ / 256), 256, 0, stream>>>(kk, qg, alph);
  softmax_kernel<<<B_ * NH_, 256, 0, stream>>>(alph, alph);
  // 7. outer_sum (partials into X — hsb dead after fused gemm) + transposed split-bf16 reduce
  outer_sum_kernel<<<dim3(B_ * NKV_, NCH_), 256, 0, stream>>>(kk, lin, alph, part);
  osum_reduce_t<<<64, 256, 0, stream>>>(part, osumb);
  // 8. ctx = Xphi * (Qk @ osum) -> bf16 into X (part dead after reduce)
  ctx_mfma<<<dim3(B_ * NH_, S_ / 64 / 4), 256, 0, stream>>>(qk, osumb, lin, ctx);
  // 9. out = ctx @ Wo (fp32 C)
  gemm256<<<dim3(HID_/256, M/256), 512, 0, stream>>>(ctx, wot, out, (int)M, HID_, HID_, 0);
}

// Round 9
// 515.464 us; speedup vs baseline: 1.4314x; 1.0022x over previous
//
#include <hip/hip_runtime.h>
#include <hip/hip_bf16.h>

#define B_ 2
#define S_ 4096
#define HID_ 2048
#define NH_ 32
#define NKV_ 8
#define HD_ 64
#define GROUPS_ 4
#define NCH_ 32   // outer_sum S-chunks
#define NLIN_ 5120  // fused projection width: Q 0..2047 | K 2048..2559 | V 2560..3071 | phi 3072..5119

typedef short short8 __attribute__((ext_vector_type(8)));
typedef float floatx4 __attribute__((ext_vector_type(4)));

__device__ __forceinline__ float bf2f(unsigned short u){
  union { unsigned int i; float f; } v; v.i = ((unsigned int)u) << 16; return v.f;
}
__device__ __forceinline__ unsigned short f2bf(float f){
  union { float f; unsigned int i; } v; v.f = f;
  unsigned int i = v.i;
  unsigned int r = (i + 0x7fffu + ((i >> 16) & 1u)) >> 16;  // RNE
  return (unsigned short)r;
}

// async global->LDS, 16B per lane, LDS dest = wave-uniform base + lane*16
__device__ __forceinline__ void async_copy16(unsigned short* lds, const unsigned short* g){
  __builtin_amdgcn_global_load_lds((const __attribute__((address_space(1))) void*)g,
                                   (__attribute__((address_space(3))) void*)lds,
                                   16, 0, 0);
}

// ---------------- fp32 -> bf16 bulk convert (hidden_states) ----------------
__global__ void conv_bf16(const float* __restrict__ x, unsigned short* __restrict__ y, int n4){
  int i = blockIdx.x * 256 + threadIdx.x;
  if (i < n4){
    float4 v = ((const float4*)x)[i];
    ushort4 o;
    o.x = f2bf(v.x); o.y = f2bf(v.y); o.z = f2bf(v.z); o.w = f2bf(v.w);
    ((ushort4*)y)[i] = o;
  }
}

// ---------------- all 5 weight transposes in one launch (z selects) ----------------
__global__ void transpose_all(const float* __restrict__ Wq, const float* __restrict__ Wk,
                              const float* __restrict__ Wv, const float* __restrict__ Wphi,
                              const float* __restrict__ Wo,
                              unsigned short* __restrict__ wcat, unsigned short* __restrict__ wot){
  const float* W; unsigned short* Wt; int N;
  switch (blockIdx.z){
    case 0:  W = Wq;   Wt = wcat;                              N = 2048; break;
    case 1:  W = Wk;   Wt = wcat + (size_t)2048 * HID_;        N = 512;  break;
    case 2:  W = Wv;   Wt = wcat + (size_t)2560 * HID_;        N = 512;  break;
    case 3:  W = Wphi; Wt = wcat + (size_t)3072 * HID_;        N = 2048; break;
    default: W = Wo;   Wt = wot;                               N = 2048; break;
  }
  int n0 = blockIdx.x * 32, k0 = blockIdx.y * 32;
  if (n0 >= N) return;
  __shared__ float tile[32][33];
  int tx = threadIdx.x, ty = threadIdx.y;   // 32 x 8
  #pragma unroll
  for (int j = 0; j < 4; j++)
    tile[ty + j*8][tx] = W[(size_t)(k0 + ty + j*8) * N + n0 + tx];
  __syncthreads();
  #pragma unroll
  for (int j = 0; j < 4; j++)
    Wt[(size_t)(n0 + ty + j*8) * HID_ + k0 + tx] = f2bf(tile[tx][ty + j*8]);
}

// ---------------- 256x256-tile 4-phase interleaved GEMM: C = A[M,K]bf16 @ Bt[N,K]^T ----------------
// R7-proven schedule (195 us fused). Unchanged this round.
#define GTILE 16384   // 256*64 bf16 elements per operand per buffer

__global__ __launch_bounds__(512, 2) void gemm256(
    const unsigned short* __restrict__ A, const unsigned short* __restrict__ Bt,
    void* __restrict__ Cv, int M, int N, int K, int cbf16)
{
  __shared__ __align__(16) unsigned short As[2 * GTILE];
  __shared__ __align__(16) unsigned short Bs[2 * GTILE];

  const int tid = threadIdx.x;
  const int w = tid >> 6, lane = tid & 63;
  const int wr = w >> 2, wc = w & 3;
  const int l15 = lane & 15, quad = lane >> 4;

  // bijective XCD-aware swizzle (nwg % 8 == 0 for all shapes here)
  const int nbx = N >> 8;
  int flat = blockIdx.y * nbx + blockIdx.x;
  int nwg  = nbx * (M >> 8);
  int cpx  = nwg >> 3;
  int swz  = (flat & 7) * cpx + (flat >> 3);
  int bx = swz % nbx, by = swz / nbx;
  const int m0 = by << 8, n0 = bx << 8;

  // ---- staging addressing (per wave-call: 64 lanes x 16B = 512 shorts linear in LDS) ----
  const int srow = (w << 3) + (lane >> 3);          // row 0..63 within a 64-row call
  const int scc  = (lane & 7) ^ (lane >> 3);        // swizzled 16B chunk within 128B row
  const unsigned short* gA = A  + (size_t)(m0 + srow) * K + scc * 8;
  const unsigned short* gB = Bt + (size_t)(n0 + srow) * K + scc * 8;
  const size_t rs64  = (size_t)64  * K;             // second-call row offset
  const size_t rs128 = (size_t)128 * K;             // half-tile row offset
  unsigned short* lA0 = As + (w << 9);
  unsigned short* lB0 = Bs + (w << 9);

#define STAGE_A(bsel, h, t) do { \
    unsigned short* _d = lA0 + (bsel) * GTILE + (h) * 8192; \
    const unsigned short* _g = gA + (size_t)(h) * rs128 + (size_t)(t) * 64; \
    async_copy16(_d, _g); \
    async_copy16(_d + 4096, _g + rs64); \
  } while (0)
#define STAGE_B(bsel, h, t) do { \
    unsigned short* _d = lB0 + (bsel) * GTILE + (h) * 8192; \
    const unsigned short* _g = gB + (size_t)(h) * rs128 + (size_t)(t) * 64; \
    async_copy16(_d, _g); \
    async_copy16(_d + 4096, _g + rs64); \
  } while (0)
#define SCHED0 __builtin_amdgcn_sched_barrier(0)

  // ---- fragment read offsets (shorts): row*64 + ((kchunk ^ (row&7))<<3); row&7 == lane&7 ----
  const int ks0  = ((quad     ^ (lane & 7)) << 3);
  const int ks1  = (((4+quad) ^ (lane & 7)) << 3);
  const int arow0 = (wr * 64 + l15) * 64;   // af[m]: + (m&3)*1024 + (m>>2)*8192
  const int brow0 = (wc * 32 + l15) * 64;   // bfr[n]: + (n&1)*1024 + (n>>1)*8192

  floatx4 acc[8][4] = {};
  short8 af[8][2], bfr[4][2];

  const int nt = K >> 6;

  // ---- prologue: full tile0 + tile1 {A0,B0,B1}; tile1's A1 comes from t0-p0's stage ----
  STAGE_A(0, 0, 0); STAGE_A(0, 1, 0); STAGE_B(0, 0, 0); STAGE_B(0, 1, 0);
  if (nt > 1){
    STAGE_A(1, 0, 1); STAGE_B(1, 0, 1); STAGE_B(1, 1, 1);
    asm volatile("s_waitcnt vmcnt(6)" ::: "memory");   // tile0's 8 confirmed
  } else {
    asm volatile("s_waitcnt vmcnt(0)" ::: "memory");
  }
  SCHED0;
  __builtin_amdgcn_s_barrier();
  SCHED0;

  for (int T = 0; T < nt; ++T){
    const int cb = T & 1;
    const unsigned short* Ab = As + cb * GTILE;
    const unsigned short* Bb = Bs + cb * GTILE;

    // ========== p0: reads a0-3,b0-1 | stage A1(T+1) -> buf^1 | MFMA m0-3 x n0-1 ==========
    #pragma unroll
    for (int m = 0; m < 4; ++m){
      af[m][0] = *(const short8*)(Ab + arow0 + m * 1024 + ks0);
      af[m][1] = *(const short8*)(Ab + arow0 + m * 1024 + ks1);
    }
    #pragma unroll
    for (int n = 0; n < 2; ++n){
      bfr[n][0] = *(const short8*)(Bb + brow0 + n * 1024 + ks0);
      bfr[n][1] = *(const short8*)(Bb + brow0 + n * 1024 + ks1);
    }
    if (T + 1 < nt){ STAGE_A(cb ^ 1, 1, T + 1); }
    SCHED0; __builtin_amdgcn_s_barrier(); SCHED0;
    __builtin_amdgcn_s_setprio(1);
    #pragma unroll
    for (int k = 0; k < 2; ++k)
      #pragma unroll
      for (int m = 0; m < 4; ++m)
        #pragma unroll
        for (int n = 0; n < 2; ++n)
          acc[m][n] = __builtin_amdgcn_mfma_f32_16x16x32_bf16(af[m][k], bfr[n][k], acc[m][n], 0, 0, 0);
    __builtin_amdgcn_s_setprio(0);
    SCHED0; __builtin_amdgcn_s_barrier(); SCHED0;

    // ========== p1: reads b2-3 | stage A0(T+2) | MFMA m0-3 x n2-3 ==========
    #pragma unroll
    for (int n = 2; n < 4; ++n){
      bfr[n][0] = *(const short8*)(Bb + brow0 + 8192 + (n - 2) * 1024 + ks0);
      bfr[n][1] = *(const short8*)(Bb + brow0 + 8192 + (n - 2) * 1024 + ks1);
    }
    if (T + 2 < nt){ STAGE_A(cb, 0, T + 2); }
    SCHED0; __builtin_amdgcn_s_barrier(); SCHED0;
    __builtin_amdgcn_s_setprio(1);
    #pragma unroll
    for (int k = 0; k < 2; ++k)
      #pragma unroll
      for (int m = 0; m < 4; ++m)
        #pragma unroll
        for (int n = 2; n < 4; ++n)
          acc[m][n] = __builtin_amdgcn_mfma_f32_16x16x32_bf16(af[m][k], bfr[n][k], acc[m][n], 0, 0, 0);
    __builtin_amdgcn_s_setprio(0);
    SCHED0; __builtin_amdgcn_s_barrier(); SCHED0;

    // ========== p2: reads a4-7 | stage B0(T+2) | MFMA m4-7 x n0-1 ==========
    #pragma unroll
    for (int m = 4; m < 8; ++m){
      af[m][0] = *(const short8*)(Ab + arow0 + 8192 + (m - 4) * 1024 + ks0);
      af[m][1] = *(const short8*)(Ab + arow0 + 8192 + (m - 4) * 1024 + ks1);
    }
    if (T + 2 < nt){ STAGE_B(cb, 0, T + 2); }
    SCHED0; __builtin_amdgcn_s_barrier(); SCHED0;
    __builtin_amdgcn_s_setprio(1);
    #pragma unroll
    for (int k = 0; k < 2; ++k)
      #pragma unroll
      for (int m = 4; m < 8; ++m)
        #pragma unroll
        for (int n = 0; n < 2; ++n)
          acc[m][n] = __builtin_amdgcn_mfma_f32_16x16x32_bf16(af[m][k], bfr[n][k], acc[m][n], 0, 0, 0);
    __builtin_amdgcn_s_setprio(0);
    SCHED0; __builtin_amdgcn_s_barrier(); SCHED0;

    // ========== p3: stage B1(T+2); vmcnt(6) | MFMA m4-7 x n2-3 ==========
    if (T + 2 < nt){
      STAGE_B(cb, 1, T + 2);
      asm volatile("s_waitcnt vmcnt(6)" ::: "memory");   // tile T+1 fully landed
    } else {
      asm volatile("s_waitcnt vmcnt(0)" ::: "memory");   // tail drain
    }
    SCHED0; __builtin_amdgcn_s_barrier(); SCHED0;
    __builtin_amdgcn_s_setprio(1);
    #pragma unroll
    for (int k = 0; k < 2; ++k)
      #pragma unroll
      for (int m = 4; m < 8; ++m)
        #pragma unroll
        for (int n = 2; n < 4; ++n)
          acc[m][n] = __builtin_amdgcn_mfma_f32_16x16x32_bf16(af[m][k], bfr[n][k], acc[m][n], 0, 0, 0);
    __builtin_amdgcn_s_setprio(0);
    SCHED0; __builtin_amdgcn_s_barrier(); SCHED0;
  }

#undef STAGE_A
#undef STAGE_B
#undef SCHED0

  if (cbf16){
    unsigned short* Cb = (unsigned short*)Cv;
    #pragma unroll
    for (int mi = 0; mi < 8; ++mi){
      const int row = m0 + (mi & 3) * 16 + wr * 64 + (mi >> 2) * 128 + quad * 4;
      #pragma unroll
      for (int ni = 0; ni < 4; ++ni){
        const int col = n0 + (ni & 1) * 16 + wc * 32 + (ni >> 1) * 128 + l15;
        #pragma unroll
        for (int r = 0; r < 4; ++r)
          Cb[(size_t)(row + r) * N + col] = f2bf(acc[mi][ni][r]);
      }
    }
  } else {
    float* Cf = (float*)Cv;
    #pragma unroll
    for (int mi = 0; mi < 8; ++mi){
      const int row = m0 + (mi & 3) * 16 + wr * 64 + (mi >> 2) * 128 + quad * 4;
      #pragma unroll
      for (int ni = 0; ni < 4; ++ni){
        const int col = n0 + (ni & 1) * 16 + wc * 32 + (ni >> 1) * 128 + l15;
        #pragma unroll
        for (int r = 0; r < 4; ++r)
          Cf[(size_t)(row + r) * N + col] = acc[mi][ni][r];
      }
    }
  }
}

// ---------------- fused RoPE + kappa for Q (with Qg mean) and K (one launch) ----------------
// grid (80, 16): x<64 -> Q path (bn = x), else K path (bkv = x-64). 256 threads:
// i = tid&31 (freq), si = tid>>5 (8 s-lanes). Each thread: 32 s-values, one __sincosf
// per (r1,r2) pair. Q path accumulates per-d partial sums -> LDS reduce -> 1 atomicAdd/d.
__global__ __launch_bounds__(256) void rope_fused(const unsigned short* __restrict__ lin,
                                                  unsigned short* __restrict__ Qk,
                                                  unsigned short* __restrict__ Kk,
                                                  float* __restrict__ Qg){
  int bx = blockIdx.x, sc = blockIdx.y;
  int tid = threadIdx.x;
  int i = tid & 31, si = tid >> 5;
  float invf = exp2f(-(float)i * (13.287712379549449f / 32.0f));  // 10000^(-i/32)
  if (bx < 64){
    int bn = bx, b = bx >> 5, n = bx & 31;
    float qa0 = 0.f, qa1 = 0.f;
    for (int j = 0; j < 32; ++j){
      int s = sc * 256 + j * 8 + si;
      size_t in_o = (size_t)(b * S_ + s) * NLIN_ + n * HD_;
      float x1 = bf2f(lin[in_o + i]);
      float x2 = bf2f(lin[in_o + i + 32]);
      float sn, c;
      __sincosf((float)s * invf, &sn, &c);
      float r1 = x1 * c - x2 * sn;
      float r2 = x2 * c + x1 * sn;
      r1 = r1 > 0.f ? r1 + 1.f : __expf(r1);
      r2 = r2 > 0.f ? r2 + 1.f : __expf(r2);
      size_t o = ((size_t)bn * S_ + s) * HD_;
      Qk[o + i] = f2bf(r1);
      Qk[o + i + 32] = f2bf(r2);
      qa0 += r1; qa1 += r2;
    }
    __shared__ float red[8][64];
    red[si][i] = qa0;
    red[si][i + 32] = qa1;
    __syncthreads();
    if (tid < 64){
      float ssum = 0.f;
      #pragma unroll
      for (int g = 0; g < 8; ++g) ssum += red[g][tid];
      atomicAdd(&Qg[bn * 64 + tid], ssum * (1.0f / (float)S_));
    }
  } else {
    int bkv = bx - 64, b = bkv >> 3, kv = bkv & 7;
    for (int j = 0; j < 32; ++j){
      int s = sc * 256 + j * 8 + si;
      size_t in_o = (size_t)(b * S_ + s) * NLIN_ + 2048 + kv * HD_;
      float x1 = bf2f(lin[in_o + i]);
      float x2 = bf2f(lin[in_o + i + 32]);
      float sn, c;
      __sincosf((float)s * invf, &sn, &c);
      float r1 = x1 * c - x2 * sn;
      float r2 = x2 * c + x1 * sn;
      r1 = r1 > 0.f ? r1 + 1.f : __expf(r1);
      r2 = r2 > 0.f ? r2 + 1.f : __expf(r2);
      size_t o = ((size_t)(b * NKV_ + kv) * S_ + s) * HD_;
      Kk[o + i] = f2bf(r1);
      Kk[o + i + 32] = f2bf(r2);
    }
  }
}

// ---------------- logits[b,n,s] = dot(Qg[b,n], Kk[b,kv,s]) ----------------
__global__ __launch_bounds__(256) void logits_kernel(const unsigned short* __restrict__ Kk,
                                                     const float* __restrict__ Qg,
                                                     float* __restrict__ logits){
  int bn = blockIdx.x, chunk = blockIdx.y;     // 64 x 16
  int b = bn / NH_, n = bn % NH_, kv = n / GROUPS_;
  int tid = threadIdx.x;
  __shared__ float qg[64];
  if (tid < 64) qg[tid] = Qg[bn * 64 + tid];
  __syncthreads();
  int s = chunk * 256 + tid;
  const unsigned short* row = Kk + ((size_t)(b * NKV_ + kv) * S_ + s) * HD_;
  float acc = 0.f;
  #pragma unroll
  for (int c = 0; c < 8; c++){
    short8 v = *(const short8*)(row + c * 8);
    #pragma unroll
    for (int e = 0; e < 8; e++) acc += qg[c * 8 + e] * bf2f((unsigned short)v[e]);
  }
  logits[(size_t)bn * S_ + s] = acc;
}

// ---------------- softmax * S over logits -> alpha (in place OK) ----------------
__global__ __launch_bounds__(256) void softmax_kernel(const float* __restrict__ logits,
                                                      float* __restrict__ alpha){
  int bn = blockIdx.x;
  int tid = threadIdx.x;
  float l[16];
  float mymax = -1e30f;
  #pragma unroll
  for (int j = 0; j < 16; j++){
    l[j] = logits[(size_t)bn * S_ + j * 256 + tid];
    mymax = fmaxf(mymax, l[j]);
  }
  __shared__ float red[256];
  red[tid] = mymax; __syncthreads();
  for (int st = 128; st > 0; st >>= 1){
    if (tid < st) red[tid] = fmaxf(red[tid], red[tid + st]);
    __syncthreads();
  }
  float gmax = red[0];
  __syncthreads();
  float mysum = 0.f;
  #pragma unroll
  for (int j = 0; j < 16; j++){ l[j] = __expf(l[j] - gmax); mysum += l[j]; }
  red[tid] = mysum; __syncthreads();
  for (int st = 128; st > 0; st >>= 1){
    if (tid < st) red[tid] += red[tid + st];
    __syncthreads();
  }
  float inv = (float)S_ / red[0];
  #pragma unroll
  for (int j = 0; j < 16; j++)
    alpha[(size_t)bn * S_ + j * 256 + tid] = l[j] * inv;
}

// ---------------- outer_sum: per (b,kv,chunk), all 4 GQA heads; V from lin cols 2560.. ----------------
__global__ __launch_bounds__(256) void outer_sum_kernel(const unsigned short* __restrict__ Kk,
                                                        const unsigned short* __restrict__ lin,
                                                        const float* __restrict__ alpha,
                                                        float* __restrict__ part){
  int bkv = blockIdx.x, chunk = blockIdx.y;     // 16 x NCH_
  int b = bkv >> 3, kv = bkv & 7;
  int tid = threadIdx.x;
  int d = tid >> 2, fb = (tid & 3) * 16;
  __shared__ float ks[64][64];   // [si][d]
  __shared__ float vs[64][64];   // [si][f]
  __shared__ float as4[64][4];   // [si][h] -- one b128 broadcast read per si
  float acc[4][16] = {};
  const unsigned short* kb = Kk + (size_t)(b * NKV_ + kv) * S_ * HD_;
  const int SPC = S_ / NCH_;     // 128 s per chunk

  for (int t = 0; t < SPC / 64; t++){
    int ss = chunk * SPC + t * 64;
    // stage K and V tiles (64x64 bf16 each) with short4 loads
    #pragma unroll
    for (int jj = 0; jj < 4; jj++){
      int idx4 = jj * 256 + tid;          // 1024 short4 chunks per tile
      int si = idx4 >> 4, c4 = (idx4 & 15) * 4;
      ushort4 kv4 = *(const ushort4*)(kb + (size_t)(ss + si) * HD_ + c4);
      ks[si][c4]   = bf2f(kv4.x); ks[si][c4+1] = bf2f(kv4.y);
      ks[si][c4+2] = bf2f(kv4.z); ks[si][c4+3] = bf2f(kv4.w);
      ushort4 vv4 = *(const ushort4*)(lin + (size_t)(b * S_ + ss + si) * NLIN_ + 2560 + kv * HD_ + c4);
      vs[si][c4]   = bf2f(vv4.x); vs[si][c4+1] = bf2f(vv4.y);
      vs[si][c4+2] = bf2f(vv4.z); vs[si][c4+3] = bf2f(vv4.w);
    }
    {
      int si = tid >> 2, h = tid & 3;
      as4[si][h] = alpha[(size_t)(b * NH_ + kv * GROUPS_ + h) * S_ + ss + si];
    }
    __syncthreads();
    #pragma unroll 4
    for (int si = 0; si < 64; si++){
      float k = ks[si][d];
      float4 a4 = *(const float4*)&as4[si][0];
      float4 v0 = *(const float4*)&vs[si][fb];
      float4 v1 = *(const float4*)&vs[si][fb + 4];
      float4 v2 = *(const float4*)&vs[si][fb + 8];
      float4 v3 = *(const float4*)&vs[si][fb + 12];
      float ak0 = a4.x * k, ak1 = a4.y * k, ak2 = a4.z * k, ak3 = a4.w * k;
      acc[0][0]  += ak0 * v0.x; acc[0][1]  += ak0 * v0.y; acc[0][2]  += ak0 * v0.z; acc[0][3]  += ak0 * v0.w;
      acc[0][4]  += ak0 * v1.x; acc[0][5]  += ak0 * v1.y; acc[0][6]  += ak0 * v1.z; acc[0][7]  += ak0 * v1.w;
      acc[0][8]  += ak0 * v2.x; acc[0][9]  += ak0 * v2.y; acc[0][10] += ak0 * v2.z; acc[0][11] += ak0 * v2.w;
      acc[0][12] += ak0 * v3.x; acc[0][13] += ak0 * v3.y; acc[0][14] += ak0 * v3.z; acc[0][15] += ak0 * v3.w;
      acc[1][0]  += ak1 * v0.x; acc[1][1]  += ak1 * v0.y; acc[1][2]  += ak1 * v0.z; acc[1][3]  += ak1 * v0.w;
      acc[1][4]  += ak1 * v1.x; acc[1][5]  += ak1 * v1.y; acc[1][6]  += ak1 * v1.z; acc[1][7]  += ak1 * v1.w;
      acc[1][8]  += ak1 * v2.x; acc[1][9]  += ak1 * v2.y; acc[1][10] += ak1 * v2.z; acc[1][11] += ak1 * v2.w;
      acc[1][12] += ak1 * v3.x; acc[1][13] += ak1 * v3.y; acc[1][14] += ak1 * v3.z; acc[1][15] += ak1 * v3.w;
      acc[2][0]  += ak2 * v0.x; acc[2][1]  += ak2 * v0.y; acc[2][2]  += ak2 * v0.z; acc[2][3]  += ak2 * v0.w;
      acc[2][4]  += ak2 * v1.x; acc[2][5]  += ak2 * v1.y; acc[2][6]  += ak2 * v1.z; acc[2][7]  += ak2 * v1.w;
      acc[2][8]  += ak2 * v2.x; acc[2][9]  += ak2 * v2.y; acc[2][10] += ak2 * v2.z; acc[2][11] += ak2 * v2.w;
      acc[2][12] += ak2 * v3.x; acc[2][13] += ak2 * v3.y; acc[2][14] += ak2 * v3.z; acc[2][15] += ak2 * v3.w;
      acc[3][0]  += ak3 * v0.x; acc[3][1]  += ak3 * v0.y; acc[3][2]  += ak3 * v0.z; acc[3][3]  += ak3 * v0.w;
      acc[3][4]  += ak3 * v1.x; acc[3][5]  += ak3 * v1.y; acc[3][6]  += ak3 * v1.z; acc[3][7]  += ak3 * v1.w;
      acc[3][8]  += ak3 * v2.x; acc[3][9]  += ak3 * v2.y; acc[3][10] += ak3 * v2.z; acc[3][11] += ak3 * v2.w;
      acc[3][12] += ak3 * v3.x; acc[3][13] += ak3 * v3.y; acc[3][14] += ak3 * v3.z; acc[3][15] += ak3 * v3.w;
    }
    __syncthreads();
  }

  #pragma unroll
  for (int h = 0; h < 4; h++){
    float* pb = part + ((size_t)(chunk * 16 + bkv) * 4 + h) * 4096 + d * 64 + fb;
    #pragma unroll
    for (int j = 0; j < 4; j++)
      *(float4*)&pb[j * 4] = *(float4*)&acc[h][j * 4];
  }
}

// ---------------- reduce partials over NCH_ chunks -> transposed split-bf16 osum ----------------
// osumb layout: [bn][plane][f][d] bf16, plane 0 = hi, plane 1 = lo (x - hi).
__global__ __launch_bounds__(256) void osum_reduce_t(const float* __restrict__ part,
                                                     unsigned short* __restrict__ osumb){
  int bn = blockIdx.x;            // 64
  int tid = threadIdx.x;
  __shared__ float os[64][65];
  const float4* p4 = (const float4*)part;
  #pragma unroll
  for (int r = 0; r < 4; r++){
    int idx4 = r * 256 + tid;     // float4 index within this bn's 1024
    float4 s = {0.f, 0.f, 0.f, 0.f};
    #pragma unroll 8
    for (int c = 0; c < NCH_; c++){
      float4 v = p4[(size_t)c * 65536 + bn * 1024 + idx4];
      s.x += v.x; s.y += v.y; s.z += v.z; s.w += v.w;
    }
    int d = idx4 >> 4;            // (idx4*4)/64
    int f0 = (idx4 & 15) * 4;
    os[d][f0] = s.x; os[d][f0+1] = s.y; os[d][f0+2] = s.z; os[d][f0+3] = s.w;
  }
  __syncthreads();
  int f = tid >> 2, d0 = (tid & 3) * 16;
  unsigned short hi[16], lo[16];
  #pragma unroll
  for (int j = 0; j < 16; j++){
    float x = os[d0 + j][f];
    unsigned short h = f2bf(x);
    hi[j] = h;
    lo[j] = f2bf(x - bf2f(h));
  }
  unsigned short* oh = osumb + ((size_t)bn * 2) * 4096 + (size_t)f * 64 + d0;
  unsigned short* ol = oh + 4096;
  *(short8*)(oh)     = *(const short8*)(hi);
  *(short8*)(oh + 8) = *(const short8*)(hi + 8);
  *(short8*)(ol)     = *(const short8*)(lo);
  *(short8*)(ol + 8) = *(const short8*)(lo + 8);
}

// ---------------- ctx via MFMA: R = Qk @ osum (hi+lo), ctx = bf16(Xphi * R) ----------------
// Xphi read from lin cols 3072.., stride NLIN_. Epilogue via LDS bounce:
// R -> bf16 LDS rb[256][72], barrier, then one s-row per thread with 16B vector
// Xphi loads / LDS reads / ctx stores (replaces 256 scalar 2B stores per thread).
__global__ __launch_bounds__(256) void ctx_mfma(const unsigned short* __restrict__ Qk,
                                                const unsigned short* __restrict__ osumb,
                                                const unsigned short* __restrict__ lin,
                                                unsigned short* __restrict__ ctx){
  int bn = blockIdx.x, sc = blockIdx.y;   // 64 x 16
  int b = bn >> 5, n = bn & 31;
  int tid = threadIdx.x;
  int w = tid >> 6, lane = tid & 63;
  int l15 = lane & 15, quad = lane >> 4;

  __shared__ unsigned short rb[256][72];   // 36 KB, padded rows (144B, 16B-aligned)

  const unsigned short* obase = osumb + ((size_t)bn * 2) * 4096;
  short8 bh[4][2], bl[4][2];
  #pragma unroll
  for (int nf = 0; nf < 4; nf++){
    int f = nf * 16 + l15;
    #pragma unroll
    for (int kh = 0; kh < 2; kh++){
      bh[nf][kh] = *(const short8*)(obase + (size_t)f * 64 + kh * 32 + quad * 8);
      bl[nf][kh] = *(const short8*)(obase + 4096 + (size_t)f * 64 + kh * 32 + quad * 8);
    }
  }

  int s0 = sc * 256 + w * 64;
  const unsigned short* qbase = Qk + ((size_t)bn * S_ + s0) * HD_;
  floatx4 acc[4][4] = {};
  #pragma unroll
  for (int m = 0; m < 4; m++){
    short8 a0 = *(const short8*)(qbase + (size_t)(m * 16 + l15) * HD_ + quad * 8);
    short8 a1 = *(const short8*)(qbase + (size_t)(m * 16 + l15) * HD_ + 32 + quad * 8);
    #pragma unroll
    for (int nf = 0; nf < 4; nf++){
      acc[m][nf] = __builtin_amdgcn_mfma_f32_16x16x32_bf16(a0, bh[nf][0], acc[m][nf], 0, 0, 0);
      acc[m][nf] = __builtin_amdgcn_mfma_f32_16x16x32_bf16(a1, bh[nf][1], acc[m][nf], 0, 0, 0);
      acc[m][nf] = __builtin_amdgcn_mfma_f32_16x16x32_bf16(a0, bl[nf][0], acc[m][nf], 0, 0, 0);
      acc[m][nf] = __builtin_amdgcn_mfma_f32_16x16x32_bf16(a1, bl[nf][1], acc[m][nf], 0, 0, 0);
    }
  }

  // write R to LDS (C/D mapping: col=l15, row=quad*4+r within each 16x16 frag)
  #pragma unroll
  for (int m = 0; m < 4; m++)
    #pragma unroll
    for (int nf = 0; nf < 4; nf++)
      #pragma unroll
      for (int r = 0; r < 4; r++)
        rb[w * 64 + m * 16 + quad * 4 + r][nf * 16 + l15] = f2bf(acc[m][nf][r]);
  __syncthreads();

  // coalesced epilogue: one s-row per thread, 16B vector ops
  int srow = tid;                      // 0..255
  int s = sc * 256 + srow;
  const unsigned short* xp = lin + (size_t)(b * S_ + s) * NLIN_ + 3072 + n * HD_;
  unsigned short* cp = ctx + (size_t)(b * S_ + s) * HID_ + n * HD_;
  #pragma unroll
  for (int c = 0; c < 8; c++){
    short8 xv = *(const short8*)(xp + c * 8);
    short8 rv = *(const short8*)(&rb[srow][c * 8]);
    unsigned short o8[8];
    #pragma unroll
    for (int e = 0; e < 8; e++)
      o8[e] = f2bf(bf2f((unsigned short)xv[e]) * bf2f((unsigned short)rv[e]));
    *(short8*)(cp + c * 8) = *(const short8*)o8;
  }
}

extern "C" void kernel_launch(void* const* d_in, const int* in_sizes, int n_in,
                              void* d_out, int out_size, void* d_ws, size_t ws_size,
                              hipStream_t stream) {
  const float* hs   = (const float*)d_in[0];
  const float* Wq   = (const float*)d_in[1];
  const float* Wk   = (const float*)d_in[2];
  const float* Wv   = (const float*)d_in[3];
  const float* Wphi = (const float*)d_in[4];
  const float* Wo   = (const float*)d_in[5];
  float* out = (float*)d_out;

  char* ws = (char*)d_ws;
  const size_t M = (size_t)B_ * S_;          // 8192
  size_t off = 0;
  auto alloc = [&](size_t bytes){ size_t o = off; off += (bytes + 255) & ~(size_t)255; return o; };

  // region X (32MB): hsb bf16 -> part fp32 -> ctx bf16 (strictly sequential lifetimes)
  size_t off_x     = alloc(M * HID_ * 4);                 // 32MB (fp32-part sized)
  size_t off_wcat  = alloc((size_t)NLIN_ * HID_ * 2);     // 20MB  [Wq^T; Wk^T; Wv^T; Wphi^T]
  size_t off_wot   = alloc((size_t)HID_ * HID_ * 2);      // 8MB
  size_t off_lin   = alloc(M * NLIN_ * 2);                // 80MB bf16 fused Q|K|V|phi
  size_t off_qk    = alloc(M * HID_ * 2);                 // 32MB bf16 [B,NH,S,D]
  size_t off_kk    = alloc(M * 512 * 2);                  // 8MB  bf16 [B,NKV,S,D]
  size_t off_qg    = alloc(64 * 64 * 4);
  size_t off_alph  = alloc((size_t)B_ * NH_ * S_ * 4);    // 1MB
  size_t off_osumb = alloc((size_t)64 * 2 * 4096 * 2);    // 1MB split-bf16 osum^T
  (void)ws_size;

  unsigned short* hsb  = (unsigned short*)(ws + off_x);
  float*          part = (float*)(ws + off_x);
  unsigned short* ctx  = (unsigned short*)(ws + off_x);
  unsigned short* wcat = (unsigned short*)(ws + off_wcat);
  unsigned short* wot  = (unsigned short*)(ws + off_wot);
  unsigned short* lin  = (unsigned short*)(ws + off_lin);
  unsigned short* qk = (unsigned short*)(ws + off_qk);
  unsigned short* kk = (unsigned short*)(ws + off_kk);
  float* qg   = (float*)(ws + off_qg);
  float* alph = (float*)(ws + off_alph);
  unsigned short* osumb = (unsigned short*)(ws + off_osumb);

  // 1. hs -> bf16 (into X)
  conv_bf16<<<(int)(M * HID_ / 4 / 256), 256, 0, stream>>>(hs, hsb, (int)(M * HID_ / 4));
  // 2. all weight transposes in one launch
  transpose_all<<<dim3(64, 64, 5), dim3(32, 8), 0, stream>>>(Wq, Wk, Wv, Wphi, Wo, wcat, wot);
  // 3. fused Q|K|V|phi projection (bf16 C)
  gemm256<<<dim3(NLIN_/256, M/256), 512, 0, stream>>>(hsb, wcat, lin, (int)M, NLIN_, HID_, 1);
  // 4. fused RoPE + kappa for Q (with Qg mean) and K
  hipMemsetAsync(qg, 0, 64 * 64 * 4, stream);
  rope_fused<<<dim3(80, 16), 256, 0, stream>>>(lin, qk, kk, qg);
  // 5. logits + softmax * S
  logits_kernel<<<dim3(B_ * NH_, S_ / 256), 256, 0, stream>>>(kk, qg, alph);
  softmax_kernel<<<B_ * NH_, 256, 0, stream>>>(alph, alph);
  // 6. outer_sum (partials into X — hsb dead after fused gemm) + transposed split-bf16 reduce
  outer_sum_kernel<<<dim3(B_ * NKV_, NCH_), 256, 0, stream>>>(kk, lin, alph, part);
  osum_reduce_t<<<64, 256, 0, stream>>>(part, osumb);
  // 7. ctx = Xphi * (Qk @ osum) -> bf16 into X (part dead after reduce)
  ctx_mfma<<<dim3(B_ * NH_, S_ / 64 / 4), 256, 0, stream>>>(qk, osumb, lin, ctx);
  // 8. out = ctx @ Wo (fp32 C)
  gemm256<<<dim3(HID_/256, M/256), 512, 0, stream>>>(ctx, wot, out, (int)M, HID_, HID_, 0);
}